// Round 1
// baseline (769.385 us; speedup 1.0000x reference)
//
#include <hip/hip_runtime.h>
#include <hip/hip_bf16.h>
#include <math.h>

// ---- problem dims ----
constexpr int B2   = 2;
constexpr int CIN  = 64;
constexpr int COUT = 128;
constexpr int T    = 8192;
constexpr int L    = 4096;     // T/2
constexpr int DI   = 256;
constexpr int NST  = 16;       // d_state
constexpr int DTR  = 8;
constexpr int Q    = 128;      // scan chunk length
constexpr int NC   = 32;       // L / Q
constexpr int TOK  = B2 * L;   // 8192 tokens

__device__ __forceinline__ float sigmoidf_(float x) { return 1.f / (1.f + __expf(-x)); }

// ---------------------------------------------------------------- zero stats
__global__ __launch_bounds__(64) void zero_stats_kernel(float* stats) {
    if (threadIdx.x < 4) stats[threadIdx.x] = 0.f;
}

// ------------------------------------------------- conv1d stride2 + GN stats
// grid (L/32, COUT/32, B), 256 thr. h stored [B][L][COUT] (token-major).
__global__ __launch_bounds__(256) void conv_gn_kernel(
    const float* __restrict__ x, const float* __restrict__ cw,
    const float* __restrict__ cb, float* __restrict__ h, float* __restrict__ stats) {
    __shared__ float xs[64 * 68];     // 64 cin x 67 positions (pad 68)
    __shared__ float wsw[32 * 325];   // 32 cout x 320 (pad 325)
    const int lt0 = blockIdx.x * 32;
    const int ct0 = blockIdx.y * 32;
    const int b   = blockIdx.z;
    const int tid = threadIdx.x;
    const int p0  = 2 * lt0 - 2;
    for (int idx = tid; idx < 64 * 68; idx += 256) {
        int ci = idx / 68, pl = idx % 68;
        int p = p0 + pl;
        float v = 0.f;
        if (pl < 67 && p >= 0 && p < T) v = x[((size_t)b * CIN + ci) * T + p];
        xs[ci * 68 + pl] = v;
    }
    for (int idx = tid; idx < 32 * 320; idx += 256) {
        int cl = idx / 320, rem = idx % 320;
        wsw[cl * 325 + rem] = cw[(size_t)(ct0 + cl) * 320 + rem];
    }
    __syncthreads();
    const int c_sub = tid & 31, l_sub = tid >> 5;   // l_sub 0..7
    float acc[4] = {0.f, 0.f, 0.f, 0.f};
    for (int ci = 0; ci < 64; ++ci) {
        const float* xb = &xs[ci * 68];
        const float* wb = &wsw[c_sub * 325 + ci * 5];
        #pragma unroll
        for (int k = 0; k < 5; ++k) {
            float w = wb[k];
            #pragma unroll
            for (int j = 0; j < 4; ++j) {
                int ll = l_sub + 8 * j;
                acc[j] = fmaf(w, xb[2 * ll + k], acc[j]);
            }
        }
    }
    float bias = cb[ct0 + c_sub];
    float s = 0.f, ss = 0.f;
    #pragma unroll
    for (int j = 0; j < 4; ++j) {
        float v = acc[j] + bias;
        int l = lt0 + l_sub + 8 * j;
        h[((size_t)b * L + l) * COUT + ct0 + c_sub] = v;
        s += v; ss += v * v;
    }
    #pragma unroll
    for (int off = 32; off; off >>= 1) {
        s  += __shfl_down(s,  off, 64);
        ss += __shfl_down(ss, off, 64);
    }
    if ((tid & 63) == 0) {
        atomicAdd(&stats[b * 2 + 0], s);
        atomicAdd(&stats[b * 2 + 1], ss);
    }
}

// ------------------------------------------------------ GN apply + PReLU
__global__ __launch_bounds__(256) void gn_prelu_kernel(
    float* __restrict__ h, const float* __restrict__ gn_g,
    const float* __restrict__ gn_b, const float* __restrict__ prelu_a,
    const float* __restrict__ stats) {
    int i = blockIdx.x * 256 + threadIdx.x;      // 262144 threads, x4 elements
    size_t base = (size_t)i * 4;
    int b = (base >= (size_t)L * COUT) ? 1 : 0;
    const float n = (float)(L * COUT);
    float mu   = stats[b * 2 + 0] / n;
    float var  = stats[b * 2 + 1] / n - mu * mu;
    float rstd = rsqrtf(var + 1e-5f);
    float a = prelu_a[0];
    float4 v = *(const float4*)&h[base];
    int c = (int)(base % COUT);
    float4 g  = *(const float4*)&gn_g[c];
    float4 bb = *(const float4*)&gn_b[c];
    v.x = (v.x - mu) * rstd * g.x + bb.x; v.x = v.x >= 0.f ? v.x : a * v.x;
    v.y = (v.y - mu) * rstd * g.y + bb.y; v.y = v.y >= 0.f ? v.y : a * v.y;
    v.z = (v.z - mu) * rstd * g.z + bb.z; v.z = v.z >= 0.f ? v.z : a * v.z;
    v.w = (v.w - mu) * rstd * g.w + bb.w; v.w = v.w >= 0.f ? v.w : a * v.w;
    *(float4*)&h[base] = v;
}

// ------------------------------------------------------ per-token LayerNorm
// wave per token (C=128, 2 per lane); block = 4 waves.
__global__ __launch_bounds__(256) void ln_kernel(
    const float* __restrict__ h, float* __restrict__ hn,
    const float* __restrict__ g, const float* __restrict__ bta) {
    int wave = threadIdx.x >> 6, lane = threadIdx.x & 63;
    int t = blockIdx.x * 4 + wave;
    const float* row = h + (size_t)t * COUT;
    float2 v = *(const float2*)&row[lane * 2];
    float s = v.x + v.y, ss = v.x * v.x + v.y * v.y;
    #pragma unroll
    for (int off = 32; off; off >>= 1) {
        s  += __shfl_xor(s,  off, 64);
        ss += __shfl_xor(ss, off, 64);
    }
    float mu = s * (1.f / 128.f);
    float var = ss * (1.f / 128.f) - mu * mu;
    float rstd = rsqrtf(var + 1e-5f);
    float2 gg = *(const float2*)&g[lane * 2];
    float2 bb = *(const float2*)&bta[lane * 2];
    float2 o;
    o.x = (v.x - mu) * rstd * gg.x + bb.x;
    o.y = (v.y - mu) * rstd * gg.y + bb.y;
    *(float2*)&hn[(size_t)t * COUT + lane * 2] = o;
}

// ------------------------------------------------- inproj GEMM  M=8192 K=128
// N=1024 (2 inst x 512). BM=64, BN=64, k-chunks of 32. 256 thr, 4x4 micro.
__global__ __launch_bounds__(256) void inproj_kernel(
    const float* __restrict__ hn, const float* __restrict__ W_in,
    float* __restrict__ xp0, float* __restrict__ z0,
    float* __restrict__ xp1, float* __restrict__ z1, int layer) {
    __shared__ float As[32 * 68];
    __shared__ float Bs[32 * 68];
    const int tid   = threadIdx.x;
    const int tBase = blockIdx.x * 64;
    const int nBase = blockIdx.y * 64;
    const int inst  = nBase >> 9;
    const int e0    = nBase & 511;
    const int m     = layer * 2 + inst;
    const float* Wm = W_in + ((size_t)m * 512 + e0) * 128;
    const int mrow = tid >> 2;      // 0..63
    const int kq   = tid & 3;       // 0..3
    const int m0   = (tid & 15) * 4;
    const int n0   = (tid >> 4) * 4;
    float acc[4][4] = {};
    for (int kc = 0; kc < 128; kc += 32) {
        {
            const float* srcA = hn + (size_t)(tBase + mrow) * 128 + kc + kq * 8;
            float4 a0 = *(const float4*)srcA;
            float4 a1 = *(const float4*)(srcA + 4);
            int kk = kq * 8;
            As[(kk + 0) * 68 + mrow] = a0.x; As[(kk + 1) * 68 + mrow] = a0.y;
            As[(kk + 2) * 68 + mrow] = a0.z; As[(kk + 3) * 68 + mrow] = a0.w;
            As[(kk + 4) * 68 + mrow] = a1.x; As[(kk + 5) * 68 + mrow] = a1.y;
            As[(kk + 6) * 68 + mrow] = a1.z; As[(kk + 7) * 68 + mrow] = a1.w;
            const float* srcB = Wm + (size_t)mrow * 128 + kc + kq * 8;
            float4 b0 = *(const float4*)srcB;
            float4 b1 = *(const float4*)(srcB + 4);
            Bs[(kk + 0) * 68 + mrow] = b0.x; Bs[(kk + 1) * 68 + mrow] = b0.y;
            Bs[(kk + 2) * 68 + mrow] = b0.z; Bs[(kk + 3) * 68 + mrow] = b0.w;
            Bs[(kk + 4) * 68 + mrow] = b1.x; Bs[(kk + 5) * 68 + mrow] = b1.y;
            Bs[(kk + 6) * 68 + mrow] = b1.z; Bs[(kk + 7) * 68 + mrow] = b1.w;
        }
        __syncthreads();
        #pragma unroll
        for (int kk = 0; kk < 32; ++kk) {
            float4 a = *(const float4*)&As[kk * 68 + m0];
            float4 b = *(const float4*)&Bs[kk * 68 + n0];
            acc[0][0] = fmaf(a.x, b.x, acc[0][0]); acc[0][1] = fmaf(a.x, b.y, acc[0][1]);
            acc[0][2] = fmaf(a.x, b.z, acc[0][2]); acc[0][3] = fmaf(a.x, b.w, acc[0][3]);
            acc[1][0] = fmaf(a.y, b.x, acc[1][0]); acc[1][1] = fmaf(a.y, b.y, acc[1][1]);
            acc[1][2] = fmaf(a.y, b.z, acc[1][2]); acc[1][3] = fmaf(a.y, b.w, acc[1][3]);
            acc[2][0] = fmaf(a.z, b.x, acc[2][0]); acc[2][1] = fmaf(a.z, b.y, acc[2][1]);
            acc[2][2] = fmaf(a.z, b.z, acc[2][2]); acc[2][3] = fmaf(a.z, b.w, acc[2][3]);
            acc[3][0] = fmaf(a.w, b.x, acc[3][0]); acc[3][1] = fmaf(a.w, b.y, acc[3][1]);
            acc[3][2] = fmaf(a.w, b.z, acc[3][2]); acc[3][3] = fmaf(a.w, b.w, acc[3][3]);
        }
        __syncthreads();
    }
    float* dst; int eoff;
    if (e0 < 256) { dst = inst ? xp1 : xp0; eoff = e0; }
    else          { dst = inst ? z1  : z0;  eoff = e0 - 256; }
    #pragma unroll
    for (int im = 0; im < 4; ++im) {
        float4 v = make_float4(acc[im][0], acc[im][1], acc[im][2], acc[im][3]);
        *(float4*)&dst[(size_t)(tBase + m0 + im) * DI + eoff + n0] = v;
    }
}

// ---------------------------------------- depthwise causal conv (d=4) + SiLU
__global__ __launch_bounds__(256) void dwconv_kernel(
    const float* __restrict__ xp0, const float* __restrict__ xp1,
    const float* __restrict__ cw, const float* __restrict__ cbias,
    float* __restrict__ u0, float* __restrict__ u1, int layer) {
    int flat = blockIdx.x * 256 + threadIdx.x;
    int d    = flat & 255;
    int l    = (flat >> 8) & (L - 1);
    int b    = (flat >> 20) & 1;
    int inst = flat >> 21;
    const float* xp = inst ? xp1 : xp0;
    float* u = inst ? u1 : u0;
    int m = layer * 2 + inst;
    const float4 w4 = *(const float4*)&cw[(size_t)(m * DI + d) * 4];
    float acc = cbias[m * DI + d];
    size_t base = ((size_t)b * L) * DI + d;
    if (inst == 0) {  // forward: taps l-3..l, weights w[0]..w[3]
        if (l - 3 >= 0) acc = fmaf(w4.x, xp[base + (size_t)(l - 3) * DI], acc);
        if (l - 2 >= 0) acc = fmaf(w4.y, xp[base + (size_t)(l - 2) * DI], acc);
        if (l - 1 >= 0) acc = fmaf(w4.z, xp[base + (size_t)(l - 1) * DI], acc);
        acc = fmaf(w4.w, xp[base + (size_t)l * DI], acc);
    } else {          // backward (natural coords): taps l..l+3, w[3]..w[0]
        acc = fmaf(w4.w, xp[base + (size_t)l * DI], acc);
        if (l + 1 < L) acc = fmaf(w4.z, xp[base + (size_t)(l + 1) * DI], acc);
        if (l + 2 < L) acc = fmaf(w4.y, xp[base + (size_t)(l + 2) * DI], acc);
        if (l + 3 < L) acc = fmaf(w4.x, xp[base + (size_t)(l + 3) * DI], acc);
    }
    u[base + (size_t)l * DI] = acc * sigmoidf_(acc);
}

// ------------------------------------- xproj (u->dt,B,C) + dt-proj + softplus
// block: 32 tokens x 1 inst. grid (TOK/32, 2).
__global__ __launch_bounds__(256) void xproj_kernel(
    const float* __restrict__ u0, const float* __restrict__ u1,
    const float* __restrict__ Wx, const float* __restrict__ Wdt,
    const float* __restrict__ bdt,
    float* __restrict__ dl0, float* __restrict__ dl1,
    float* __restrict__ Bm0, float* __restrict__ Bm1,
    float* __restrict__ Cm0, float* __restrict__ Cm1, int layer) {
    __shared__ float Us[32 * 261];
    __shared__ float xd[32 * 45];
    const int tid   = threadIdx.x;
    const int tBase = blockIdx.x * 32;
    const int inst  = blockIdx.y;
    const int m     = layer * 2 + inst;
    const float* u = inst ? u1 : u0;
    for (int idx = tid; idx < 32 * 256; idx += 256) {
        int t = idx >> 8, k = idx & 255;
        Us[t * 261 + k] = u[(size_t)(tBase + t) * DI + k];
    }
    __syncthreads();
    {
        int t = tid & 31, eq = tid >> 5;
        float* Bm = inst ? Bm1 : Bm0;
        float* Cm = inst ? Cm1 : Cm0;
        #pragma unroll
        for (int j = 0; j < 5; ++j) {
            int e = eq + 8 * j;
            const float* wr = Wx + ((size_t)m * 40 + e) * 256;
            const float* ur = &Us[t * 261];
            float acc = 0.f;
            #pragma unroll 4
            for (int k = 0; k < 256; ++k) acc = fmaf(ur[k], wr[k], acc);
            if (e < 8)        xd[t * 45 + e] = acc;
            else if (e < 24)  Bm[(size_t)(tBase + t) * NST + (e - 8)]  = acc;
            else              Cm[(size_t)(tBase + t) * NST + (e - 24)] = acc;
        }
    }
    __syncthreads();
    {
        int d = tid;
        float wr[8];
        #pragma unroll
        for (int r = 0; r < 8; ++r) wr[r] = Wdt[((size_t)m * DI + d) * DTR + r];
        float bb = bdt[m * DI + d];
        float* dl = inst ? dl1 : dl0;
        for (int t = 0; t < 32; ++t) {
            float acc = bb;
            #pragma unroll
            for (int r = 0; r < 8; ++r) acc = fmaf(xd[t * 45 + r], wr[r], acc);
            float sp = (acc > 15.f) ? acc : log1pf(expf(acc));   // softplus
            dl[(size_t)(tBase + t) * DI + d] = sp;
        }
    }
}

// ---------------------------------------------- scan phase 1: chunk-local
// grid (NC*16 dtiles, B, inst); thread = n(16) x dsub(16).
__global__ __launch_bounds__(256) void scan1_kernel(
    const float* __restrict__ dl0, const float* __restrict__ dl1,
    const float* __restrict__ u0,  const float* __restrict__ u1,
    const float* __restrict__ Bm0, const float* __restrict__ Bm1,
    const float* __restrict__ A_log,
    float* __restrict__ hend, float* __restrict__ dsumb, int layer) {
    const int tid = threadIdx.x;
    const int n = tid & 15, dsub = tid >> 4;
    const int chunk = blockIdx.x & 31, dtile = blockIdx.x >> 5;
    const int b = blockIdx.y, inst = blockIdx.z;
    const int m = layer * 2 + inst, dir = inst;
    const int d = dtile * 16 + dsub;
    const float* dl = inst ? dl1 : dl0;
    const float* u  = inst ? u1  : u0;
    const float* Bm = inst ? Bm1 : Bm0;
    const float a = -expf(A_log[((size_t)m * DI + d) * NST + n]);
    const int s0 = chunk * Q;
    const int l0 = dir ? (L - 1 - s0) : s0;
    const int stp = dir ? -1 : 1;
    long iDU = ((long)b * L + l0) * DI + d;
    int  iB  = ((b * L + l0) << 4) + n;
    const long sDU = (long)stp * DI;
    const int  sB  = stp * NST;
    float hc = 0.f, dsum = 0.f;
    #pragma unroll 4
    for (int t = 0; t < Q; ++t) {
        float dlt = dl[iDU], uu = u[iDU], bm = Bm[iB];
        hc = fmaf(__expf(dlt * a), hc, dlt * uu * bm);
        dsum += dlt;
        iDU += sDU; iB += sB;
    }
    hend[(((size_t)(inst * 2 + b) * DI + d) * NC + chunk) * NST + n] = hc;
    if (n == 0) dsumb[((size_t)(inst * 2 + b) * NC + chunk) * DI + d] = dsum;
}

// ---------------------------------------------- scan combine (32 steps)
__global__ __launch_bounds__(256) void combine_kernel(
    const float* __restrict__ hend, const float* __restrict__ dsumb,
    const float* __restrict__ A_log, float* __restrict__ hin, int layer) {
    int flat = blockIdx.x * 256 + threadIdx.x;   // 16384
    int n = flat & 15;
    int d = (flat >> 4) & 255;
    int b = (flat >> 12) & 1;
    int inst = flat >> 13;
    int m = layer * 2 + inst;
    float a = -expf(A_log[((size_t)m * DI + d) * NST + n]);
    size_t baseE = (((size_t)(inst * 2 + b) * DI + d) * NC) * NST + n;
    size_t baseD = ((size_t)(inst * 2 + b) * NC) * DI + d;
    float hc = 0.f;
    for (int c = 0; c < NC; ++c) {
        hin[baseE + (size_t)c * NST] = hc;
        float ds = dsumb[baseD + (size_t)c * DI];
        hc = fmaf(__expf(a * ds), hc, hend[baseE + (size_t)c * NST]);
    }
}

// --------------------------------- scan phase 2: full scan + y + gate(z)
__global__ __launch_bounds__(256) void scan2_kernel(
    const float* __restrict__ dl0, const float* __restrict__ dl1,
    const float* __restrict__ u0,  const float* __restrict__ u1,
    const float* __restrict__ Bm0, const float* __restrict__ Bm1,
    const float* __restrict__ Cm0, const float* __restrict__ Cm1,
    const float* __restrict__ z0,  const float* __restrict__ z1,
    const float* __restrict__ hin, const float* __restrict__ A_log,
    const float* __restrict__ Dp,
    float* __restrict__ yg0, float* __restrict__ yg1, int layer) {
    const int tid = threadIdx.x;
    const int n = tid & 15, dsub = tid >> 4;
    const int chunk = blockIdx.x & 31, dtile = blockIdx.x >> 5;
    const int b = blockIdx.y, inst = blockIdx.z;
    const int m = layer * 2 + inst, dir = inst;
    const int d = dtile * 16 + dsub;
    const float* dl = inst ? dl1 : dl0;
    const float* u  = inst ? u1  : u0;
    const float* Bm = inst ? Bm1 : Bm0;
    const float* Cm = inst ? Cm1 : Cm0;
    const float* z  = inst ? z1  : z0;
    float* yg = inst ? yg1 : yg0;
    const float a = -expf(A_log[((size_t)m * DI + d) * NST + n]);
    const float dpar = Dp[m * DI + d];
    const int s0 = chunk * Q;
    const int l0 = dir ? (L - 1 - s0) : s0;
    const int stp = dir ? -1 : 1;
    long iDU = ((long)b * L + l0) * DI + d;
    int  iB  = ((b * L + l0) << 4) + n;
    const long sDU = (long)stp * DI;
    const int  sB  = stp * NST;
    float hc = hin[(((size_t)(inst * 2 + b) * DI + d) * NC + chunk) * NST + n];
    #pragma unroll 2
    for (int t = 0; t < Q; ++t) {
        float dlt = dl[iDU], uu = u[iDU], bm = Bm[iB], cm = Cm[iB];
        hc = fmaf(__expf(dlt * a), hc, dlt * uu * bm);
        float yp = hc * cm;
        yp += __shfl_xor(yp, 1, 16);
        yp += __shfl_xor(yp, 2, 16);
        yp += __shfl_xor(yp, 4, 16);
        yp += __shfl_xor(yp, 8, 16);
        float zv = z[iDU];
        if (n == 0) {
            yg[iDU] = (yp + uu * dpar) * (zv * sigmoidf_(zv));
        }
        iDU += sDU; iB += sB;
    }
}

// ------------------------------- outproj GEMM (both insts) + residual into h
// BM=32, N=128, K=256 per inst. 256 thr, 2x8 micro.
__global__ __launch_bounds__(256) void outproj_kernel(
    const float* __restrict__ yg0, const float* __restrict__ yg1,
    const float* __restrict__ W_out, float* __restrict__ h, int layer) {
    __shared__ float As[32 * 36];
    __shared__ float Bs[32 * 132];
    const int tid = threadIdx.x;
    const int tBase = blockIdx.x * 32;
    const int m00 = (tid & 15) * 2, n0 = (tid >> 4) * 8;
    float acc[2][8] = {};
    for (int inst = 0; inst < 2; ++inst) {
        const float* yg = inst ? yg1 : yg0;
        const float* Wm = W_out + (size_t)(layer * 2 + inst) * COUT * DI;
        for (int kc = 0; kc < 256; kc += 32) {
            {
                int t = tid >> 3, kq = tid & 7;
                float4 v = *(const float4*)&yg[(size_t)(tBase + t) * DI + kc + kq * 4];
                As[(kq * 4 + 0) * 36 + t] = v.x; As[(kq * 4 + 1) * 36 + t] = v.y;
                As[(kq * 4 + 2) * 36 + t] = v.z; As[(kq * 4 + 3) * 36 + t] = v.w;
                int nr = tid >> 1, kq2 = tid & 1;
                const float* wsrc = Wm + (size_t)nr * DI + kc + kq2 * 16;
                #pragma unroll
                for (int q = 0; q < 4; ++q) {
                    float4 wv = *(const float4*)(wsrc + q * 4);
                    int kk = kq2 * 16 + q * 4;
                    Bs[(kk + 0) * 132 + nr] = wv.x; Bs[(kk + 1) * 132 + nr] = wv.y;
                    Bs[(kk + 2) * 132 + nr] = wv.z; Bs[(kk + 3) * 132 + nr] = wv.w;
                }
            }
            __syncthreads();
            #pragma unroll
            for (int kk = 0; kk < 32; ++kk) {
                float2 av = *(const float2*)&As[kk * 36 + m00];
                float4 b0 = *(const float4*)&Bs[kk * 132 + n0];
                float4 b1 = *(const float4*)&Bs[kk * 132 + n0 + 4];
                acc[0][0] = fmaf(av.x, b0.x, acc[0][0]); acc[0][1] = fmaf(av.x, b0.y, acc[0][1]);
                acc[0][2] = fmaf(av.x, b0.z, acc[0][2]); acc[0][3] = fmaf(av.x, b0.w, acc[0][3]);
                acc[0][4] = fmaf(av.x, b1.x, acc[0][4]); acc[0][5] = fmaf(av.x, b1.y, acc[0][5]);
                acc[0][6] = fmaf(av.x, b1.z, acc[0][6]); acc[0][7] = fmaf(av.x, b1.w, acc[0][7]);
                acc[1][0] = fmaf(av.y, b0.x, acc[1][0]); acc[1][1] = fmaf(av.y, b0.y, acc[1][1]);
                acc[1][2] = fmaf(av.y, b0.z, acc[1][2]); acc[1][3] = fmaf(av.y, b0.w, acc[1][3]);
                acc[1][4] = fmaf(av.y, b1.x, acc[1][4]); acc[1][5] = fmaf(av.y, b1.y, acc[1][5]);
                acc[1][6] = fmaf(av.y, b1.z, acc[1][6]); acc[1][7] = fmaf(av.y, b1.w, acc[1][7]);
            }
            __syncthreads();
        }
    }
    #pragma unroll
    for (int im = 0; im < 2; ++im) {
        size_t row = (size_t)(tBase + m00 + im) * COUT + n0;
        float4 h0 = *(const float4*)&h[row];
        float4 h1 = *(const float4*)&h[row + 4];
        h0.x += acc[im][0]; h0.y += acc[im][1]; h0.z += acc[im][2]; h0.w += acc[im][3];
        h1.x += acc[im][4]; h1.y += acc[im][5]; h1.z += acc[im][6]; h1.w += acc[im][7];
        *(float4*)&h[row] = h0;
        *(float4*)&h[row + 4] = h1;
    }
}

// ------------------------------------------------ final [B,L,C] -> [B,C,L]
__global__ __launch_bounds__(256) void transpose_kernel(
    const float* __restrict__ h, float* __restrict__ out) {
    __shared__ float tile[32][33];
    int lt0 = blockIdx.x * 32, ct0 = blockIdx.y * 32, b = blockIdx.z;
    int c = threadIdx.x & 31, r = threadIdx.x >> 5;
    #pragma unroll
    for (int j = 0; j < 4; ++j) {
        int ll = r + 8 * j;
        tile[ll][c] = h[((size_t)b * L + lt0 + ll) * COUT + ct0 + c];
    }
    __syncthreads();
    #pragma unroll
    for (int j = 0; j < 4; ++j) {
        int cc = r + 8 * j;
        out[((size_t)b * COUT + ct0 + cc) * L + lt0 + c] = tile[c][cc];
    }
}

// ======================================================================
extern "C" void kernel_launch(void* const* d_in, const int* in_sizes, int n_in,
                              void* d_out, int out_size, void* d_ws, size_t ws_size,
                              hipStream_t stream) {
    const float* x        = (const float*)d_in[0];
    const float* conv_w   = (const float*)d_in[1];
    const float* conv_b   = (const float*)d_in[2];
    const float* gn_g     = (const float*)d_in[3];
    const float* gn_b     = (const float*)d_in[4];
    const float* prelu_a  = (const float*)d_in[5];
    const float* ln_g     = (const float*)d_in[6];
    const float* ln_b     = (const float*)d_in[7];
    const float* W_in     = (const float*)d_in[8];
    const float* conv1d_w = (const float*)d_in[9];
    const float* conv1d_b = (const float*)d_in[10];
    const float* W_xproj  = (const float*)d_in[11];
    const float* W_dt     = (const float*)d_in[12];
    const float* b_dt     = (const float*)d_in[13];
    const float* A_log    = (const float*)d_in[14];
    const float* D_param  = (const float*)d_in[15];
    const float* W_out    = (const float*)d_in[16];

    float* ws = (float*)d_ws;
    float* h     = ws;                   // [B,L,128]      1,048,576
    float* hn    = ws + 1048576;         // [B,L,128]
    float* xp0   = ws + 2097152;         // [B,L,256]  (reused as yg0)
    float* xp1   = ws + 4194304;         //            (reused as yg1)
    float* z0    = ws + 6291456;
    float* z1    = ws + 8388608;
    float* u0    = ws + 10485760;
    float* u1    = ws + 12582912;
    float* dl0   = ws + 14680064;
    float* dl1   = ws + 16777216;
    float* Bm0   = ws + 18874368;        // [B,L,16]
    float* Bm1   = ws + 19005440;
    float* Cm0   = ws + 19136512;
    float* Cm1   = ws + 19267584;
    float* hend  = ws + 19398656;        // [2,B,256,32,16]
    float* hin   = ws + 19922944;
    float* dsumb = ws + 20447232;        // [2,B,32,256]
    float* stats = ws + 20480000;        // [4]

    zero_stats_kernel<<<1, 64, 0, stream>>>(stats);
    conv_gn_kernel<<<dim3(L / 32, COUT / 32, B2), 256, 0, stream>>>(x, conv_w, conv_b, h, stats);
    gn_prelu_kernel<<<(TOK * COUT / 4) / 256, 256, 0, stream>>>(h, gn_g, gn_b, prelu_a, stats);

    for (int layer = 0; layer < 2; ++layer) {
        ln_kernel<<<TOK / 4, 256, 0, stream>>>(h, hn, ln_g + layer * COUT, ln_b + layer * COUT);
        inproj_kernel<<<dim3(TOK / 64, 16), 256, 0, stream>>>(hn, W_in, xp0, z0, xp1, z1, layer);
        dwconv_kernel<<<(2 * B2 * L * DI) / 256, 256, 0, stream>>>(xp0, xp1, conv1d_w, conv1d_b, u0, u1, layer);
        xproj_kernel<<<dim3(TOK / 32, 2), 256, 0, stream>>>(u0, u1, W_xproj, W_dt, b_dt,
                                                            dl0, dl1, Bm0, Bm1, Cm0, Cm1, layer);
        scan1_kernel<<<dim3(NC * 16, B2, 2), 256, 0, stream>>>(dl0, dl1, u0, u1, Bm0, Bm1,
                                                               A_log, hend, dsumb, layer);
        combine_kernel<<<64, 256, 0, stream>>>(hend, dsumb, A_log, hin, layer);
        scan2_kernel<<<dim3(NC * 16, B2, 2), 256, 0, stream>>>(dl0, dl1, u0, u1, Bm0, Bm1, Cm0, Cm1,
                                                               z0, z1, hin, A_log, D_param,
                                                               xp0, xp1, layer);
        outproj_kernel<<<TOK / 32, 256, 0, stream>>>(xp0, xp1, W_out, h, layer);
    }
    transpose_kernel<<<dim3(L / 32, COUT / 32, B2), 256, 0, stream>>>(h, (float*)d_out);
}

// Round 2
// 712.262 us; speedup vs baseline: 1.0802x; 1.0802x over previous
//
#include <hip/hip_runtime.h>
#include <hip/hip_bf16.h>
#include <math.h>

// ---- problem dims ----
constexpr int B2   = 2;
constexpr int CIN  = 64;
constexpr int COUT = 128;
constexpr int T    = 8192;
constexpr int L    = 4096;     // T/2
constexpr int DI   = 256;
constexpr int NST  = 16;       // d_state
constexpr int DTR  = 8;
constexpr int Q    = 128;      // scan chunk length
constexpr int NC   = 32;       // L / Q
constexpr int TOK  = B2 * L;   // 8192 tokens

__device__ __forceinline__ float sigmoidf_(float x) { return 1.f / (1.f + __expf(-x)); }

// ---------------------------------------------------------------- zero stats
__global__ __launch_bounds__(64) void zero_stats_kernel(float* stats) {
    if (threadIdx.x < 4) stats[threadIdx.x] = 0.f;
}

// ------------------------------------------- conv weight transpose [128][320] -> [320][128]
__global__ __launch_bounds__(256) void transpose_w_kernel(
    const float* __restrict__ cw, float* __restrict__ Wt) {
    int idx = blockIdx.x * 256 + threadIdx.x;   // 40960
    int c = idx & 127, kidx = idx >> 7;
    Wt[(size_t)kidx * COUT + c] = cw[(size_t)c * 320 + kidx];
}

// ------------------------------------- conv1d stride2 as implicit-im2col GEMM + GN stats
// A = patches[tok, K=320] (K = ci*5 + k), B = Wt[320,128]. Tile 64 tok x 64 cout.
// grid (TOK/64, COUT/64), 256 thr, 4x4 micro. h stored [B][L][COUT] token-major.
__global__ __launch_bounds__(256) void conv_gemm_kernel(
    const float* __restrict__ x, const float* __restrict__ Wt,
    const float* __restrict__ cb, float* __restrict__ h, float* __restrict__ stats) {
    __shared__ float As[32 * 68];
    __shared__ float Bs[32 * 68];
    const int tid = threadIdx.x;
    const int t0  = blockIdx.x * 64;            // flat token base (b*L + l)
    const int ct0 = blockIdx.y * 64;
    const int b   = t0 >> 12;                   // L = 4096
    const int l0  = t0 & (L - 1);
    const float* xb = x + (size_t)b * CIN * T;
    const int m0 = (tid & 15) * 4;
    const int n0 = (tid >> 4) * 4;
    float acc[4][4] = {};
    for (int kc = 0; kc < 320; kc += 32) {
        #pragma unroll
        for (int i = 0; i < 8; ++i) {
            int idx = i * 256 + tid;            // 2048 = 32 kk x 64 t
            int kk = idx >> 6, t = idx & 63;
            int K = kc + kk;
            int ci = K / 5, k = K - ci * 5;
            int p = 2 * (l0 + t) + k - 2;
            float v = (p >= 0 && p < T) ? xb[(size_t)ci * T + p] : 0.f;
            As[kk * 68 + t] = v;
            Bs[kk * 68 + t] = Wt[(size_t)K * COUT + ct0 + t];
        }
        __syncthreads();
        #pragma unroll
        for (int kk = 0; kk < 32; ++kk) {
            float4 a = *(const float4*)&As[kk * 68 + m0];
            float4 bb = *(const float4*)&Bs[kk * 68 + n0];
            acc[0][0] = fmaf(a.x, bb.x, acc[0][0]); acc[0][1] = fmaf(a.x, bb.y, acc[0][1]);
            acc[0][2] = fmaf(a.x, bb.z, acc[0][2]); acc[0][3] = fmaf(a.x, bb.w, acc[0][3]);
            acc[1][0] = fmaf(a.y, bb.x, acc[1][0]); acc[1][1] = fmaf(a.y, bb.y, acc[1][1]);
            acc[1][2] = fmaf(a.y, bb.z, acc[1][2]); acc[1][3] = fmaf(a.y, bb.w, acc[1][3]);
            acc[2][0] = fmaf(a.z, bb.x, acc[2][0]); acc[2][1] = fmaf(a.z, bb.y, acc[2][1]);
            acc[2][2] = fmaf(a.z, bb.z, acc[2][2]); acc[2][3] = fmaf(a.z, bb.w, acc[2][3]);
            acc[3][0] = fmaf(a.w, bb.x, acc[3][0]); acc[3][1] = fmaf(a.w, bb.y, acc[3][1]);
            acc[3][2] = fmaf(a.w, bb.z, acc[3][2]); acc[3][3] = fmaf(a.w, bb.w, acc[3][3]);
        }
        __syncthreads();
    }
    float4 bias = *(const float4*)&cb[ct0 + n0];
    float s = 0.f, ss = 0.f;
    #pragma unroll
    for (int im = 0; im < 4; ++im) {
        float4 v = make_float4(acc[im][0] + bias.x, acc[im][1] + bias.y,
                               acc[im][2] + bias.z, acc[im][3] + bias.w);
        *(float4*)&h[(size_t)(t0 + m0 + im) * COUT + ct0 + n0] = v;
        s  += v.x + v.y + v.z + v.w;
        ss += v.x * v.x + v.y * v.y + v.z * v.z + v.w * v.w;
    }
    #pragma unroll
    for (int off = 32; off; off >>= 1) {
        s  += __shfl_down(s,  off, 64);
        ss += __shfl_down(ss, off, 64);
    }
    if ((tid & 63) == 0) {
        atomicAdd(&stats[b * 2 + 0], s);
        atomicAdd(&stats[b * 2 + 1], ss);
    }
}

// ------------------------------------------------------ GN apply + PReLU
__global__ __launch_bounds__(256) void gn_prelu_kernel(
    float* __restrict__ h, const float* __restrict__ gn_g,
    const float* __restrict__ gn_b, const float* __restrict__ prelu_a,
    const float* __restrict__ stats) {
    int i = blockIdx.x * 256 + threadIdx.x;      // 262144 threads, x4 elements
    size_t base = (size_t)i * 4;
    int b = (base >= (size_t)L * COUT) ? 1 : 0;
    const float n = (float)(L * COUT);
    float mu   = stats[b * 2 + 0] / n;
    float var  = stats[b * 2 + 1] / n - mu * mu;
    float rstd = rsqrtf(var + 1e-5f);
    float a = prelu_a[0];
    float4 v = *(const float4*)&h[base];
    int c = (int)(base % COUT);
    float4 g  = *(const float4*)&gn_g[c];
    float4 bb = *(const float4*)&gn_b[c];
    v.x = (v.x - mu) * rstd * g.x + bb.x; v.x = v.x >= 0.f ? v.x : a * v.x;
    v.y = (v.y - mu) * rstd * g.y + bb.y; v.y = v.y >= 0.f ? v.y : a * v.y;
    v.z = (v.z - mu) * rstd * g.z + bb.z; v.z = v.z >= 0.f ? v.z : a * v.z;
    v.w = (v.w - mu) * rstd * g.w + bb.w; v.w = v.w >= 0.f ? v.w : a * v.w;
    *(float4*)&h[base] = v;
}

// ------------------------------------------------------ per-token LayerNorm
// wave per token (C=128, 2 per lane); block = 4 waves.
__global__ __launch_bounds__(256) void ln_kernel(
    const float* __restrict__ h, float* __restrict__ hn,
    const float* __restrict__ g, const float* __restrict__ bta) {
    int wave = threadIdx.x >> 6, lane = threadIdx.x & 63;
    int t = blockIdx.x * 4 + wave;
    const float* row = h + (size_t)t * COUT;
    float2 v = *(const float2*)&row[lane * 2];
    float s = v.x + v.y, ss = v.x * v.x + v.y * v.y;
    #pragma unroll
    for (int off = 32; off; off >>= 1) {
        s  += __shfl_xor(s,  off, 64);
        ss += __shfl_xor(ss, off, 64);
    }
    float mu = s * (1.f / 128.f);
    float var = ss * (1.f / 128.f) - mu * mu;
    float rstd = rsqrtf(var + 1e-5f);
    float2 gg = *(const float2*)&g[lane * 2];
    float2 bb = *(const float2*)&bta[lane * 2];
    float2 o;
    o.x = (v.x - mu) * rstd * gg.x + bb.x;
    o.y = (v.y - mu) * rstd * gg.y + bb.y;
    *(float2*)&hn[(size_t)t * COUT + lane * 2] = o;
}

// ------------------------------------------------- inproj GEMM  M=8192 K=128
// N=1024 (2 inst x 512). BM=64, BN=64, k-chunks of 32. 256 thr, 4x4 micro.
__global__ __launch_bounds__(256) void inproj_kernel(
    const float* __restrict__ hn, const float* __restrict__ W_in,
    float* __restrict__ xp0, float* __restrict__ z0,
    float* __restrict__ xp1, float* __restrict__ z1, int layer) {
    __shared__ float As[32 * 68];
    __shared__ float Bs[32 * 68];
    const int tid   = threadIdx.x;
    const int tBase = blockIdx.x * 64;
    const int nBase = blockIdx.y * 64;
    const int inst  = nBase >> 9;
    const int e0    = nBase & 511;
    const int m     = layer * 2 + inst;
    const float* Wm = W_in + ((size_t)m * 512 + e0) * 128;
    const int mrow = tid >> 2;      // 0..63
    const int kq   = tid & 3;       // 0..3
    const int m0   = (tid & 15) * 4;
    const int n0   = (tid >> 4) * 4;
    float acc[4][4] = {};
    for (int kc = 0; kc < 128; kc += 32) {
        {
            const float* srcA = hn + (size_t)(tBase + mrow) * 128 + kc + kq * 8;
            float4 a0 = *(const float4*)srcA;
            float4 a1 = *(const float4*)(srcA + 4);
            int kk = kq * 8;
            As[(kk + 0) * 68 + mrow] = a0.x; As[(kk + 1) * 68 + mrow] = a0.y;
            As[(kk + 2) * 68 + mrow] = a0.z; As[(kk + 3) * 68 + mrow] = a0.w;
            As[(kk + 4) * 68 + mrow] = a1.x; As[(kk + 5) * 68 + mrow] = a1.y;
            As[(kk + 6) * 68 + mrow] = a1.z; As[(kk + 7) * 68 + mrow] = a1.w;
            const float* srcB = Wm + (size_t)mrow * 128 + kc + kq * 8;
            float4 b0 = *(const float4*)srcB;
            float4 b1 = *(const float4*)(srcB + 4);
            Bs[(kk + 0) * 68 + mrow] = b0.x; Bs[(kk + 1) * 68 + mrow] = b0.y;
            Bs[(kk + 2) * 68 + mrow] = b0.z; Bs[(kk + 3) * 68 + mrow] = b0.w;
            Bs[(kk + 4) * 68 + mrow] = b1.x; Bs[(kk + 5) * 68 + mrow] = b1.y;
            Bs[(kk + 6) * 68 + mrow] = b1.z; Bs[(kk + 7) * 68 + mrow] = b1.w;
        }
        __syncthreads();
        #pragma unroll
        for (int kk = 0; kk < 32; ++kk) {
            float4 a = *(const float4*)&As[kk * 68 + m0];
            float4 b = *(const float4*)&Bs[kk * 68 + n0];
            acc[0][0] = fmaf(a.x, b.x, acc[0][0]); acc[0][1] = fmaf(a.x, b.y, acc[0][1]);
            acc[0][2] = fmaf(a.x, b.z, acc[0][2]); acc[0][3] = fmaf(a.x, b.w, acc[0][3]);
            acc[1][0] = fmaf(a.y, b.x, acc[1][0]); acc[1][1] = fmaf(a.y, b.y, acc[1][1]);
            acc[1][2] = fmaf(a.y, b.z, acc[1][2]); acc[1][3] = fmaf(a.y, b.w, acc[1][3]);
            acc[2][0] = fmaf(a.z, b.x, acc[2][0]); acc[2][1] = fmaf(a.z, b.y, acc[2][1]);
            acc[2][2] = fmaf(a.z, b.z, acc[2][2]); acc[2][3] = fmaf(a.z, b.w, acc[2][3]);
            acc[3][0] = fmaf(a.w, b.x, acc[3][0]); acc[3][1] = fmaf(a.w, b.y, acc[3][1]);
            acc[3][2] = fmaf(a.w, b.z, acc[3][2]); acc[3][3] = fmaf(a.w, b.w, acc[3][3]);
        }
        __syncthreads();
    }
    float* dst; int eoff;
    if (e0 < 256) { dst = inst ? xp1 : xp0; eoff = e0; }
    else          { dst = inst ? z1  : z0;  eoff = e0 - 256; }
    #pragma unroll
    for (int im = 0; im < 4; ++im) {
        float4 v = make_float4(acc[im][0], acc[im][1], acc[im][2], acc[im][3]);
        *(float4*)&dst[(size_t)(tBase + m0 + im) * DI + eoff + n0] = v;
    }
}

// ---------------------------------------- depthwise causal conv (d=4) + SiLU
__global__ __launch_bounds__(256) void dwconv_kernel(
    const float* __restrict__ xp0, const float* __restrict__ xp1,
    const float* __restrict__ cw, const float* __restrict__ cbias,
    float* __restrict__ u0, float* __restrict__ u1, int layer) {
    int flat = blockIdx.x * 256 + threadIdx.x;
    int d    = flat & 255;
    int l    = (flat >> 8) & (L - 1);
    int b    = (flat >> 20) & 1;
    int inst = flat >> 21;
    const float* xp = inst ? xp1 : xp0;
    float* u = inst ? u1 : u0;
    int m = layer * 2 + inst;
    const float4 w4 = *(const float4*)&cw[(size_t)(m * DI + d) * 4];
    float acc = cbias[m * DI + d];
    size_t base = ((size_t)b * L) * DI + d;
    if (inst == 0) {  // forward: taps l-3..l, weights w[0]..w[3]
        if (l - 3 >= 0) acc = fmaf(w4.x, xp[base + (size_t)(l - 3) * DI], acc);
        if (l - 2 >= 0) acc = fmaf(w4.y, xp[base + (size_t)(l - 2) * DI], acc);
        if (l - 1 >= 0) acc = fmaf(w4.z, xp[base + (size_t)(l - 1) * DI], acc);
        acc = fmaf(w4.w, xp[base + (size_t)l * DI], acc);
    } else {          // backward (natural coords): taps l..l+3, w[3]..w[0]
        acc = fmaf(w4.w, xp[base + (size_t)l * DI], acc);
        if (l + 1 < L) acc = fmaf(w4.z, xp[base + (size_t)(l + 1) * DI], acc);
        if (l + 2 < L) acc = fmaf(w4.y, xp[base + (size_t)(l + 2) * DI], acc);
        if (l + 3 < L) acc = fmaf(w4.x, xp[base + (size_t)(l + 3) * DI], acc);
    }
    u[base + (size_t)l * DI] = acc * sigmoidf_(acc);
}

// ------------------------------------- xproj (u->dt,B,C) + dt-proj + softplus
// block: 32 tokens x 1 inst. grid (TOK/32, 2).
__global__ __launch_bounds__(256) void xproj_kernel(
    const float* __restrict__ u0, const float* __restrict__ u1,
    const float* __restrict__ Wx, const float* __restrict__ Wdt,
    const float* __restrict__ bdt,
    float* __restrict__ dl0, float* __restrict__ dl1,
    float* __restrict__ Bm0, float* __restrict__ Bm1,
    float* __restrict__ Cm0, float* __restrict__ Cm1, int layer) {
    __shared__ float Us[32 * 261];
    __shared__ float xd[32 * 45];
    const int tid   = threadIdx.x;
    const int tBase = blockIdx.x * 32;
    const int inst  = blockIdx.y;
    const int m     = layer * 2 + inst;
    const float* u = inst ? u1 : u0;
    for (int idx = tid; idx < 32 * 256; idx += 256) {
        int t = idx >> 8, k = idx & 255;
        Us[t * 261 + k] = u[(size_t)(tBase + t) * DI + k];
    }
    __syncthreads();
    {
        int t = tid & 31, eq = tid >> 5;
        float* Bm = inst ? Bm1 : Bm0;
        float* Cm = inst ? Cm1 : Cm0;
        #pragma unroll
        for (int j = 0; j < 5; ++j) {
            int e = eq + 8 * j;
            const float* wr = Wx + ((size_t)m * 40 + e) * 256;
            const float* ur = &Us[t * 261];
            float acc = 0.f;
            #pragma unroll 4
            for (int k = 0; k < 256; ++k) acc = fmaf(ur[k], wr[k], acc);
            if (e < 8)        xd[t * 45 + e] = acc;
            else if (e < 24)  Bm[(size_t)(tBase + t) * NST + (e - 8)]  = acc;
            else              Cm[(size_t)(tBase + t) * NST + (e - 24)] = acc;
        }
    }
    __syncthreads();
    {
        int d = tid;
        float wr[8];
        #pragma unroll
        for (int r = 0; r < 8; ++r) wr[r] = Wdt[((size_t)m * DI + d) * DTR + r];
        float bb = bdt[m * DI + d];
        float* dl = inst ? dl1 : dl0;
        for (int t = 0; t < 32; ++t) {
            float acc = bb;
            #pragma unroll
            for (int r = 0; r < 8; ++r) acc = fmaf(xd[t * 45 + r], wr[r], acc);
            float sp = (acc > 15.f) ? acc : log1pf(expf(acc));   // softplus
            dl[(size_t)(tBase + t) * DI + d] = sp;
        }
    }
}

// ---------------------------------------------- scan phase 1: chunk-local
// grid (NC*16 dtiles, B, inst); thread = n(16) x dsub(16).
__global__ __launch_bounds__(256) void scan1_kernel(
    const float* __restrict__ dl0, const float* __restrict__ dl1,
    const float* __restrict__ u0,  const float* __restrict__ u1,
    const float* __restrict__ Bm0, const float* __restrict__ Bm1,
    const float* __restrict__ A_log,
    float* __restrict__ hend, float* __restrict__ dsumb, int layer) {
    const int tid = threadIdx.x;
    const int n = tid & 15, dsub = tid >> 4;
    const int chunk = blockIdx.x & 31, dtile = blockIdx.x >> 5;
    const int b = blockIdx.y, inst = blockIdx.z;
    const int m = layer * 2 + inst, dir = inst;
    const int d = dtile * 16 + dsub;
    const float* dl = inst ? dl1 : dl0;
    const float* u  = inst ? u1  : u0;
    const float* Bm = inst ? Bm1 : Bm0;
    const float a = -expf(A_log[((size_t)m * DI + d) * NST + n]);
    const int s0 = chunk * Q;
    const int l0 = dir ? (L - 1 - s0) : s0;
    const int stp = dir ? -1 : 1;
    long iDU = ((long)b * L + l0) * DI + d;
    int  iB  = ((b * L + l0) << 4) + n;
    const long sDU = (long)stp * DI;
    const int  sB  = stp * NST;
    float hc = 0.f, dsum = 0.f;
    #pragma unroll 4
    for (int t = 0; t < Q; ++t) {
        float dlt = dl[iDU], uu = u[iDU], bm = Bm[iB];
        hc = fmaf(__expf(dlt * a), hc, dlt * uu * bm);
        dsum += dlt;
        iDU += sDU; iB += sB;
    }
    hend[(((size_t)(inst * 2 + b) * DI + d) * NC + chunk) * NST + n] = hc;
    if (n == 0) dsumb[((size_t)(inst * 2 + b) * NC + chunk) * DI + d] = dsum;
}

// ---------------------------------------------- scan combine (32 steps)
__global__ __launch_bounds__(256) void combine_kernel(
    const float* __restrict__ hend, const float* __restrict__ dsumb,
    const float* __restrict__ A_log, float* __restrict__ hin, int layer) {
    int flat = blockIdx.x * 256 + threadIdx.x;   // 16384
    int n = flat & 15;
    int d = (flat >> 4) & 255;
    int b = (flat >> 12) & 1;
    int inst = flat >> 13;
    int m = layer * 2 + inst;
    float a = -expf(A_log[((size_t)m * DI + d) * NST + n]);
    size_t baseE = (((size_t)(inst * 2 + b) * DI + d) * NC) * NST + n;
    size_t baseD = ((size_t)(inst * 2 + b) * NC) * DI + d;
    float hc = 0.f;
    for (int c = 0; c < NC; ++c) {
        hin[baseE + (size_t)c * NST] = hc;
        float ds = dsumb[baseD + (size_t)c * DI];
        hc = fmaf(__expf(a * ds), hc, hend[baseE + (size_t)c * NST]);
    }
}

// --------------------------------- scan phase 2: full scan + y + gate(z)
__global__ __launch_bounds__(256) void scan2_kernel(
    const float* __restrict__ dl0, const float* __restrict__ dl1,
    const float* __restrict__ u0,  const float* __restrict__ u1,
    const float* __restrict__ Bm0, const float* __restrict__ Bm1,
    const float* __restrict__ Cm0, const float* __restrict__ Cm1,
    const float* __restrict__ z0,  const float* __restrict__ z1,
    const float* __restrict__ hin, const float* __restrict__ A_log,
    const float* __restrict__ Dp,
    float* __restrict__ yg0, float* __restrict__ yg1, int layer) {
    const int tid = threadIdx.x;
    const int n = tid & 15, dsub = tid >> 4;
    const int chunk = blockIdx.x & 31, dtile = blockIdx.x >> 5;
    const int b = blockIdx.y, inst = blockIdx.z;
    const int m = layer * 2 + inst, dir = inst;
    const int d = dtile * 16 + dsub;
    const float* dl = inst ? dl1 : dl0;
    const float* u  = inst ? u1  : u0;
    const float* Bm = inst ? Bm1 : Bm0;
    const float* Cm = inst ? Cm1 : Cm0;
    const float* z  = inst ? z1  : z0;
    float* yg = inst ? yg1 : yg0;
    const float a = -expf(A_log[((size_t)m * DI + d) * NST + n]);
    const float dpar = Dp[m * DI + d];
    const int s0 = chunk * Q;
    const int l0 = dir ? (L - 1 - s0) : s0;
    const int stp = dir ? -1 : 1;
    long iDU = ((long)b * L + l0) * DI + d;
    int  iB  = ((b * L + l0) << 4) + n;
    const long sDU = (long)stp * DI;
    const int  sB  = stp * NST;
    float hc = hin[(((size_t)(inst * 2 + b) * DI + d) * NC + chunk) * NST + n];
    #pragma unroll 2
    for (int t = 0; t < Q; ++t) {
        float dlt = dl[iDU], uu = u[iDU], bm = Bm[iB], cm = Cm[iB];
        hc = fmaf(__expf(dlt * a), hc, dlt * uu * bm);
        float yp = hc * cm;
        yp += __shfl_xor(yp, 1, 16);
        yp += __shfl_xor(yp, 2, 16);
        yp += __shfl_xor(yp, 4, 16);
        yp += __shfl_xor(yp, 8, 16);
        float zv = z[iDU];
        if (n == 0) {
            yg[iDU] = (yp + uu * dpar) * (zv * sigmoidf_(zv));
        }
        iDU += sDU; iB += sB;
    }
}

// ------------------------------- outproj GEMM (both insts) + residual into h
// BM=32, N=128, K=256 per inst. 256 thr, 2x8 micro.
__global__ __launch_bounds__(256) void outproj_kernel(
    const float* __restrict__ yg0, const float* __restrict__ yg1,
    const float* __restrict__ W_out, float* __restrict__ h, int layer) {
    __shared__ float As[32 * 36];
    __shared__ float Bs[32 * 132];
    const int tid = threadIdx.x;
    const int tBase = blockIdx.x * 32;
    const int m00 = (tid & 15) * 2, n0 = (tid >> 4) * 8;
    float acc[2][8] = {};
    for (int inst = 0; inst < 2; ++inst) {
        const float* yg = inst ? yg1 : yg0;
        const float* Wm = W_out + (size_t)(layer * 2 + inst) * COUT * DI;
        for (int kc = 0; kc < 256; kc += 32) {
            {
                int t = tid >> 3, kq = tid & 7;
                float4 v = *(const float4*)&yg[(size_t)(tBase + t) * DI + kc + kq * 4];
                As[(kq * 4 + 0) * 36 + t] = v.x; As[(kq * 4 + 1) * 36 + t] = v.y;
                As[(kq * 4 + 2) * 36 + t] = v.z; As[(kq * 4 + 3) * 36 + t] = v.w;
                int nr = tid >> 1, kq2 = tid & 1;
                const float* wsrc = Wm + (size_t)nr * DI + kc + kq2 * 16;
                #pragma unroll
                for (int q = 0; q < 4; ++q) {
                    float4 wv = *(const float4*)(wsrc + q * 4);
                    int kk = kq2 * 16 + q * 4;
                    Bs[(kk + 0) * 132 + nr] = wv.x; Bs[(kk + 1) * 132 + nr] = wv.y;
                    Bs[(kk + 2) * 132 + nr] = wv.z; Bs[(kk + 3) * 132 + nr] = wv.w;
                }
            }
            __syncthreads();
            #pragma unroll
            for (int kk = 0; kk < 32; ++kk) {
                float2 av = *(const float2*)&As[kk * 36 + m00];
                float4 b0 = *(const float4*)&Bs[kk * 132 + n0];
                float4 b1 = *(const float4*)&Bs[kk * 132 + n0 + 4];
                acc[0][0] = fmaf(av.x, b0.x, acc[0][0]); acc[0][1] = fmaf(av.x, b0.y, acc[0][1]);
                acc[0][2] = fmaf(av.x, b0.z, acc[0][2]); acc[0][3] = fmaf(av.x, b0.w, acc[0][3]);
                acc[0][4] = fmaf(av.x, b1.x, acc[0][4]); acc[0][5] = fmaf(av.x, b1.y, acc[0][5]);
                acc[0][6] = fmaf(av.x, b1.z, acc[0][6]); acc[0][7] = fmaf(av.x, b1.w, acc[0][7]);
                acc[1][0] = fmaf(av.y, b0.x, acc[1][0]); acc[1][1] = fmaf(av.y, b0.y, acc[1][1]);
                acc[1][2] = fmaf(av.y, b0.z, acc[1][2]); acc[1][3] = fmaf(av.y, b0.w, acc[1][3]);
                acc[1][4] = fmaf(av.y, b1.x, acc[1][4]); acc[1][5] = fmaf(av.y, b1.y, acc[1][5]);
                acc[1][6] = fmaf(av.y, b1.z, acc[1][6]); acc[1][7] = fmaf(av.y, b1.w, acc[1][7]);
            }
            __syncthreads();
        }
    }
    #pragma unroll
    for (int im = 0; im < 2; ++im) {
        size_t row = (size_t)(tBase + m00 + im) * COUT + n0;
        float4 h0 = *(const float4*)&h[row];
        float4 h1 = *(const float4*)&h[row + 4];
        h0.x += acc[im][0]; h0.y += acc[im][1]; h0.z += acc[im][2]; h0.w += acc[im][3];
        h1.x += acc[im][4]; h1.y += acc[im][5]; h1.z += acc[im][6]; h1.w += acc[im][7];
        *(float4*)&h[row] = h0;
        *(float4*)&h[row + 4] = h1;
    }
}

// ------------------------------------------------ final [B,L,C] -> [B,C,L]
__global__ __launch_bounds__(256) void transpose_kernel(
    const float* __restrict__ h, float* __restrict__ out) {
    __shared__ float tile[32][33];
    int lt0 = blockIdx.x * 32, ct0 = blockIdx.y * 32, b = blockIdx.z;
    int c = threadIdx.x & 31, r = threadIdx.x >> 5;
    #pragma unroll
    for (int j = 0; j < 4; ++j) {
        int ll = r + 8 * j;
        tile[ll][c] = h[((size_t)b * L + lt0 + ll) * COUT + ct0 + c];
    }
    __syncthreads();
    #pragma unroll
    for (int j = 0; j < 4; ++j) {
        int cc = r + 8 * j;
        out[((size_t)b * COUT + ct0 + cc) * L + lt0 + c] = tile[c][cc];
    }
}

// ======================================================================
extern "C" void kernel_launch(void* const* d_in, const int* in_sizes, int n_in,
                              void* d_out, int out_size, void* d_ws, size_t ws_size,
                              hipStream_t stream) {
    const float* x        = (const float*)d_in[0];
    const float* conv_w   = (const float*)d_in[1];
    const float* conv_b   = (const float*)d_in[2];
    const float* gn_g     = (const float*)d_in[3];
    const float* gn_b     = (const float*)d_in[4];
    const float* prelu_a  = (const float*)d_in[5];
    const float* ln_g     = (const float*)d_in[6];
    const float* ln_b     = (const float*)d_in[7];
    const float* W_in     = (const float*)d_in[8];
    const float* conv1d_w = (const float*)d_in[9];
    const float* conv1d_b = (const float*)d_in[10];
    const float* W_xproj  = (const float*)d_in[11];
    const float* W_dt     = (const float*)d_in[12];
    const float* b_dt     = (const float*)d_in[13];
    const float* A_log    = (const float*)d_in[14];
    const float* D_param  = (const float*)d_in[15];
    const float* W_out    = (const float*)d_in[16];

    float* ws = (float*)d_ws;
    float* h     = ws;                   // [B,L,128]      1,048,576
    float* hn    = ws + 1048576;         // [B,L,128]  (conv-weight transpose scratch pre-layers)
    float* xp0   = ws + 2097152;         // [B,L,256]  (reused as yg0)
    float* xp1   = ws + 4194304;         //            (reused as yg1)
    float* z0    = ws + 6291456;
    float* z1    = ws + 8388608;
    float* u0    = ws + 10485760;
    float* u1    = ws + 12582912;
    float* dl0   = ws + 14680064;
    float* dl1   = ws + 16777216;
    float* Bm0   = ws + 18874368;        // [B,L,16]
    float* Bm1   = ws + 19005440;
    float* Cm0   = ws + 19136512;
    float* Cm1   = ws + 19267584;
    float* hend  = ws + 19398656;        // [2,B,256,32,16]
    float* hin   = ws + 19922944;
    float* dsumb = ws + 20447232;        // [2,B,32,256]
    float* stats = ws + 20480000;        // [4]
    float* Wt    = hn;                   // [320,128] — hn unused until ln_kernel

    zero_stats_kernel<<<1, 64, 0, stream>>>(stats);
    transpose_w_kernel<<<160, 256, 0, stream>>>(conv_w, Wt);
    conv_gemm_kernel<<<dim3(TOK / 64, COUT / 64), 256, 0, stream>>>(x, Wt, conv_b, h, stats);
    gn_prelu_kernel<<<(TOK * COUT / 4) / 256, 256, 0, stream>>>(h, gn_g, gn_b, prelu_a, stats);

    for (int layer = 0; layer < 2; ++layer) {
        ln_kernel<<<TOK / 4, 256, 0, stream>>>(h, hn, ln_g + layer * COUT, ln_b + layer * COUT);
        inproj_kernel<<<dim3(TOK / 64, 16), 256, 0, stream>>>(hn, W_in, xp0, z0, xp1, z1, layer);
        dwconv_kernel<<<(2 * B2 * L * DI) / 256, 256, 0, stream>>>(xp0, xp1, conv1d_w, conv1d_b, u0, u1, layer);
        xproj_kernel<<<dim3(TOK / 32, 2), 256, 0, stream>>>(u0, u1, W_xproj, W_dt, b_dt,
                                                            dl0, dl1, Bm0, Bm1, Cm0, Cm1, layer);
        scan1_kernel<<<dim3(NC * 16, B2, 2), 256, 0, stream>>>(dl0, dl1, u0, u1, Bm0, Bm1,
                                                               A_log, hend, dsumb, layer);
        combine_kernel<<<64, 256, 0, stream>>>(hend, dsumb, A_log, hin, layer);
        scan2_kernel<<<dim3(NC * 16, B2, 2), 256, 0, stream>>>(dl0, dl1, u0, u1, Bm0, Bm1, Cm0, Cm1,
                                                               z0, z1, hin, A_log, D_param,
                                                               xp0, xp1, layer);
        outproj_kernel<<<TOK / 32, 256, 0, stream>>>(xp0, xp1, W_out, h, layer);
    }
    transpose_kernel<<<dim3(L / 32, COUT / 32, B2), 256, 0, stream>>>(h, (float*)d_out);
}

// Round 3
// 582.529 us; speedup vs baseline: 1.3208x; 1.2227x over previous
//
#include <hip/hip_runtime.h>
#include <hip/hip_bf16.h>
#include <math.h>

// ---- problem dims ----
constexpr int B2   = 2;
constexpr int CIN  = 64;
constexpr int COUT = 128;
constexpr int T    = 8192;
constexpr int L    = 4096;     // T/2
constexpr int DI   = 256;
constexpr int NST  = 16;       // d_state
constexpr int DTR  = 8;
constexpr int Q    = 64;       // scan chunk length
constexpr int NC   = 64;       // L / Q
constexpr int TOK  = B2 * L;   // 8192 tokens

__device__ __forceinline__ float sigmoidf_(float x) { return 1.f / (1.f + __expf(-x)); }

// ---------------------------------------------------------------- zero stats
__global__ __launch_bounds__(64) void zero_stats_kernel(float* stats) {
    if (threadIdx.x < 4) stats[threadIdx.x] = 0.f;
}

// ------------------------------------------- conv weight transpose [128][320] -> [320][128]
__global__ __launch_bounds__(256) void transpose_w_kernel(
    const float* __restrict__ cw, float* __restrict__ Wt) {
    int idx = blockIdx.x * 256 + threadIdx.x;   // 40960
    int c = idx & 127, kidx = idx >> 7;
    Wt[(size_t)kidx * COUT + c] = cw[(size_t)c * 320 + kidx];
}

// ------------------------------------- conv1d stride2 as implicit-im2col GEMM + GN stats
__global__ __launch_bounds__(256) void conv_gemm_kernel(
    const float* __restrict__ x, const float* __restrict__ Wt,
    const float* __restrict__ cb, float* __restrict__ h, float* __restrict__ stats) {
    __shared__ float As[32 * 68];
    __shared__ float Bs[32 * 68];
    const int tid = threadIdx.x;
    const int t0  = blockIdx.x * 64;            // flat token base (b*L + l)
    const int ct0 = blockIdx.y * 64;
    const int b   = t0 >> 12;                   // L = 4096
    const int l0  = t0 & (L - 1);
    const float* xb = x + (size_t)b * CIN * T;
    const int m0 = (tid & 15) * 4;
    const int n0 = (tid >> 4) * 4;
    float acc[4][4] = {};
    for (int kc = 0; kc < 320; kc += 32) {
        #pragma unroll
        for (int i = 0; i < 8; ++i) {
            int idx = i * 256 + tid;            // 2048 = 32 kk x 64 t
            int kk = idx >> 6, t = idx & 63;
            int K = kc + kk;
            int ci = K / 5, k = K - ci * 5;
            int p = 2 * (l0 + t) + k - 2;
            float v = (p >= 0 && p < T) ? xb[(size_t)ci * T + p] : 0.f;
            As[kk * 68 + t] = v;
            Bs[kk * 68 + t] = Wt[(size_t)K * COUT + ct0 + t];
        }
        __syncthreads();
        #pragma unroll
        for (int kk = 0; kk < 32; ++kk) {
            float4 a = *(const float4*)&As[kk * 68 + m0];
            float4 bb = *(const float4*)&Bs[kk * 68 + n0];
            acc[0][0] = fmaf(a.x, bb.x, acc[0][0]); acc[0][1] = fmaf(a.x, bb.y, acc[0][1]);
            acc[0][2] = fmaf(a.x, bb.z, acc[0][2]); acc[0][3] = fmaf(a.x, bb.w, acc[0][3]);
            acc[1][0] = fmaf(a.y, bb.x, acc[1][0]); acc[1][1] = fmaf(a.y, bb.y, acc[1][1]);
            acc[1][2] = fmaf(a.y, bb.z, acc[1][2]); acc[1][3] = fmaf(a.y, bb.w, acc[1][3]);
            acc[2][0] = fmaf(a.z, bb.x, acc[2][0]); acc[2][1] = fmaf(a.z, bb.y, acc[2][1]);
            acc[2][2] = fmaf(a.z, bb.z, acc[2][2]); acc[2][3] = fmaf(a.z, bb.w, acc[2][3]);
            acc[3][0] = fmaf(a.w, bb.x, acc[3][0]); acc[3][1] = fmaf(a.w, bb.y, acc[3][1]);
            acc[3][2] = fmaf(a.w, bb.z, acc[3][2]); acc[3][3] = fmaf(a.w, bb.w, acc[3][3]);
        }
        __syncthreads();
    }
    float4 bias = *(const float4*)&cb[ct0 + n0];
    float s = 0.f, ss = 0.f;
    #pragma unroll
    for (int im = 0; im < 4; ++im) {
        float4 v = make_float4(acc[im][0] + bias.x, acc[im][1] + bias.y,
                               acc[im][2] + bias.z, acc[im][3] + bias.w);
        *(float4*)&h[(size_t)(t0 + m0 + im) * COUT + ct0 + n0] = v;
        s  += v.x + v.y + v.z + v.w;
        ss += v.x * v.x + v.y * v.y + v.z * v.z + v.w * v.w;
    }
    #pragma unroll
    for (int off = 32; off; off >>= 1) {
        s  += __shfl_down(s,  off, 64);
        ss += __shfl_down(ss, off, 64);
    }
    if ((tid & 63) == 0) {
        atomicAdd(&stats[b * 2 + 0], s);
        atomicAdd(&stats[b * 2 + 1], ss);
    }
}

// ------------------------------------------------------ GN apply + PReLU
__global__ __launch_bounds__(256) void gn_prelu_kernel(
    float* __restrict__ h, const float* __restrict__ gn_g,
    const float* __restrict__ gn_b, const float* __restrict__ prelu_a,
    const float* __restrict__ stats) {
    int i = blockIdx.x * 256 + threadIdx.x;      // 262144 threads, x4 elements
    size_t base = (size_t)i * 4;
    int b = (base >= (size_t)L * COUT) ? 1 : 0;
    const float n = (float)(L * COUT);
    float mu   = stats[b * 2 + 0] / n;
    float var  = stats[b * 2 + 1] / n - mu * mu;
    float rstd = rsqrtf(var + 1e-5f);
    float a = prelu_a[0];
    float4 v = *(const float4*)&h[base];
    int c = (int)(base % COUT);
    float4 g  = *(const float4*)&gn_g[c];
    float4 bb = *(const float4*)&gn_b[c];
    v.x = (v.x - mu) * rstd * g.x + bb.x; v.x = v.x >= 0.f ? v.x : a * v.x;
    v.y = (v.y - mu) * rstd * g.y + bb.y; v.y = v.y >= 0.f ? v.y : a * v.y;
    v.z = (v.z - mu) * rstd * g.z + bb.z; v.z = v.z >= 0.f ? v.z : a * v.z;
    v.w = (v.w - mu) * rstd * g.w + bb.w; v.w = v.w >= 0.f ? v.w : a * v.w;
    *(float4*)&h[base] = v;
}

// ------------------------------------------------------ per-token LayerNorm
__global__ __launch_bounds__(256) void ln_kernel(
    const float* __restrict__ h, float* __restrict__ hn,
    const float* __restrict__ g, const float* __restrict__ bta) {
    int wave = threadIdx.x >> 6, lane = threadIdx.x & 63;
    int t = blockIdx.x * 4 + wave;
    const float* row = h + (size_t)t * COUT;
    float2 v = *(const float2*)&row[lane * 2];
    float s = v.x + v.y, ss = v.x * v.x + v.y * v.y;
    #pragma unroll
    for (int off = 32; off; off >>= 1) {
        s  += __shfl_xor(s,  off, 64);
        ss += __shfl_xor(ss, off, 64);
    }
    float mu = s * (1.f / 128.f);
    float var = ss * (1.f / 128.f) - mu * mu;
    float rstd = rsqrtf(var + 1e-5f);
    float2 gg = *(const float2*)&g[lane * 2];
    float2 bb = *(const float2*)&bta[lane * 2];
    float2 o;
    o.x = (v.x - mu) * rstd * gg.x + bb.x;
    o.y = (v.y - mu) * rstd * gg.y + bb.y;
    *(float2*)&hn[(size_t)t * COUT + lane * 2] = o;
}

// ------------------------------------------------- inproj GEMM  M=8192 K=128
// z-half gets SiLU applied in epilogue (gate is only ever used as silu(z)).
__global__ __launch_bounds__(256) void inproj_kernel(
    const float* __restrict__ hn, const float* __restrict__ W_in,
    float* __restrict__ xp0, float* __restrict__ z0,
    float* __restrict__ xp1, float* __restrict__ z1, int layer) {
    __shared__ float As[32 * 68];
    __shared__ float Bs[32 * 68];
    const int tid   = threadIdx.x;
    const int tBase = blockIdx.x * 64;
    const int nBase = blockIdx.y * 64;
    const int inst  = nBase >> 9;
    const int e0    = nBase & 511;
    const int m     = layer * 2 + inst;
    const float* Wm = W_in + ((size_t)m * 512 + e0) * 128;
    const int mrow = tid >> 2;      // 0..63
    const int kq   = tid & 3;       // 0..3
    const int m0   = (tid & 15) * 4;
    const int n0   = (tid >> 4) * 4;
    float acc[4][4] = {};
    for (int kc = 0; kc < 128; kc += 32) {
        {
            const float* srcA = hn + (size_t)(tBase + mrow) * 128 + kc + kq * 8;
            float4 a0 = *(const float4*)srcA;
            float4 a1 = *(const float4*)(srcA + 4);
            int kk = kq * 8;
            As[(kk + 0) * 68 + mrow] = a0.x; As[(kk + 1) * 68 + mrow] = a0.y;
            As[(kk + 2) * 68 + mrow] = a0.z; As[(kk + 3) * 68 + mrow] = a0.w;
            As[(kk + 4) * 68 + mrow] = a1.x; As[(kk + 5) * 68 + mrow] = a1.y;
            As[(kk + 6) * 68 + mrow] = a1.z; As[(kk + 7) * 68 + mrow] = a1.w;
            const float* srcB = Wm + (size_t)mrow * 128 + kc + kq * 8;
            float4 b0 = *(const float4*)srcB;
            float4 b1 = *(const float4*)(srcB + 4);
            Bs[(kk + 0) * 68 + mrow] = b0.x; Bs[(kk + 1) * 68 + mrow] = b0.y;
            Bs[(kk + 2) * 68 + mrow] = b0.z; Bs[(kk + 3) * 68 + mrow] = b0.w;
            Bs[(kk + 4) * 68 + mrow] = b1.x; Bs[(kk + 5) * 68 + mrow] = b1.y;
            Bs[(kk + 6) * 68 + mrow] = b1.z; Bs[(kk + 7) * 68 + mrow] = b1.w;
        }
        __syncthreads();
        #pragma unroll
        for (int kk = 0; kk < 32; ++kk) {
            float4 a = *(const float4*)&As[kk * 68 + m0];
            float4 b = *(const float4*)&Bs[kk * 68 + n0];
            acc[0][0] = fmaf(a.x, b.x, acc[0][0]); acc[0][1] = fmaf(a.x, b.y, acc[0][1]);
            acc[0][2] = fmaf(a.x, b.z, acc[0][2]); acc[0][3] = fmaf(a.x, b.w, acc[0][3]);
            acc[1][0] = fmaf(a.y, b.x, acc[1][0]); acc[1][1] = fmaf(a.y, b.y, acc[1][1]);
            acc[1][2] = fmaf(a.y, b.z, acc[1][2]); acc[1][3] = fmaf(a.y, b.w, acc[1][3]);
            acc[2][0] = fmaf(a.z, b.x, acc[2][0]); acc[2][1] = fmaf(a.z, b.y, acc[2][1]);
            acc[2][2] = fmaf(a.z, b.z, acc[2][2]); acc[2][3] = fmaf(a.z, b.w, acc[2][3]);
            acc[3][0] = fmaf(a.w, b.x, acc[3][0]); acc[3][1] = fmaf(a.w, b.y, acc[3][1]);
            acc[3][2] = fmaf(a.w, b.z, acc[3][2]); acc[3][3] = fmaf(a.w, b.w, acc[3][3]);
        }
        __syncthreads();
    }
    const bool isz = (e0 >= 256);
    float* dst; int eoff;
    if (!isz) { dst = inst ? xp1 : xp0; eoff = e0; }
    else      { dst = inst ? z1  : z0;  eoff = e0 - 256; }
    #pragma unroll
    for (int im = 0; im < 4; ++im) {
        float4 v = make_float4(acc[im][0], acc[im][1], acc[im][2], acc[im][3]);
        if (isz) {
            v.x *= sigmoidf_(v.x); v.y *= sigmoidf_(v.y);
            v.z *= sigmoidf_(v.z); v.w *= sigmoidf_(v.w);
        }
        *(float4*)&dst[(size_t)(tBase + m0 + im) * DI + eoff + n0] = v;
    }
}

// ---------------------------------------- depthwise causal conv (d=4) + SiLU
__global__ __launch_bounds__(256) void dwconv_kernel(
    const float* __restrict__ xp0, const float* __restrict__ xp1,
    const float* __restrict__ cw, const float* __restrict__ cbias,
    float* __restrict__ u0, float* __restrict__ u1, int layer) {
    int flat = blockIdx.x * 256 + threadIdx.x;
    int d    = flat & 255;
    int l    = (flat >> 8) & (L - 1);
    int b    = (flat >> 20) & 1;
    int inst = flat >> 21;
    const float* xp = inst ? xp1 : xp0;
    float* u = inst ? u1 : u0;
    int m = layer * 2 + inst;
    const float4 w4 = *(const float4*)&cw[(size_t)(m * DI + d) * 4];
    float acc = cbias[m * DI + d];
    size_t base = ((size_t)b * L) * DI + d;
    if (inst == 0) {  // forward: taps l-3..l, weights w[0]..w[3]
        if (l - 3 >= 0) acc = fmaf(w4.x, xp[base + (size_t)(l - 3) * DI], acc);
        if (l - 2 >= 0) acc = fmaf(w4.y, xp[base + (size_t)(l - 2) * DI], acc);
        if (l - 1 >= 0) acc = fmaf(w4.z, xp[base + (size_t)(l - 1) * DI], acc);
        acc = fmaf(w4.w, xp[base + (size_t)l * DI], acc);
    } else {          // backward (natural coords): taps l..l+3, w[3]..w[0]
        acc = fmaf(w4.w, xp[base + (size_t)l * DI], acc);
        if (l + 1 < L) acc = fmaf(w4.z, xp[base + (size_t)(l + 1) * DI], acc);
        if (l + 2 < L) acc = fmaf(w4.y, xp[base + (size_t)(l + 2) * DI], acc);
        if (l + 3 < L) acc = fmaf(w4.x, xp[base + (size_t)(l + 3) * DI], acc);
    }
    u[base + (size_t)l * DI] = acc * sigmoidf_(acc);
}

// ------------------------------------- xproj (u->dt,B,C) + dt-proj + softplus
__global__ __launch_bounds__(256) void xproj_kernel(
    const float* __restrict__ u0, const float* __restrict__ u1,
    const float* __restrict__ Wx, const float* __restrict__ Wdt,
    const float* __restrict__ bdt,
    float* __restrict__ dl0, float* __restrict__ dl1,
    float* __restrict__ Bm0, float* __restrict__ Bm1,
    float* __restrict__ Cm0, float* __restrict__ Cm1, int layer) {
    __shared__ float Us[32 * 261];
    __shared__ float xd[32 * 45];
    const int tid   = threadIdx.x;
    const int tBase = blockIdx.x * 32;
    const int inst  = blockIdx.y;
    const int m     = layer * 2 + inst;
    const float* u = inst ? u1 : u0;
    for (int idx = tid; idx < 32 * 256; idx += 256) {
        int t = idx >> 8, k = idx & 255;
        Us[t * 261 + k] = u[(size_t)(tBase + t) * DI + k];
    }
    __syncthreads();
    {
        int t = tid & 31, eq = tid >> 5;
        float* Bm = inst ? Bm1 : Bm0;
        float* Cm = inst ? Cm1 : Cm0;
        #pragma unroll
        for (int j = 0; j < 5; ++j) {
            int e = eq + 8 * j;
            const float* wr = Wx + ((size_t)m * 40 + e) * 256;
            const float* ur = &Us[t * 261];
            float acc = 0.f;
            #pragma unroll 4
            for (int k = 0; k < 256; ++k) acc = fmaf(ur[k], wr[k], acc);
            if (e < 8)        xd[t * 45 + e] = acc;
            else if (e < 24)  Bm[(size_t)(tBase + t) * NST + (e - 8)]  = acc;
            else              Cm[(size_t)(tBase + t) * NST + (e - 24)] = acc;
        }
    }
    __syncthreads();
    {
        int d = tid;
        float wr[8];
        #pragma unroll
        for (int r = 0; r < 8; ++r) wr[r] = Wdt[((size_t)m * DI + d) * DTR + r];
        float bb = bdt[m * DI + d];
        float* dl = inst ? dl1 : dl0;
        for (int t = 0; t < 32; ++t) {
            float acc = bb;
            #pragma unroll
            for (int r = 0; r < 8; ++r) acc = fmaf(xd[t * 45 + r], wr[r], acc);
            float sp = (acc > 15.f) ? acc : log1pf(expf(acc));   // softplus
            dl[(size_t)(tBase + t) * DI + d] = sp;
        }
    }
}

// ---------------------------------------------- scan phase 1: chunk-local
// thread = (nq 0..3, dlane 0..63); block covers 64 d of one chunk.
// grid (NC * DI/64, B, inst). 4 states per thread in registers.
__global__ __launch_bounds__(256) void scan1_kernel(
    const float* __restrict__ dl0, const float* __restrict__ dl1,
    const float* __restrict__ u0,  const float* __restrict__ u1,
    const float* __restrict__ Bm0, const float* __restrict__ Bm1,
    const float* __restrict__ A_log,
    float* __restrict__ hend, float* __restrict__ dsumb, int layer) {
    const int tid = threadIdx.x;
    const int nq = tid & 3, dlane = tid >> 2;
    const int chunk = blockIdx.x & (NC - 1), dtile = blockIdx.x >> 6;
    const int b = blockIdx.y, inst = blockIdx.z;
    const int m = layer * 2 + inst, dir = inst;
    const int d = dtile * 64 + dlane;
    const float* dl = inst ? dl1 : dl0;
    const float* u  = inst ? u1  : u0;
    const float* Bm = inst ? Bm1 : Bm0;
    float4 av = *(const float4*)&A_log[((size_t)m * DI + d) * NST + nq * 4];
    const float a0 = -expf(av.x), a1 = -expf(av.y), a2 = -expf(av.z), a3 = -expf(av.w);
    const int s0 = chunk * Q;
    const int l0 = dir ? (L - 1 - s0) : s0;
    const int stp = dir ? -1 : 1;
    long iDU = ((long)(b * L + l0)) * DI + d;
    int  iB  = ((b * L + l0) << 4) + nq * 4;
    const long sDU = (long)stp * DI;
    const int  sB  = stp * NST;
    float h0 = 0.f, h1 = 0.f, h2 = 0.f, h3 = 0.f, dsum = 0.f;
    #pragma unroll 4
    for (int t = 0; t < Q; ++t) {
        float dlt = dl[iDU], uu = u[iDU];
        float4 bm = *(const float4*)&Bm[iB];
        float du = dlt * uu;
        h0 = fmaf(__expf(dlt * a0), h0, du * bm.x);
        h1 = fmaf(__expf(dlt * a1), h1, du * bm.y);
        h2 = fmaf(__expf(dlt * a2), h2, du * bm.z);
        h3 = fmaf(__expf(dlt * a3), h3, du * bm.w);
        dsum += dlt;
        iDU += sDU; iB += sB;
    }
    size_t oh = (((size_t)(inst * 2 + b) * DI + d) * NC + chunk) * NST + nq * 4;
    *(float4*)&hend[oh] = make_float4(h0, h1, h2, h3);
    if (nq == 0) dsumb[((size_t)(inst * 2 + b) * NC + chunk) * DI + d] = dsum;
}

// ---------------------------------------------- scan combine (in-place prefix)
// hend[c] -> prefix-state before chunk c. One thread per (inst,b,d,n).
__global__ __launch_bounds__(256) void combine_kernel(
    float* __restrict__ hend, const float* __restrict__ dsumb,
    const float* __restrict__ A_log, int layer) {
    int flat = blockIdx.x * 256 + threadIdx.x;   // 16384
    int n = flat & 15;
    int d = (flat >> 4) & 255;
    int b = (flat >> 12) & 1;
    int inst = flat >> 13;
    int m = layer * 2 + inst;
    float a = -expf(A_log[((size_t)m * DI + d) * NST + n]);
    size_t baseE = (((size_t)(inst * 2 + b) * DI + d) * NC) * NST + n;
    size_t baseD = ((size_t)(inst * 2 + b) * NC) * DI + d;
    float hc = 0.f;
    for (int c = 0; c < NC; ++c) {
        float tmp = hend[baseE + (size_t)c * NST];
        hend[baseE + (size_t)c * NST] = hc;
        float ds = dsumb[baseD + (size_t)c * DI];
        hc = fmaf(__expf(a * ds), hc, tmp);
    }
}

// --------------------------------- scan phase 2: full scan + y + gate
// Same thread layout as scan1; y reduced over the 4-lane n-quad group.
__global__ __launch_bounds__(256) void scan2_kernel(
    const float* __restrict__ dl0, const float* __restrict__ dl1,
    const float* __restrict__ u0,  const float* __restrict__ u1,
    const float* __restrict__ Bm0, const float* __restrict__ Bm1,
    const float* __restrict__ Cm0, const float* __restrict__ Cm1,
    const float* __restrict__ zs0, const float* __restrict__ zs1,
    const float* __restrict__ hin, const float* __restrict__ A_log,
    const float* __restrict__ Dp,
    float* __restrict__ yg0, float* __restrict__ yg1, int layer) {
    const int tid = threadIdx.x;
    const int nq = tid & 3, dlane = tid >> 2;
    const int chunk = blockIdx.x & (NC - 1), dtile = blockIdx.x >> 6;
    const int b = blockIdx.y, inst = blockIdx.z;
    const int m = layer * 2 + inst, dir = inst;
    const int d = dtile * 64 + dlane;
    const float* dl = inst ? dl1 : dl0;
    const float* u  = inst ? u1  : u0;
    const float* Bm = inst ? Bm1 : Bm0;
    const float* Cm = inst ? Cm1 : Cm0;
    const float* zs = inst ? zs1 : zs0;
    float* yg = inst ? yg1 : yg0;
    float4 av = *(const float4*)&A_log[((size_t)m * DI + d) * NST + nq * 4];
    const float a0 = -expf(av.x), a1 = -expf(av.y), a2 = -expf(av.z), a3 = -expf(av.w);
    const float dpar = Dp[m * DI + d];
    const int s0 = chunk * Q;
    const int l0 = dir ? (L - 1 - s0) : s0;
    const int stp = dir ? -1 : 1;
    long iDU = ((long)(b * L + l0)) * DI + d;
    int  iB  = ((b * L + l0) << 4) + nq * 4;
    const long sDU = (long)stp * DI;
    const int  sB  = stp * NST;
    float4 hv = *(const float4*)&hin[(((size_t)(inst * 2 + b) * DI + d) * NC + chunk) * NST + nq * 4];
    float h0 = hv.x, h1 = hv.y, h2 = hv.z, h3 = hv.w;
    #pragma unroll 4
    for (int t = 0; t < Q; ++t) {
        float dlt = dl[iDU], uu = u[iDU];
        float4 bm = *(const float4*)&Bm[iB];
        float4 cm = *(const float4*)&Cm[iB];
        float du = dlt * uu;
        h0 = fmaf(__expf(dlt * a0), h0, du * bm.x);
        h1 = fmaf(__expf(dlt * a1), h1, du * bm.y);
        h2 = fmaf(__expf(dlt * a2), h2, du * bm.z);
        h3 = fmaf(__expf(dlt * a3), h3, du * bm.w);
        float yp = h0 * cm.x + h1 * cm.y + h2 * cm.z + h3 * cm.w;
        yp += __shfl_xor(yp, 1, 4);
        yp += __shfl_xor(yp, 2, 4);
        if (nq == 0) {
            float zv = zs[iDU];
            yg[iDU] = fmaf(uu, dpar, yp) * zv;
        }
        iDU += sDU; iB += sB;
    }
}

// ------------------------------- outproj GEMM (both insts) + residual into h
__global__ __launch_bounds__(256) void outproj_kernel(
    const float* __restrict__ yg0, const float* __restrict__ yg1,
    const float* __restrict__ W_out, float* __restrict__ h, int layer) {
    __shared__ float As[32 * 36];
    __shared__ float Bs[32 * 132];
    const int tid = threadIdx.x;
    const int tBase = blockIdx.x * 32;
    const int m00 = (tid & 15) * 2, n0 = (tid >> 4) * 8;
    float acc[2][8] = {};
    for (int inst = 0; inst < 2; ++inst) {
        const float* yg = inst ? yg1 : yg0;
        const float* Wm = W_out + (size_t)(layer * 2 + inst) * COUT * DI;
        for (int kc = 0; kc < 256; kc += 32) {
            {
                int t = tid >> 3, kq = tid & 7;
                float4 v = *(const float4*)&yg[(size_t)(tBase + t) * DI + kc + kq * 4];
                As[(kq * 4 + 0) * 36 + t] = v.x; As[(kq * 4 + 1) * 36 + t] = v.y;
                As[(kq * 4 + 2) * 36 + t] = v.z; As[(kq * 4 + 3) * 36 + t] = v.w;
                int nr = tid >> 1, kq2 = tid & 1;
                const float* wsrc = Wm + (size_t)nr * DI + kc + kq2 * 16;
                #pragma unroll
                for (int q = 0; q < 4; ++q) {
                    float4 wv = *(const float4*)(wsrc + q * 4);
                    int kk = kq2 * 16 + q * 4;
                    Bs[(kk + 0) * 132 + nr] = wv.x; Bs[(kk + 1) * 132 + nr] = wv.y;
                    Bs[(kk + 2) * 132 + nr] = wv.z; Bs[(kk + 3) * 132 + nr] = wv.w;
                }
            }
            __syncthreads();
            #pragma unroll
            for (int kk = 0; kk < 32; ++kk) {
                float2 av = *(const float2*)&As[kk * 36 + m00];
                float4 b0 = *(const float4*)&Bs[kk * 132 + n0];
                float4 b1 = *(const float4*)&Bs[kk * 132 + n0 + 4];
                acc[0][0] = fmaf(av.x, b0.x, acc[0][0]); acc[0][1] = fmaf(av.x, b0.y, acc[0][1]);
                acc[0][2] = fmaf(av.x, b0.z, acc[0][2]); acc[0][3] = fmaf(av.x, b0.w, acc[0][3]);
                acc[0][4] = fmaf(av.x, b1.x, acc[0][4]); acc[0][5] = fmaf(av.x, b1.y, acc[0][5]);
                acc[0][6] = fmaf(av.x, b1.z, acc[0][6]); acc[0][7] = fmaf(av.x, b1.w, acc[0][7]);
                acc[1][0] = fmaf(av.y, b0.x, acc[1][0]); acc[1][1] = fmaf(av.y, b0.y, acc[1][1]);
                acc[1][2] = fmaf(av.y, b0.z, acc[1][2]); acc[1][3] = fmaf(av.y, b0.w, acc[1][3]);
                acc[1][4] = fmaf(av.y, b1.x, acc[1][4]); acc[1][5] = fmaf(av.y, b1.y, acc[1][5]);
                acc[1][6] = fmaf(av.y, b1.z, acc[1][6]); acc[1][7] = fmaf(av.y, b1.w, acc[1][7]);
            }
            __syncthreads();
        }
    }
    #pragma unroll
    for (int im = 0; im < 2; ++im) {
        size_t row = (size_t)(tBase + m00 + im) * COUT + n0;
        float4 h0 = *(const float4*)&h[row];
        float4 h1 = *(const float4*)&h[row + 4];
        h0.x += acc[im][0]; h0.y += acc[im][1]; h0.z += acc[im][2]; h0.w += acc[im][3];
        h1.x += acc[im][4]; h1.y += acc[im][5]; h1.z += acc[im][6]; h1.w += acc[im][7];
        *(float4*)&h[row] = h0;
        *(float4*)&h[row + 4] = h1;
    }
}

// ------------------------------------------------ final [B,L,C] -> [B,C,L]
__global__ __launch_bounds__(256) void transpose_kernel(
    const float* __restrict__ h, float* __restrict__ out) {
    __shared__ float tile[32][33];
    int lt0 = blockIdx.x * 32, ct0 = blockIdx.y * 32, b = blockIdx.z;
    int c = threadIdx.x & 31, r = threadIdx.x >> 5;
    #pragma unroll
    for (int j = 0; j < 4; ++j) {
        int ll = r + 8 * j;
        tile[ll][c] = h[((size_t)b * L + lt0 + ll) * COUT + ct0 + c];
    }
    __syncthreads();
    #pragma unroll
    for (int j = 0; j < 4; ++j) {
        int cc = r + 8 * j;
        out[((size_t)b * COUT + ct0 + cc) * L + lt0 + c] = tile[c][cc];
    }
}

// ======================================================================
extern "C" void kernel_launch(void* const* d_in, const int* in_sizes, int n_in,
                              void* d_out, int out_size, void* d_ws, size_t ws_size,
                              hipStream_t stream) {
    const float* x        = (const float*)d_in[0];
    const float* conv_w   = (const float*)d_in[1];
    const float* conv_b   = (const float*)d_in[2];
    const float* gn_g     = (const float*)d_in[3];
    const float* gn_b     = (const float*)d_in[4];
    const float* prelu_a  = (const float*)d_in[5];
    const float* ln_g     = (const float*)d_in[6];
    const float* ln_b     = (const float*)d_in[7];
    const float* W_in     = (const float*)d_in[8];
    const float* conv1d_w = (const float*)d_in[9];
    const float* conv1d_b = (const float*)d_in[10];
    const float* W_xproj  = (const float*)d_in[11];
    const float* W_dt     = (const float*)d_in[12];
    const float* b_dt     = (const float*)d_in[13];
    const float* A_log    = (const float*)d_in[14];
    const float* D_param  = (const float*)d_in[15];
    const float* W_out    = (const float*)d_in[16];

    float* ws = (float*)d_ws;
    float* h     = ws;                   // [B,L,128]
    float* hn    = ws + 1048576;         // [B,L,128] (aliased: Wt pre-loop, dsumb during scans)
    float* xp0   = ws + 2097152;         // [B,L,256] (reused as yg0)
    float* xp1   = ws + 4194304;         //           (reused as yg1)
    float* z0    = ws + 6291456;         // silu(z) from inproj epilogue
    float* z1    = ws + 8388608;
    float* u0    = ws + 10485760;
    float* u1    = ws + 12582912;
    float* dl0   = ws + 14680064;
    float* dl1   = ws + 16777216;
    float* Bm0   = ws + 18874368;        // [B,L,16]
    float* Bm1   = ws + 19005440;
    float* Cm0   = ws + 19136512;
    float* Cm1   = ws + 19267584;
    float* hend  = ws + 19398656;        // [2,B,256,NC,16] = 1,048,576 (prefix in-place)
    float* stats = ws + 20447232;        // [4]
    float* Wt    = hn;                   // [320,128]
    float* dsumb = hn;                   // [2,B,NC,256] = 65,536 (hn dead during scans)

    zero_stats_kernel<<<1, 64, 0, stream>>>(stats);
    transpose_w_kernel<<<160, 256, 0, stream>>>(conv_w, Wt);
    conv_gemm_kernel<<<dim3(TOK / 64, COUT / 64), 256, 0, stream>>>(x, Wt, conv_b, h, stats);
    gn_prelu_kernel<<<(TOK * COUT / 4) / 256, 256, 0, stream>>>(h, gn_g, gn_b, prelu_a, stats);

    for (int layer = 0; layer < 2; ++layer) {
        ln_kernel<<<TOK / 4, 256, 0, stream>>>(h, hn, ln_g + layer * COUT, ln_b + layer * COUT);
        inproj_kernel<<<dim3(TOK / 64, 16), 256, 0, stream>>>(hn, W_in, xp0, z0, xp1, z1, layer);
        dwconv_kernel<<<(2 * B2 * L * DI) / 256, 256, 0, stream>>>(xp0, xp1, conv1d_w, conv1d_b, u0, u1, layer);
        xproj_kernel<<<dim3(TOK / 32, 2), 256, 0, stream>>>(u0, u1, W_xproj, W_dt, b_dt,
                                                            dl0, dl1, Bm0, Bm1, Cm0, Cm1, layer);
        scan1_kernel<<<dim3(NC * 4, B2, 2), 256, 0, stream>>>(dl0, dl1, u0, u1, Bm0, Bm1,
                                                              A_log, hend, dsumb, layer);
        combine_kernel<<<64, 256, 0, stream>>>(hend, dsumb, A_log, layer);
        scan2_kernel<<<dim3(NC * 4, B2, 2), 256, 0, stream>>>(dl0, dl1, u0, u1, Bm0, Bm1, Cm0, Cm1,
                                                              z0, z1, hend, A_log, D_param,
                                                              xp0, xp1, layer);
        outproj_kernel<<<TOK / 32, 256, 0, stream>>>(xp0, xp1, W_out, h, layer);
    }
    transpose_kernel<<<dim3(L / 32, COUT / 32, B2), 256, 0, stream>>>(h, (float*)d_out);
}

// Round 6
// 559.863 us; speedup vs baseline: 1.3742x; 1.0405x over previous
//
#include <hip/hip_runtime.h>
#include <hip/hip_bf16.h>
#include <math.h>

// ---- problem dims ----
constexpr int B2   = 2;
constexpr int CIN  = 64;
constexpr int COUT = 128;
constexpr int T    = 8192;
constexpr int L    = 4096;     // T/2
constexpr int DI   = 256;
constexpr int NST  = 16;       // d_state
constexpr int DTR  = 8;
constexpr int Q    = 64;       // scan chunk length
constexpr int NC   = 64;       // L / Q
constexpr int TOK  = B2 * L;   // 8192 tokens

__device__ __forceinline__ float sigmoidf_(float x) { return 1.f / (1.f + __expf(-x)); }

// ---------------------------------------------------------------- zero stats
__global__ __launch_bounds__(64) void zero_stats_kernel(float* stats) {
    if (threadIdx.x < 4) stats[threadIdx.x] = 0.f;
}

// ------------------------------------------- conv weight transpose [128][320] -> [320][128]
__global__ __launch_bounds__(256) void transpose_w_kernel(
    const float* __restrict__ cw, float* __restrict__ Wt) {
    int idx = blockIdx.x * 256 + threadIdx.x;   // 40960
    int c = idx & 127, kidx = idx >> 7;
    Wt[(size_t)kidx * COUT + c] = cw[(size_t)c * 320 + kidx];
}

// ------------------------------------- conv1d stride2 as implicit-im2col GEMM + GN stats
// 32 tok x 32 cout tiles -> 1024 blocks (latency hiding via block oversubscription).
__global__ __launch_bounds__(256) void conv_gemm_kernel(
    const float* __restrict__ x, const float* __restrict__ Wt,
    const float* __restrict__ cb, float* __restrict__ h, float* __restrict__ stats) {
    __shared__ float As[32 * 34];   // [k][t]
    __shared__ float Bs[32 * 34];   // [k][c]
    const int tid = threadIdx.x;
    const int t0  = blockIdx.x * 32;            // flat token base (b*L + l)
    const int ct0 = blockIdx.y * 32;
    const int b   = t0 >> 12;                   // L = 4096
    const int l0  = t0 & (L - 1);
    const float* xb = x + (size_t)b * CIN * T;
    const int m0 = (tid & 15) * 2;
    const int n0 = (tid >> 4) * 2;
    float acc[2][2] = {};
    for (int kc = 0; kc < 320; kc += 32) {
        #pragma unroll
        for (int i = 0; i < 4; ++i) {
            int idx = i * 256 + tid;            // 1024 = 32 kk x 32 t
            int kk = idx >> 5, t = idx & 31;
            int K = kc + kk;
            int ci = K / 5, k = K - ci * 5;
            int p = 2 * (l0 + t) + k - 2;
            As[kk * 34 + t] = (p >= 0 && p < T) ? xb[(size_t)ci * T + p] : 0.f;
            Bs[kk * 34 + t] = Wt[(size_t)K * COUT + ct0 + t];
        }
        __syncthreads();
        #pragma unroll
        for (int kk = 0; kk < 32; ++kk) {
            float2 a  = *(const float2*)&As[kk * 34 + m0];
            float2 bb = *(const float2*)&Bs[kk * 34 + n0];
            acc[0][0] = fmaf(a.x, bb.x, acc[0][0]); acc[0][1] = fmaf(a.x, bb.y, acc[0][1]);
            acc[1][0] = fmaf(a.y, bb.x, acc[1][0]); acc[1][1] = fmaf(a.y, bb.y, acc[1][1]);
        }
        __syncthreads();
    }
    float2 bias = *(const float2*)&cb[ct0 + n0];
    float s = 0.f, ss = 0.f;
    #pragma unroll
    for (int im = 0; im < 2; ++im) {
        float2 v = make_float2(acc[im][0] + bias.x, acc[im][1] + bias.y);
        *(float2*)&h[(size_t)(t0 + m0 + im) * COUT + ct0 + n0] = v;
        s  += v.x + v.y;
        ss += v.x * v.x + v.y * v.y;
    }
    #pragma unroll
    for (int off = 32; off; off >>= 1) {
        s  += __shfl_down(s,  off, 64);
        ss += __shfl_down(ss, off, 64);
    }
    if ((tid & 63) == 0) {
        atomicAdd(&stats[b * 2 + 0], s);
        atomicAdd(&stats[b * 2 + 1], ss);
    }
}

// ------------------------------------------------------ GN apply + PReLU
__global__ __launch_bounds__(256) void gn_prelu_kernel(
    float* __restrict__ h, const float* __restrict__ gn_g,
    const float* __restrict__ gn_b, const float* __restrict__ prelu_a,
    const float* __restrict__ stats) {
    int i = blockIdx.x * 256 + threadIdx.x;      // 262144 threads, x4 elements
    size_t base = (size_t)i * 4;
    int b = (base >= (size_t)L * COUT) ? 1 : 0;
    const float n = (float)(L * COUT);
    float mu   = stats[b * 2 + 0] / n;
    float var  = stats[b * 2 + 1] / n - mu * mu;
    float rstd = rsqrtf(var + 1e-5f);
    float a = prelu_a[0];
    float4 v = *(const float4*)&h[base];
    int c = (int)(base % COUT);
    float4 g  = *(const float4*)&gn_g[c];
    float4 bb = *(const float4*)&gn_b[c];
    v.x = (v.x - mu) * rstd * g.x + bb.x; v.x = v.x >= 0.f ? v.x : a * v.x;
    v.y = (v.y - mu) * rstd * g.y + bb.y; v.y = v.y >= 0.f ? v.y : a * v.y;
    v.z = (v.z - mu) * rstd * g.z + bb.z; v.z = v.z >= 0.f ? v.z : a * v.z;
    v.w = (v.w - mu) * rstd * g.w + bb.w; v.w = v.w >= 0.f ? v.w : a * v.w;
    *(float4*)&h[base] = v;
}

// ------------------------------------------------------ per-token LayerNorm
__global__ __launch_bounds__(256) void ln_kernel(
    const float* __restrict__ h, float* __restrict__ hn,
    const float* __restrict__ g, const float* __restrict__ bta) {
    int wave = threadIdx.x >> 6, lane = threadIdx.x & 63;
    int t = blockIdx.x * 4 + wave;
    const float* row = h + (size_t)t * COUT;
    float2 v = *(const float2*)&row[lane * 2];
    float s = v.x + v.y, ss = v.x * v.x + v.y * v.y;
    #pragma unroll
    for (int off = 32; off; off >>= 1) {
        s  += __shfl_xor(s,  off, 64);
        ss += __shfl_xor(ss, off, 64);
    }
    float mu = s * (1.f / 128.f);
    float var = ss * (1.f / 128.f) - mu * mu;
    float rstd = rsqrtf(var + 1e-5f);
    float2 gg = *(const float2*)&g[lane * 2];
    float2 bb = *(const float2*)&bta[lane * 2];
    float2 o;
    o.x = (v.x - mu) * rstd * gg.x + bb.x;
    o.y = (v.y - mu) * rstd * gg.y + bb.y;
    *(float2*)&hn[(size_t)t * COUT + lane * 2] = o;
}

// ------------------------------------------------- inproj GEMM  M=8192 K=128
// z-half gets SiLU applied in epilogue (gate is only ever used as silu(z)).
__global__ __launch_bounds__(256) void inproj_kernel(
    const float* __restrict__ hn, const float* __restrict__ W_in,
    float* __restrict__ xp0, float* __restrict__ z0,
    float* __restrict__ xp1, float* __restrict__ z1, int layer) {
    __shared__ float As[32 * 68];
    __shared__ float Bs[32 * 68];
    const int tid   = threadIdx.x;
    const int tBase = blockIdx.x * 64;
    const int nBase = blockIdx.y * 64;
    const int inst  = nBase >> 9;
    const int e0    = nBase & 511;
    const int m     = layer * 2 + inst;
    const float* Wm = W_in + ((size_t)m * 512 + e0) * 128;
    const int mrow = tid >> 2;      // 0..63
    const int kq   = tid & 3;       // 0..3
    const int m0   = (tid & 15) * 4;
    const int n0   = (tid >> 4) * 4;
    float acc[4][4] = {};
    for (int kc = 0; kc < 128; kc += 32) {
        {
            const float* srcA = hn + (size_t)(tBase + mrow) * 128 + kc + kq * 8;
            float4 a0 = *(const float4*)srcA;
            float4 a1 = *(const float4*)(srcA + 4);
            int kk = kq * 8;
            As[(kk + 0) * 68 + mrow] = a0.x; As[(kk + 1) * 68 + mrow] = a0.y;
            As[(kk + 2) * 68 + mrow] = a0.z; As[(kk + 3) * 68 + mrow] = a0.w;
            As[(kk + 4) * 68 + mrow] = a1.x; As[(kk + 5) * 68 + mrow] = a1.y;
            As[(kk + 6) * 68 + mrow] = a1.z; As[(kk + 7) * 68 + mrow] = a1.w;
            const float* srcB = Wm + (size_t)mrow * 128 + kc + kq * 8;
            float4 b0 = *(const float4*)srcB;
            float4 b1 = *(const float4*)(srcB + 4);
            Bs[(kk + 0) * 68 + mrow] = b0.x; Bs[(kk + 1) * 68 + mrow] = b0.y;
            Bs[(kk + 2) * 68 + mrow] = b0.z; Bs[(kk + 3) * 68 + mrow] = b0.w;
            Bs[(kk + 4) * 68 + mrow] = b1.x; Bs[(kk + 5) * 68 + mrow] = b1.y;
            Bs[(kk + 6) * 68 + mrow] = b1.z; Bs[(kk + 7) * 68 + mrow] = b1.w;
        }
        __syncthreads();
        #pragma unroll
        for (int kk = 0; kk < 32; ++kk) {
            float4 a = *(const float4*)&As[kk * 68 + m0];
            float4 b = *(const float4*)&Bs[kk * 68 + n0];
            acc[0][0] = fmaf(a.x, b.x, acc[0][0]); acc[0][1] = fmaf(a.x, b.y, acc[0][1]);
            acc[0][2] = fmaf(a.x, b.z, acc[0][2]); acc[0][3] = fmaf(a.x, b.w, acc[0][3]);
            acc[1][0] = fmaf(a.y, b.x, acc[1][0]); acc[1][1] = fmaf(a.y, b.y, acc[1][1]);
            acc[1][2] = fmaf(a.y, b.z, acc[1][2]); acc[1][3] = fmaf(a.y, b.w, acc[1][3]);
            acc[2][0] = fmaf(a.z, b.x, acc[2][0]); acc[2][1] = fmaf(a.z, b.y, acc[2][1]);
            acc[2][2] = fmaf(a.z, b.z, acc[2][2]); acc[2][3] = fmaf(a.z, b.w, acc[2][3]);
            acc[3][0] = fmaf(a.w, b.x, acc[3][0]); acc[3][1] = fmaf(a.w, b.y, acc[3][1]);
            acc[3][2] = fmaf(a.w, b.z, acc[3][2]); acc[3][3] = fmaf(a.w, b.w, acc[3][3]);
        }
        __syncthreads();
    }
    const bool isz = (e0 >= 256);
    float* dst; int eoff;
    if (!isz) { dst = inst ? xp1 : xp0; eoff = e0; }
    else      { dst = inst ? z1  : z0;  eoff = e0 - 256; }
    #pragma unroll
    for (int im = 0; im < 4; ++im) {
        float4 v = make_float4(acc[im][0], acc[im][1], acc[im][2], acc[im][3]);
        if (isz) {
            v.x *= sigmoidf_(v.x); v.y *= sigmoidf_(v.y);
            v.z *= sigmoidf_(v.z); v.w *= sigmoidf_(v.w);
        }
        *(float4*)&dst[(size_t)(tBase + m0 + im) * DI + eoff + n0] = v;
    }
}

// ---------------------------------------- depthwise causal conv (d=4) + SiLU
__global__ __launch_bounds__(256) void dwconv_kernel(
    const float* __restrict__ xp0, const float* __restrict__ xp1,
    const float* __restrict__ cw, const float* __restrict__ cbias,
    float* __restrict__ u0, float* __restrict__ u1, int layer) {
    int flat = blockIdx.x * 256 + threadIdx.x;
    int d    = flat & 255;
    int l    = (flat >> 8) & (L - 1);
    int b    = (flat >> 20) & 1;
    int inst = flat >> 21;
    const float* xp = inst ? xp1 : xp0;
    float* u = inst ? u1 : u0;
    int m = layer * 2 + inst;
    const float4 w4 = *(const float4*)&cw[(size_t)(m * DI + d) * 4];
    float acc = cbias[m * DI + d];
    size_t base = ((size_t)b * L) * DI + d;
    if (inst == 0) {  // forward: taps l-3..l, weights w[0]..w[3]
        if (l - 3 >= 0) acc = fmaf(w4.x, xp[base + (size_t)(l - 3) * DI], acc);
        if (l - 2 >= 0) acc = fmaf(w4.y, xp[base + (size_t)(l - 2) * DI], acc);
        if (l - 1 >= 0) acc = fmaf(w4.z, xp[base + (size_t)(l - 1) * DI], acc);
        acc = fmaf(w4.w, xp[base + (size_t)l * DI], acc);
    } else {          // backward (natural coords): taps l..l+3, w[3]..w[0]
        acc = fmaf(w4.w, xp[base + (size_t)l * DI], acc);
        if (l + 1 < L) acc = fmaf(w4.z, xp[base + (size_t)(l + 1) * DI], acc);
        if (l + 2 < L) acc = fmaf(w4.y, xp[base + (size_t)(l + 2) * DI], acc);
        if (l + 3 < L) acc = fmaf(w4.x, xp[base + (size_t)(l + 3) * DI], acc);
    }
    u[base + (size_t)l * DI] = acc * sigmoidf_(acc);
}

// ------------------------------------- xproj as GEMM (M=32tok/blk, N=40, K=256)
// W staged per 128-wide K chunk (40x128 slab, ~21 KB) -> total LDS ~39 KB.
// Then dt-proj + softplus fused. grid (TOK/32, 2).
__global__ __launch_bounds__(256) void xproj_kernel(
    const float* __restrict__ u0, const float* __restrict__ u1,
    const float* __restrict__ Wx, const float* __restrict__ Wdt,
    const float* __restrict__ bdt,
    float* __restrict__ dl0, float* __restrict__ dl1,
    float* __restrict__ Bm0, float* __restrict__ Bm1,
    float* __restrict__ Cm0, float* __restrict__ Cm1, int layer) {
    __shared__ float Ws[40 * 132];   // [e][k-sub] current K slab
    __shared__ float As[128 * 33];   // [k][t] half-K u tile
    __shared__ float xd[32 * 9];     // dt outputs
    const int tid   = threadIdx.x;
    const int tBase = blockIdx.x * 32;
    const int inst  = blockIdx.y;
    const int m     = layer * 2 + inst;
    const float* u  = inst ? u1 : u0;
    const float* Wm = Wx + (size_t)m * 40 * 256;
    const int t  = tid & 31;
    const int eq = tid >> 5;                // 0..7
    float acc[5] = {};
    for (int kc = 0; kc < 256; kc += 128) {
        __syncthreads();
        // stage W slab: 40 e x 128 k = 1280 float4
        #pragma unroll
        for (int i = 0; i < 5; ++i) {
            int idx = i * 256 + tid;        // e = idx>>5, kq = idx&31
            int e = idx >> 5, kq = idx & 31;
            float4 w4 = *(const float4*)&Wm[(size_t)e * 256 + kc + kq * 4];
            float* dstw = &Ws[e * 132 + kq * 4];
            dstw[0] = w4.x; dstw[1] = w4.y; dstw[2] = w4.z; dstw[3] = w4.w;
        }
        // stage u tile: 32 t x 128 k
        #pragma unroll
        for (int i = 0; i < 4; ++i) {
            int flat = i * 256 + tid;       // 1024 float4 = 32 t x 32 kq
            int tt = flat >> 5, kq = flat & 31;
            float4 v = *(const float4*)&u[(size_t)(tBase + tt) * DI + kc + kq * 4];
            As[(kq * 4 + 0) * 33 + tt] = v.x;
            As[(kq * 4 + 1) * 33 + tt] = v.y;
            As[(kq * 4 + 2) * 33 + tt] = v.z;
            As[(kq * 4 + 3) * 33 + tt] = v.w;
        }
        __syncthreads();
        #pragma unroll 4
        for (int kk = 0; kk < 128; ++kk) {
            float a = As[kk * 33 + t];
            acc[0] = fmaf(a, Ws[(eq     ) * 132 + kk], acc[0]);
            acc[1] = fmaf(a, Ws[(eq +  8) * 132 + kk], acc[1]);
            acc[2] = fmaf(a, Ws[(eq + 16) * 132 + kk], acc[2]);
            acc[3] = fmaf(a, Ws[(eq + 24) * 132 + kk], acc[3]);
            acc[4] = fmaf(a, Ws[(eq + 32) * 132 + kk], acc[4]);
        }
    }
    {
        int tok = tBase + t;
        float* Bm = inst ? Bm1 : Bm0;
        float* Cm = inst ? Cm1 : Cm0;
        xd[t * 9 + eq] = acc[0];
        Bm[(size_t)tok * NST + eq]     = acc[1];
        Bm[(size_t)tok * NST + 8 + eq] = acc[2];
        Cm[(size_t)tok * NST + eq]     = acc[3];
        Cm[(size_t)tok * NST + 8 + eq] = acc[4];
    }
    __syncthreads();
    {
        int d = tid;
        float wr[8];
        #pragma unroll
        for (int r = 0; r < 8; ++r) wr[r] = Wdt[((size_t)m * DI + d) * DTR + r];
        float bb = bdt[m * DI + d];
        float* dl = inst ? dl1 : dl0;
        #pragma unroll 4
        for (int tt = 0; tt < 32; ++tt) {
            float a2 = bb;
            #pragma unroll
            for (int r = 0; r < 8; ++r) a2 = fmaf(xd[tt * 9 + r], wr[r], a2);
            // stable fast softplus
            float sp = fmaxf(a2, 0.f) + __logf(1.f + __expf(-fabsf(a2)));
            dl[(size_t)(tBase + tt) * DI + d] = sp;
        }
    }
}

// ---------------------------------------------- scan phase 1: chunk-local
__global__ __launch_bounds__(256) void scan1_kernel(
    const float* __restrict__ dl0, const float* __restrict__ dl1,
    const float* __restrict__ u0,  const float* __restrict__ u1,
    const float* __restrict__ Bm0, const float* __restrict__ Bm1,
    const float* __restrict__ A_log,
    float* __restrict__ hend, float* __restrict__ dsumb, int layer) {
    const int tid = threadIdx.x;
    const int nq = tid & 3, dlane = tid >> 2;
    const int chunk = blockIdx.x & (NC - 1), dtile = blockIdx.x >> 6;
    const int b = blockIdx.y, inst = blockIdx.z;
    const int m = layer * 2 + inst, dir = inst;
    const int d = dtile * 64 + dlane;
    const float* dl = inst ? dl1 : dl0;
    const float* u  = inst ? u1  : u0;
    const float* Bm = inst ? Bm1 : Bm0;
    float4 av = *(const float4*)&A_log[((size_t)m * DI + d) * NST + nq * 4];
    const float a0 = -expf(av.x), a1 = -expf(av.y), a2 = -expf(av.z), a3 = -expf(av.w);
    const int s0 = chunk * Q;
    const int l0 = dir ? (L - 1 - s0) : s0;
    const int stp = dir ? -1 : 1;
    long iDU = ((long)(b * L + l0)) * DI + d;
    int  iB  = ((b * L + l0) << 4) + nq * 4;
    const long sDU = (long)stp * DI;
    const int  sB  = stp * NST;
    float h0 = 0.f, h1 = 0.f, h2 = 0.f, h3 = 0.f, dsum = 0.f;
    #pragma unroll 4
    for (int t = 0; t < Q; ++t) {
        float dlt = dl[iDU], uu = u[iDU];
        float4 bm = *(const float4*)&Bm[iB];
        float du = dlt * uu;
        h0 = fmaf(__expf(dlt * a0), h0, du * bm.x);
        h1 = fmaf(__expf(dlt * a1), h1, du * bm.y);
        h2 = fmaf(__expf(dlt * a2), h2, du * bm.z);
        h3 = fmaf(__expf(dlt * a3), h3, du * bm.w);
        dsum += dlt;
        iDU += sDU; iB += sB;
    }
    size_t oh = (((size_t)(inst * 2 + b) * DI + d) * NC + chunk) * NST + nq * 4;
    *(float4*)&hend[oh] = make_float4(h0, h1, h2, h3);
    if (nq == 0) dsumb[((size_t)(inst * 2 + b) * NC + chunk) * DI + d] = dsum;
}

// ---------------------------------------------- scan combine (in-place prefix)
__global__ __launch_bounds__(256) void combine_kernel(
    float* __restrict__ hend, const float* __restrict__ dsumb,
    const float* __restrict__ A_log, int layer) {
    int flat = blockIdx.x * 256 + threadIdx.x;   // 16384
    int n = flat & 15;
    int d = (flat >> 4) & 255;
    int b = (flat >> 12) & 1;
    int inst = flat >> 13;
    int m = layer * 2 + inst;
    float a = -expf(A_log[((size_t)m * DI + d) * NST + n]);
    size_t baseE = (((size_t)(inst * 2 + b) * DI + d) * NC) * NST + n;
    size_t baseD = ((size_t)(inst * 2 + b) * NC) * DI + d;
    float hc = 0.f;
    for (int c = 0; c < NC; ++c) {
        float tmp = hend[baseE + (size_t)c * NST];
        hend[baseE + (size_t)c * NST] = hc;
        float ds = dsumb[baseD + (size_t)c * DI];
        hc = fmaf(__expf(a * ds), hc, tmp);
    }
}

// --------------------------------- scan phase 2: full scan + y + gate
__global__ __launch_bounds__(256) void scan2_kernel(
    const float* __restrict__ dl0, const float* __restrict__ dl1,
    const float* __restrict__ u0,  const float* __restrict__ u1,
    const float* __restrict__ Bm0, const float* __restrict__ Bm1,
    const float* __restrict__ Cm0, const float* __restrict__ Cm1,
    const float* __restrict__ zs0, const float* __restrict__ zs1,
    const float* __restrict__ hin, const float* __restrict__ A_log,
    const float* __restrict__ Dp,
    float* __restrict__ yg0, float* __restrict__ yg1, int layer) {
    const int tid = threadIdx.x;
    const int nq = tid & 3, dlane = tid >> 2;
    const int chunk = blockIdx.x & (NC - 1), dtile = blockIdx.x >> 6;
    const int b = blockIdx.y, inst = blockIdx.z;
    const int m = layer * 2 + inst, dir = inst;
    const int d = dtile * 64 + dlane;
    const float* dl = inst ? dl1 : dl0;
    const float* u  = inst ? u1  : u0;
    const float* Bm = inst ? Bm1 : Bm0;
    const float* Cm = inst ? Cm1 : Cm0;
    const float* zs = inst ? zs1 : zs0;
    float* yg = inst ? yg1 : yg0;
    float4 av = *(const float4*)&A_log[((size_t)m * DI + d) * NST + nq * 4];
    const float a0 = -expf(av.x), a1 = -expf(av.y), a2 = -expf(av.z), a3 = -expf(av.w);
    const float dpar = Dp[m * DI + d];
    const int s0 = chunk * Q;
    const int l0 = dir ? (L - 1 - s0) : s0;
    const int stp = dir ? -1 : 1;
    long iDU = ((long)(b * L + l0)) * DI + d;
    int  iB  = ((b * L + l0) << 4) + nq * 4;
    const long sDU = (long)stp * DI;
    const int  sB  = stp * NST;
    float4 hv = *(const float4*)&hin[(((size_t)(inst * 2 + b) * DI + d) * NC + chunk) * NST + nq * 4];
    float h0 = hv.x, h1 = hv.y, h2 = hv.z, h3 = hv.w;
    #pragma unroll 4
    for (int t = 0; t < Q; ++t) {
        float dlt = dl[iDU], uu = u[iDU];
        float4 bm = *(const float4*)&Bm[iB];
        float4 cm = *(const float4*)&Cm[iB];
        float du = dlt * uu;
        h0 = fmaf(__expf(dlt * a0), h0, du * bm.x);
        h1 = fmaf(__expf(dlt * a1), h1, du * bm.y);
        h2 = fmaf(__expf(dlt * a2), h2, du * bm.z);
        h3 = fmaf(__expf(dlt * a3), h3, du * bm.w);
        float yp = h0 * cm.x + h1 * cm.y + h2 * cm.z + h3 * cm.w;
        yp += __shfl_xor(yp, 1, 4);
        yp += __shfl_xor(yp, 2, 4);
        if (nq == 0) {
            float zv = zs[iDU];
            yg[iDU] = fmaf(uu, dpar, yp) * zv;
        }
        iDU += sDU; iB += sB;
    }
}

// ------------------------------- outproj GEMM (both insts) + residual into h
__global__ __launch_bounds__(256) void outproj_kernel(
    const float* __restrict__ yg0, const float* __restrict__ yg1,
    const float* __restrict__ W_out, float* __restrict__ h, int layer) {
    __shared__ float As[32 * 36];
    __shared__ float Bs[32 * 132];
    const int tid = threadIdx.x;
    const int tBase = blockIdx.x * 32;
    const int m00 = (tid & 15) * 2, n0 = (tid >> 4) * 8;
    float acc[2][8] = {};
    for (int inst = 0; inst < 2; ++inst) {
        const float* yg = inst ? yg1 : yg0;
        const float* Wm = W_out + (size_t)(layer * 2 + inst) * COUT * DI;
        for (int kc = 0; kc < 256; kc += 32) {
            {
                int t = tid >> 3, kq = tid & 7;
                float4 v = *(const float4*)&yg[(size_t)(tBase + t) * DI + kc + kq * 4];
                As[(kq * 4 + 0) * 36 + t] = v.x; As[(kq * 4 + 1) * 36 + t] = v.y;
                As[(kq * 4 + 2) * 36 + t] = v.z; As[(kq * 4 + 3) * 36 + t] = v.w;
                int nr = tid >> 1, kq2 = tid & 1;
                const float* wsrc = Wm + (size_t)nr * DI + kc + kq2 * 16;
                #pragma unroll
                for (int q = 0; q < 4; ++q) {
                    float4 wv = *(const float4*)(wsrc + q * 4);
                    int kk = kq2 * 16 + q * 4;
                    Bs[(kk + 0) * 132 + nr] = wv.x; Bs[(kk + 1) * 132 + nr] = wv.y;
                    Bs[(kk + 2) * 132 + nr] = wv.z; Bs[(kk + 3) * 132 + nr] = wv.w;
                }
            }
            __syncthreads();
            #pragma unroll
            for (int kk = 0; kk < 32; ++kk) {
                float2 av = *(const float2*)&As[kk * 36 + m00];
                float4 b0 = *(const float4*)&Bs[kk * 132 + n0];
                float4 b1 = *(const float4*)&Bs[kk * 132 + n0 + 4];
                acc[0][0] = fmaf(av.x, b0.x, acc[0][0]); acc[0][1] = fmaf(av.x, b0.y, acc[0][1]);
                acc[0][2] = fmaf(av.x, b0.z, acc[0][2]); acc[0][3] = fmaf(av.x, b0.w, acc[0][3]);
                acc[0][4] = fmaf(av.x, b1.x, acc[0][4]); acc[0][5] = fmaf(av.x, b1.y, acc[0][5]);
                acc[0][6] = fmaf(av.x, b1.z, acc[0][6]); acc[0][7] = fmaf(av.x, b1.w, acc[0][7]);
                acc[1][0] = fmaf(av.y, b0.x, acc[1][0]); acc[1][1] = fmaf(av.y, b0.y, acc[1][1]);
                acc[1][2] = fmaf(av.y, b0.z, acc[1][2]); acc[1][3] = fmaf(av.y, b0.w, acc[1][3]);
                acc[1][4] = fmaf(av.y, b1.x, acc[1][4]); acc[1][5] = fmaf(av.y, b1.y, acc[1][5]);
                acc[1][6] = fmaf(av.y, b1.z, acc[1][6]); acc[1][7] = fmaf(av.y, b1.w, acc[1][7]);
            }
            __syncthreads();
        }
    }
    #pragma unroll
    for (int im = 0; im < 2; ++im) {
        size_t row = (size_t)(tBase + m00 + im) * COUT + n0;
        float4 h0 = *(const float4*)&h[row];
        float4 h1 = *(const float4*)&h[row + 4];
        h0.x += acc[im][0]; h0.y += acc[im][1]; h0.z += acc[im][2]; h0.w += acc[im][3];
        h1.x += acc[im][4]; h1.y += acc[im][5]; h1.z += acc[im][6]; h1.w += acc[im][7];
        *(float4*)&h[row] = h0;
        *(float4*)&h[row + 4] = h1;
    }
}

// ------------------------------------------------ final [B,L,C] -> [B,C,L]
__global__ __launch_bounds__(256) void transpose_kernel(
    const float* __restrict__ h, float* __restrict__ out) {
    __shared__ float tile[32][33];
    int lt0 = blockIdx.x * 32, ct0 = blockIdx.y * 32, b = blockIdx.z;
    int c = threadIdx.x & 31, r = threadIdx.x >> 5;
    #pragma unroll
    for (int j = 0; j < 4; ++j) {
        int ll = r + 8 * j;
        tile[ll][c] = h[((size_t)b * L + lt0 + ll) * COUT + ct0 + c];
    }
    __syncthreads();
    #pragma unroll
    for (int j = 0; j < 4; ++j) {
        int cc = r + 8 * j;
        out[((size_t)b * COUT + ct0 + cc) * L + lt0 + c] = tile[c][cc];
    }
}

// ======================================================================
extern "C" void kernel_launch(void* const* d_in, const int* in_sizes, int n_in,
                              void* d_out, int out_size, void* d_ws, size_t ws_size,
                              hipStream_t stream) {
    const float* x        = (const float*)d_in[0];
    const float* conv_w   = (const float*)d_in[1];
    const float* conv_b   = (const float*)d_in[2];
    const float* gn_g     = (const float*)d_in[3];
    const float* gn_b     = (const float*)d_in[4];
    const float* prelu_a  = (const float*)d_in[5];
    const float* ln_g     = (const float*)d_in[6];
    const float* ln_b     = (const float*)d_in[7];
    const float* W_in     = (const float*)d_in[8];
    const float* conv1d_w = (const float*)d_in[9];
    const float* conv1d_b = (const float*)d_in[10];
    const float* W_xproj  = (const float*)d_in[11];
    const float* W_dt     = (const float*)d_in[12];
    const float* b_dt     = (const float*)d_in[13];
    const float* A_log    = (const float*)d_in[14];
    const float* D_param  = (const float*)d_in[15];
    const float* W_out    = (const float*)d_in[16];

    float* ws = (float*)d_ws;
    float* h     = ws;                   // [B,L,128]
    float* hn    = ws + 1048576;         // [B,L,128] (aliased: Wt pre-loop, dsumb during scans)
    float* xp0   = ws + 2097152;         // [B,L,256] (reused as yg0)
    float* xp1   = ws + 4194304;         //           (reused as yg1)
    float* z0    = ws + 6291456;         // silu(z) from inproj epilogue
    float* z1    = ws + 8388608;
    float* u0    = ws + 10485760;
    float* u1    = ws + 12582912;
    float* dl0   = ws + 14680064;
    float* dl1   = ws + 16777216;
    float* Bm0   = ws + 18874368;        // [B,L,16]
    float* Bm1   = ws + 19005440;
    float* Cm0   = ws + 19136512;
    float* Cm1   = ws + 19267584;
    float* hend  = ws + 19398656;        // [2,B,256,NC,16] = 1,048,576 (prefix in-place)
    float* stats = ws + 20447232;        // [4]
    float* Wt    = hn;                   // [320,128]
    float* dsumb = hn;                   // [2,B,NC,256] = 65,536 (hn dead during scans)

    zero_stats_kernel<<<1, 64, 0, stream>>>(stats);
    transpose_w_kernel<<<160, 256, 0, stream>>>(conv_w, Wt);
    conv_gemm_kernel<<<dim3(TOK / 32, COUT / 32), 256, 0, stream>>>(x, Wt, conv_b, h, stats);
    gn_prelu_kernel<<<(TOK * COUT / 4) / 256, 256, 0, stream>>>(h, gn_g, gn_b, prelu_a, stats);

    for (int layer = 0; layer < 2; ++layer) {
        ln_kernel<<<TOK / 4, 256, 0, stream>>>(h, hn, ln_g + layer * COUT, ln_b + layer * COUT);
        inproj_kernel<<<dim3(TOK / 64, 16), 256, 0, stream>>>(hn, W_in, xp0, z0, xp1, z1, layer);
        dwconv_kernel<<<(2 * B2 * L * DI) / 256, 256, 0, stream>>>(xp0, xp1, conv1d_w, conv1d_b, u0, u1, layer);
        xproj_kernel<<<dim3(TOK / 32, 2), 256, 0, stream>>>(u0, u1, W_xproj, W_dt, b_dt,
                                                            dl0, dl1, Bm0, Bm1, Cm0, Cm1, layer);
        scan1_kernel<<<dim3(NC * 4, B2, 2), 256, 0, stream>>>(dl0, dl1, u0, u1, Bm0, Bm1,
                                                              A_log, hend, dsumb, layer);
        combine_kernel<<<64, 256, 0, stream>>>(hend, dsumb, A_log, layer);
        scan2_kernel<<<dim3(NC * 4, B2, 2), 256, 0, stream>>>(dl0, dl1, u0, u1, Bm0, Bm1, Cm0, Cm1,
                                                              z0, z1, hend, A_log, D_param,
                                                              xp0, xp1, layer);
        outproj_kernel<<<TOK / 32, 256, 0, stream>>>(xp0, xp1, W_out, h, layer);
    }
    transpose_kernel<<<dim3(L / 32, COUT / 32, B2), 256, 0, stream>>>(h, (float*)d_out);
}

// Round 7
// 501.755 us; speedup vs baseline: 1.5334x; 1.1158x over previous
//
#include <hip/hip_runtime.h>
#include <hip/hip_bf16.h>
#include <math.h>

// ---- problem dims ----
constexpr int B2   = 2;
constexpr int CIN  = 64;
constexpr int COUT = 128;
constexpr int T    = 8192;
constexpr int L    = 4096;     // T/2
constexpr int DI   = 256;
constexpr int NST  = 16;       // d_state
constexpr int DTR  = 8;
constexpr int Q    = 64;       // scan chunk length
constexpr int NC   = 64;       // L / Q
constexpr int TOK  = B2 * L;   // 8192 tokens

__device__ __forceinline__ float sigmoidf_(float x) { return 1.f / (1.f + __expf(-x)); }

// ---------------------------------------------------------------- zero stats
__global__ __launch_bounds__(64) void zero_stats_kernel(float* stats) {
    if (threadIdx.x < 4) stats[threadIdx.x] = 0.f;
}

// ------------------------------------------- conv weight transpose [128][320] -> [320][128]
__global__ __launch_bounds__(256) void transpose_w_kernel(
    const float* __restrict__ cw, float* __restrict__ Wt) {
    int idx = blockIdx.x * 256 + threadIdx.x;   // 40960
    int c = idx & 127, kidx = idx >> 7;
    Wt[(size_t)kidx * COUT + c] = cw[(size_t)c * 320 + kidx];
}

// ------------------------------------- conv1d stride2 as implicit-im2col GEMM + GN stats
// 64 tok x 32 cout tiles -> 512 blocks (2/CU), double-buffered K pipeline.
// Per chunk: prefetch k+1 to regs -> 256 FMAs on k -> write regs to alt buf -> 1 barrier.
__global__ __launch_bounds__(256) void conv_gemm_kernel(
    const float* __restrict__ x, const float* __restrict__ Wt,
    const float* __restrict__ cb, float* __restrict__ h, float* __restrict__ stats) {
    __shared__ float As[2][32 * 68];   // [k][t] 64 tok
    __shared__ float Bs[2][32 * 36];   // [k][c] 32 cout
    const int tid = threadIdx.x;
    const int t0  = blockIdx.x * 64;            // flat token base (b*L + l)
    const int ct0 = blockIdx.y * 32;
    const int b   = t0 >> 12;                   // L = 4096
    const int l0  = t0 & (L - 1);
    const float* xb = x + (size_t)b * CIN * T;
    const int m0 = (tid & 15) * 4;              // 4 tokens
    const int n0 = (tid >> 4) * 2;              // 2 couts
    float acc[4][2] = {};
    // stage chunk 0
    #pragma unroll
    for (int i = 0; i < 8; ++i) {
        int idx = i * 256 + tid; int kk = idx >> 6, t = idx & 63;
        int ci = kk / 5, k = kk - ci * 5;
        int p = 2 * (l0 + t) + k - 2;
        As[0][kk * 68 + t] = (p >= 0 && p < T) ? xb[(size_t)ci * T + p] : 0.f;
    }
    #pragma unroll
    for (int i = 0; i < 4; ++i) {
        int idx = i * 256 + tid; int kk = idx >> 5, c = idx & 31;
        Bs[0][kk * 36 + c] = Wt[(size_t)kk * COUT + ct0 + c];
    }
    __syncthreads();
    for (int cch = 0; cch < 10; ++cch) {
        float pa[8], pb[4];
        if (cch < 9) {                       // prefetch chunk cch+1 into registers
            int kc = (cch + 1) * 32;
            #pragma unroll
            for (int i = 0; i < 8; ++i) {
                int idx = i * 256 + tid; int kk = idx >> 6, t = idx & 63;
                int K = kc + kk; int ci = K / 5, k = K - ci * 5;
                int p = 2 * (l0 + t) + k - 2;
                pa[i] = (p >= 0 && p < T) ? xb[(size_t)ci * T + p] : 0.f;
            }
            #pragma unroll
            for (int i = 0; i < 4; ++i) {
                int idx = i * 256 + tid; int kk = idx >> 5, c = idx & 31;
                pb[i] = Wt[(size_t)(kc + kk) * COUT + ct0 + c];
            }
        }
        const float* Ac = As[cch & 1];
        const float* Bc = Bs[cch & 1];
        #pragma unroll
        for (int kk = 0; kk < 32; ++kk) {
            float4 a  = *(const float4*)&Ac[kk * 68 + m0];
            float2 bb = *(const float2*)&Bc[kk * 36 + n0];
            acc[0][0] = fmaf(a.x, bb.x, acc[0][0]); acc[0][1] = fmaf(a.x, bb.y, acc[0][1]);
            acc[1][0] = fmaf(a.y, bb.x, acc[1][0]); acc[1][1] = fmaf(a.y, bb.y, acc[1][1]);
            acc[2][0] = fmaf(a.z, bb.x, acc[2][0]); acc[2][1] = fmaf(a.z, bb.y, acc[2][1]);
            acc[3][0] = fmaf(a.w, bb.x, acc[3][0]); acc[3][1] = fmaf(a.w, bb.y, acc[3][1]);
        }
        if (cch < 9) {                       // commit prefetch to the alternate buffer
            float* An = (float*)As[(cch + 1) & 1];
            float* Bn = (float*)Bs[(cch + 1) & 1];
            #pragma unroll
            for (int i = 0; i < 8; ++i) {
                int idx = i * 256 + tid;
                An[(idx >> 6) * 68 + (idx & 63)] = pa[i];
            }
            #pragma unroll
            for (int i = 0; i < 4; ++i) {
                int idx = i * 256 + tid;
                Bn[(idx >> 5) * 36 + (idx & 31)] = pb[i];
            }
        }
        __syncthreads();
    }
    float2 bias = *(const float2*)&cb[ct0 + n0];
    float s = 0.f, ss = 0.f;
    #pragma unroll
    for (int im = 0; im < 4; ++im) {
        float2 v = make_float2(acc[im][0] + bias.x, acc[im][1] + bias.y);
        *(float2*)&h[(size_t)(t0 + m0 + im) * COUT + ct0 + n0] = v;
        s  += v.x + v.y;
        ss += v.x * v.x + v.y * v.y;
    }
    #pragma unroll
    for (int off = 32; off; off >>= 1) {
        s  += __shfl_down(s,  off, 64);
        ss += __shfl_down(ss, off, 64);
    }
    if ((tid & 63) == 0) {
        atomicAdd(&stats[b * 2 + 0], s);
        atomicAdd(&stats[b * 2 + 1], ss);
    }
}

// ------------------------------------------------------ GN apply + PReLU
__global__ __launch_bounds__(256) void gn_prelu_kernel(
    float* __restrict__ h, const float* __restrict__ gn_g,
    const float* __restrict__ gn_b, const float* __restrict__ prelu_a,
    const float* __restrict__ stats) {
    int i = blockIdx.x * 256 + threadIdx.x;      // 262144 threads, x4 elements
    size_t base = (size_t)i * 4;
    int b = (base >= (size_t)L * COUT) ? 1 : 0;
    const float n = (float)(L * COUT);
    float mu   = stats[b * 2 + 0] / n;
    float var  = stats[b * 2 + 1] / n - mu * mu;
    float rstd = rsqrtf(var + 1e-5f);
    float a = prelu_a[0];
    float4 v = *(const float4*)&h[base];
    int c = (int)(base % COUT);
    float4 g  = *(const float4*)&gn_g[c];
    float4 bb = *(const float4*)&gn_b[c];
    v.x = (v.x - mu) * rstd * g.x + bb.x; v.x = v.x >= 0.f ? v.x : a * v.x;
    v.y = (v.y - mu) * rstd * g.y + bb.y; v.y = v.y >= 0.f ? v.y : a * v.y;
    v.z = (v.z - mu) * rstd * g.z + bb.z; v.z = v.z >= 0.f ? v.z : a * v.z;
    v.w = (v.w - mu) * rstd * g.w + bb.w; v.w = v.w >= 0.f ? v.w : a * v.w;
    *(float4*)&h[base] = v;
}

// ------------------------------------------------------ per-token LayerNorm
__global__ __launch_bounds__(256) void ln_kernel(
    const float* __restrict__ h, float* __restrict__ hn,
    const float* __restrict__ g, const float* __restrict__ bta) {
    int wave = threadIdx.x >> 6, lane = threadIdx.x & 63;
    int t = blockIdx.x * 4 + wave;
    const float* row = h + (size_t)t * COUT;
    float2 v = *(const float2*)&row[lane * 2];
    float s = v.x + v.y, ss = v.x * v.x + v.y * v.y;
    #pragma unroll
    for (int off = 32; off; off >>= 1) {
        s  += __shfl_xor(s,  off, 64);
        ss += __shfl_xor(ss, off, 64);
    }
    float mu = s * (1.f / 128.f);
    float var = ss * (1.f / 128.f) - mu * mu;
    float rstd = rsqrtf(var + 1e-5f);
    float2 gg = *(const float2*)&g[lane * 2];
    float2 bb = *(const float2*)&bta[lane * 2];
    float2 o;
    o.x = (v.x - mu) * rstd * gg.x + bb.x;
    o.y = (v.y - mu) * rstd * gg.y + bb.y;
    *(float2*)&hn[(size_t)t * COUT + lane * 2] = o;
}

// ------------------------------------------------- inproj GEMM  M=8192 K=128
// z-half gets SiLU applied in epilogue (gate is only ever used as silu(z)).
__global__ __launch_bounds__(256) void inproj_kernel(
    const float* __restrict__ hn, const float* __restrict__ W_in,
    float* __restrict__ xp0, float* __restrict__ z0,
    float* __restrict__ xp1, float* __restrict__ z1, int layer) {
    __shared__ float As[32 * 68];
    __shared__ float Bs[32 * 68];
    const int tid   = threadIdx.x;
    const int tBase = blockIdx.x * 64;
    const int nBase = blockIdx.y * 64;
    const int inst  = nBase >> 9;
    const int e0    = nBase & 511;
    const int m     = layer * 2 + inst;
    const float* Wm = W_in + ((size_t)m * 512 + e0) * 128;
    const int mrow = tid >> 2;      // 0..63
    const int kq   = tid & 3;       // 0..3
    const int m0   = (tid & 15) * 4;
    const int n0   = (tid >> 4) * 4;
    float acc[4][4] = {};
    for (int kc = 0; kc < 128; kc += 32) {
        {
            const float* srcA = hn + (size_t)(tBase + mrow) * 128 + kc + kq * 8;
            float4 a0 = *(const float4*)srcA;
            float4 a1 = *(const float4*)(srcA + 4);
            int kk = kq * 8;
            As[(kk + 0) * 68 + mrow] = a0.x; As[(kk + 1) * 68 + mrow] = a0.y;
            As[(kk + 2) * 68 + mrow] = a0.z; As[(kk + 3) * 68 + mrow] = a0.w;
            As[(kk + 4) * 68 + mrow] = a1.x; As[(kk + 5) * 68 + mrow] = a1.y;
            As[(kk + 6) * 68 + mrow] = a1.z; As[(kk + 7) * 68 + mrow] = a1.w;
            const float* srcB = Wm + (size_t)mrow * 128 + kc + kq * 8;
            float4 b0 = *(const float4*)srcB;
            float4 b1 = *(const float4*)(srcB + 4);
            Bs[(kk + 0) * 68 + mrow] = b0.x; Bs[(kk + 1) * 68 + mrow] = b0.y;
            Bs[(kk + 2) * 68 + mrow] = b0.z; Bs[(kk + 3) * 68 + mrow] = b0.w;
            Bs[(kk + 4) * 68 + mrow] = b1.x; Bs[(kk + 5) * 68 + mrow] = b1.y;
            Bs[(kk + 6) * 68 + mrow] = b1.z; Bs[(kk + 7) * 68 + mrow] = b1.w;
        }
        __syncthreads();
        #pragma unroll
        for (int kk = 0; kk < 32; ++kk) {
            float4 a = *(const float4*)&As[kk * 68 + m0];
            float4 b = *(const float4*)&Bs[kk * 68 + n0];
            acc[0][0] = fmaf(a.x, b.x, acc[0][0]); acc[0][1] = fmaf(a.x, b.y, acc[0][1]);
            acc[0][2] = fmaf(a.x, b.z, acc[0][2]); acc[0][3] = fmaf(a.x, b.w, acc[0][3]);
            acc[1][0] = fmaf(a.y, b.x, acc[1][0]); acc[1][1] = fmaf(a.y, b.y, acc[1][1]);
            acc[1][2] = fmaf(a.y, b.z, acc[1][2]); acc[1][3] = fmaf(a.y, b.w, acc[1][3]);
            acc[2][0] = fmaf(a.z, b.x, acc[2][0]); acc[2][1] = fmaf(a.z, b.y, acc[2][1]);
            acc[2][2] = fmaf(a.z, b.z, acc[2][2]); acc[2][3] = fmaf(a.z, b.w, acc[2][3]);
            acc[3][0] = fmaf(a.w, b.x, acc[3][0]); acc[3][1] = fmaf(a.w, b.y, acc[3][1]);
            acc[3][2] = fmaf(a.w, b.z, acc[3][2]); acc[3][3] = fmaf(a.w, b.w, acc[3][3]);
        }
        __syncthreads();
    }
    const bool isz = (e0 >= 256);
    float* dst; int eoff;
    if (!isz) { dst = inst ? xp1 : xp0; eoff = e0; }
    else      { dst = inst ? z1  : z0;  eoff = e0 - 256; }
    #pragma unroll
    for (int im = 0; im < 4; ++im) {
        float4 v = make_float4(acc[im][0], acc[im][1], acc[im][2], acc[im][3]);
        if (isz) {
            v.x *= sigmoidf_(v.x); v.y *= sigmoidf_(v.y);
            v.z *= sigmoidf_(v.z); v.w *= sigmoidf_(v.w);
        }
        *(float4*)&dst[(size_t)(tBase + m0 + im) * DI + eoff + n0] = v;
    }
}

// ---------------------------------------- depthwise causal conv (d=4) + SiLU
__global__ __launch_bounds__(256) void dwconv_kernel(
    const float* __restrict__ xp0, const float* __restrict__ xp1,
    const float* __restrict__ cw, const float* __restrict__ cbias,
    float* __restrict__ u0, float* __restrict__ u1, int layer) {
    int flat = blockIdx.x * 256 + threadIdx.x;
    int d    = flat & 255;
    int l    = (flat >> 8) & (L - 1);
    int b    = (flat >> 20) & 1;
    int inst = flat >> 21;
    const float* xp = inst ? xp1 : xp0;
    float* u = inst ? u1 : u0;
    int m = layer * 2 + inst;
    const float4 w4 = *(const float4*)&cw[(size_t)(m * DI + d) * 4];
    float acc = cbias[m * DI + d];
    size_t base = ((size_t)b * L) * DI + d;
    if (inst == 0) {  // forward: taps l-3..l, weights w[0]..w[3]
        if (l - 3 >= 0) acc = fmaf(w4.x, xp[base + (size_t)(l - 3) * DI], acc);
        if (l - 2 >= 0) acc = fmaf(w4.y, xp[base + (size_t)(l - 2) * DI], acc);
        if (l - 1 >= 0) acc = fmaf(w4.z, xp[base + (size_t)(l - 1) * DI], acc);
        acc = fmaf(w4.w, xp[base + (size_t)l * DI], acc);
    } else {          // backward (natural coords): taps l..l+3, w[3]..w[0]
        acc = fmaf(w4.w, xp[base + (size_t)l * DI], acc);
        if (l + 1 < L) acc = fmaf(w4.z, xp[base + (size_t)(l + 1) * DI], acc);
        if (l + 2 < L) acc = fmaf(w4.y, xp[base + (size_t)(l + 2) * DI], acc);
        if (l + 3 < L) acc = fmaf(w4.x, xp[base + (size_t)(l + 3) * DI], acc);
    }
    u[base + (size_t)l * DI] = acc * sigmoidf_(acc);
}

// ------------------------------------- xproj as GEMM (M=32tok/blk, N=40, K=256)
// W staged per 128-wide K chunk (40x128 slab, ~21 KB) -> total LDS ~39 KB.
// Then dt-proj + softplus fused. grid (TOK/32, 2).
__global__ __launch_bounds__(256) void xproj_kernel(
    const float* __restrict__ u0, const float* __restrict__ u1,
    const float* __restrict__ Wx, const float* __restrict__ Wdt,
    const float* __restrict__ bdt,
    float* __restrict__ dl0, float* __restrict__ dl1,
    float* __restrict__ Bm0, float* __restrict__ Bm1,
    float* __restrict__ Cm0, float* __restrict__ Cm1, int layer) {
    __shared__ float Ws[40 * 132];   // [e][k-sub] current K slab
    __shared__ float As[128 * 33];   // [k][t] half-K u tile
    __shared__ float xd[32 * 9];     // dt outputs
    const int tid   = threadIdx.x;
    const int tBase = blockIdx.x * 32;
    const int inst  = blockIdx.y;
    const int m     = layer * 2 + inst;
    const float* u  = inst ? u1 : u0;
    const float* Wm = Wx + (size_t)m * 40 * 256;
    const int t  = tid & 31;
    const int eq = tid >> 5;                // 0..7
    float acc[5] = {};
    for (int kc = 0; kc < 256; kc += 128) {
        __syncthreads();
        // stage W slab: 40 e x 128 k = 1280 float4
        #pragma unroll
        for (int i = 0; i < 5; ++i) {
            int idx = i * 256 + tid;        // e = idx>>5, kq = idx&31
            int e = idx >> 5, kq = idx & 31;
            float4 w4 = *(const float4*)&Wm[(size_t)e * 256 + kc + kq * 4];
            float* dstw = &Ws[e * 132 + kq * 4];
            dstw[0] = w4.x; dstw[1] = w4.y; dstw[2] = w4.z; dstw[3] = w4.w;
        }
        // stage u tile: 32 t x 128 k
        #pragma unroll
        for (int i = 0; i < 4; ++i) {
            int flat = i * 256 + tid;       // 1024 float4 = 32 t x 32 kq
            int tt = flat >> 5, kq = flat & 31;
            float4 v = *(const float4*)&u[(size_t)(tBase + tt) * DI + kc + kq * 4];
            As[(kq * 4 + 0) * 33 + tt] = v.x;
            As[(kq * 4 + 1) * 33 + tt] = v.y;
            As[(kq * 4 + 2) * 33 + tt] = v.z;
            As[(kq * 4 + 3) * 33 + tt] = v.w;
        }
        __syncthreads();
        #pragma unroll 4
        for (int kk = 0; kk < 128; ++kk) {
            float a = As[kk * 33 + t];
            acc[0] = fmaf(a, Ws[(eq     ) * 132 + kk], acc[0]);
            acc[1] = fmaf(a, Ws[(eq +  8) * 132 + kk], acc[1]);
            acc[2] = fmaf(a, Ws[(eq + 16) * 132 + kk], acc[2]);
            acc[3] = fmaf(a, Ws[(eq + 24) * 132 + kk], acc[3]);
            acc[4] = fmaf(a, Ws[(eq + 32) * 132 + kk], acc[4]);
        }
    }
    {
        int tok = tBase + t;
        float* Bm = inst ? Bm1 : Bm0;
        float* Cm = inst ? Cm1 : Cm0;
        xd[t * 9 + eq] = acc[0];
        Bm[(size_t)tok * NST + eq]     = acc[1];
        Bm[(size_t)tok * NST + 8 + eq] = acc[2];
        Cm[(size_t)tok * NST + eq]     = acc[3];
        Cm[(size_t)tok * NST + 8 + eq] = acc[4];
    }
    __syncthreads();
    {
        int d = tid;
        float wr[8];
        #pragma unroll
        for (int r = 0; r < 8; ++r) wr[r] = Wdt[((size_t)m * DI + d) * DTR + r];
        float bb = bdt[m * DI + d];
        float* dl = inst ? dl1 : dl0;
        #pragma unroll 4
        for (int tt = 0; tt < 32; ++tt) {
            float a2 = bb;
            #pragma unroll
            for (int r = 0; r < 8; ++r) a2 = fmaf(xd[tt * 9 + r], wr[r], a2);
            // stable fast softplus
            float sp = fmaxf(a2, 0.f) + __logf(1.f + __expf(-fabsf(a2)));
            dl[(size_t)(tBase + tt) * DI + d] = sp;
        }
    }
}

// ---------------------------------------------- scan phase 1: chunk-local
__global__ __launch_bounds__(256) void scan1_kernel(
    const float* __restrict__ dl0, const float* __restrict__ dl1,
    const float* __restrict__ u0,  const float* __restrict__ u1,
    const float* __restrict__ Bm0, const float* __restrict__ Bm1,
    const float* __restrict__ A_log,
    float* __restrict__ hend, float* __restrict__ dsumb, int layer) {
    const int tid = threadIdx.x;
    const int nq = tid & 3, dlane = tid >> 2;
    const int chunk = blockIdx.x & (NC - 1), dtile = blockIdx.x >> 6;
    const int b = blockIdx.y, inst = blockIdx.z;
    const int m = layer * 2 + inst, dir = inst;
    const int d = dtile * 64 + dlane;
    const float* dl = inst ? dl1 : dl0;
    const float* u  = inst ? u1  : u0;
    const float* Bm = inst ? Bm1 : Bm0;
    float4 av = *(const float4*)&A_log[((size_t)m * DI + d) * NST + nq * 4];
    const float a0 = -expf(av.x), a1 = -expf(av.y), a2 = -expf(av.z), a3 = -expf(av.w);
    const int s0 = chunk * Q;
    const int l0 = dir ? (L - 1 - s0) : s0;
    const int stp = dir ? -1 : 1;
    long iDU = ((long)(b * L + l0)) * DI + d;
    int  iB  = ((b * L + l0) << 4) + nq * 4;
    const long sDU = (long)stp * DI;
    const int  sB  = stp * NST;
    float h0 = 0.f, h1 = 0.f, h2 = 0.f, h3 = 0.f, dsum = 0.f;
    #pragma unroll 4
    for (int t = 0; t < Q; ++t) {
        float dlt = dl[iDU], uu = u[iDU];
        float4 bm = *(const float4*)&Bm[iB];
        float du = dlt * uu;
        h0 = fmaf(__expf(dlt * a0), h0, du * bm.x);
        h1 = fmaf(__expf(dlt * a1), h1, du * bm.y);
        h2 = fmaf(__expf(dlt * a2), h2, du * bm.z);
        h3 = fmaf(__expf(dlt * a3), h3, du * bm.w);
        dsum += dlt;
        iDU += sDU; iB += sB;
    }
    size_t oh = (((size_t)(inst * 2 + b) * DI + d) * NC + chunk) * NST + nq * 4;
    *(float4*)&hend[oh] = make_float4(h0, h1, h2, h3);
    if (nq == 0) dsumb[((size_t)(inst * 2 + b) * NC + chunk) * DI + d] = dsum;
}

// ---------------------------------------------- scan combine (in-place prefix)
__global__ __launch_bounds__(256) void combine_kernel(
    float* __restrict__ hend, const float* __restrict__ dsumb,
    const float* __restrict__ A_log, int layer) {
    int flat = blockIdx.x * 256 + threadIdx.x;   // 16384
    int n = flat & 15;
    int d = (flat >> 4) & 255;
    int b = (flat >> 12) & 1;
    int inst = flat >> 13;
    int m = layer * 2 + inst;
    float a = -expf(A_log[((size_t)m * DI + d) * NST + n]);
    size_t baseE = (((size_t)(inst * 2 + b) * DI + d) * NC) * NST + n;
    size_t baseD = ((size_t)(inst * 2 + b) * NC) * DI + d;
    float hc = 0.f;
    for (int c = 0; c < NC; ++c) {
        float tmp = hend[baseE + (size_t)c * NST];
        hend[baseE + (size_t)c * NST] = hc;
        float ds = dsumb[baseD + (size_t)c * DI];
        hc = fmaf(__expf(a * ds), hc, tmp);
    }
}

// --------------------------------- scan phase 2: full scan + y + gate
__global__ __launch_bounds__(256) void scan2_kernel(
    const float* __restrict__ dl0, const float* __restrict__ dl1,
    const float* __restrict__ u0,  const float* __restrict__ u1,
    const float* __restrict__ Bm0, const float* __restrict__ Bm1,
    const float* __restrict__ Cm0, const float* __restrict__ Cm1,
    const float* __restrict__ zs0, const float* __restrict__ zs1,
    const float* __restrict__ hin, const float* __restrict__ A_log,
    const float* __restrict__ Dp,
    float* __restrict__ yg0, float* __restrict__ yg1, int layer) {
    const int tid = threadIdx.x;
    const int nq = tid & 3, dlane = tid >> 2;
    const int chunk = blockIdx.x & (NC - 1), dtile = blockIdx.x >> 6;
    const int b = blockIdx.y, inst = blockIdx.z;
    const int m = layer * 2 + inst, dir = inst;
    const int d = dtile * 64 + dlane;
    const float* dl = inst ? dl1 : dl0;
    const float* u  = inst ? u1  : u0;
    const float* Bm = inst ? Bm1 : Bm0;
    const float* Cm = inst ? Cm1 : Cm0;
    const float* zs = inst ? zs1 : zs0;
    float* yg = inst ? yg1 : yg0;
    float4 av = *(const float4*)&A_log[((size_t)m * DI + d) * NST + nq * 4];
    const float a0 = -expf(av.x), a1 = -expf(av.y), a2 = -expf(av.z), a3 = -expf(av.w);
    const float dpar = Dp[m * DI + d];
    const int s0 = chunk * Q;
    const int l0 = dir ? (L - 1 - s0) : s0;
    const int stp = dir ? -1 : 1;
    long iDU = ((long)(b * L + l0)) * DI + d;
    int  iB  = ((b * L + l0) << 4) + nq * 4;
    const long sDU = (long)stp * DI;
    const int  sB  = stp * NST;
    float4 hv = *(const float4*)&hin[(((size_t)(inst * 2 + b) * DI + d) * NC + chunk) * NST + nq * 4];
    float h0 = hv.x, h1 = hv.y, h2 = hv.z, h3 = hv.w;
    #pragma unroll 4
    for (int t = 0; t < Q; ++t) {
        float dlt = dl[iDU], uu = u[iDU];
        float4 bm = *(const float4*)&Bm[iB];
        float4 cm = *(const float4*)&Cm[iB];
        float du = dlt * uu;
        h0 = fmaf(__expf(dlt * a0), h0, du * bm.x);
        h1 = fmaf(__expf(dlt * a1), h1, du * bm.y);
        h2 = fmaf(__expf(dlt * a2), h2, du * bm.z);
        h3 = fmaf(__expf(dlt * a3), h3, du * bm.w);
        float yp = h0 * cm.x + h1 * cm.y + h2 * cm.z + h3 * cm.w;
        yp += __shfl_xor(yp, 1, 4);
        yp += __shfl_xor(yp, 2, 4);
        if (nq == 0) {
            float zv = zs[iDU];
            yg[iDU] = fmaf(uu, dpar, yp) * zv;
        }
        iDU += sDU; iB += sB;
    }
}

// ------------------------------- outproj GEMM (both insts) + residual into h
__global__ __launch_bounds__(256) void outproj_kernel(
    const float* __restrict__ yg0, const float* __restrict__ yg1,
    const float* __restrict__ W_out, float* __restrict__ h, int layer) {
    __shared__ float As[32 * 36];
    __shared__ float Bs[32 * 132];
    const int tid = threadIdx.x;
    const int tBase = blockIdx.x * 32;
    const int m00 = (tid & 15) * 2, n0 = (tid >> 4) * 8;
    float acc[2][8] = {};
    for (int inst = 0; inst < 2; ++inst) {
        const float* yg = inst ? yg1 : yg0;
        const float* Wm = W_out + (size_t)(layer * 2 + inst) * COUT * DI;
        for (int kc = 0; kc < 256; kc += 32) {
            {
                int t = tid >> 3, kq = tid & 7;
                float4 v = *(const float4*)&yg[(size_t)(tBase + t) * DI + kc + kq * 4];
                As[(kq * 4 + 0) * 36 + t] = v.x; As[(kq * 4 + 1) * 36 + t] = v.y;
                As[(kq * 4 + 2) * 36 + t] = v.z; As[(kq * 4 + 3) * 36 + t] = v.w;
                int nr = tid >> 1, kq2 = tid & 1;
                const float* wsrc = Wm + (size_t)nr * DI + kc + kq2 * 16;
                #pragma unroll
                for (int q = 0; q < 4; ++q) {
                    float4 wv = *(const float4*)(wsrc + q * 4);
                    int kk = kq2 * 16 + q * 4;
                    Bs[(kk + 0) * 132 + nr] = wv.x; Bs[(kk + 1) * 132 + nr] = wv.y;
                    Bs[(kk + 2) * 132 + nr] = wv.z; Bs[(kk + 3) * 132 + nr] = wv.w;
                }
            }
            __syncthreads();
            #pragma unroll
            for (int kk = 0; kk < 32; ++kk) {
                float2 av = *(const float2*)&As[kk * 36 + m00];
                float4 b0 = *(const float4*)&Bs[kk * 132 + n0];
                float4 b1 = *(const float4*)&Bs[kk * 132 + n0 + 4];
                acc[0][0] = fmaf(av.x, b0.x, acc[0][0]); acc[0][1] = fmaf(av.x, b0.y, acc[0][1]);
                acc[0][2] = fmaf(av.x, b0.z, acc[0][2]); acc[0][3] = fmaf(av.x, b0.w, acc[0][3]);
                acc[0][4] = fmaf(av.x, b1.x, acc[0][4]); acc[0][5] = fmaf(av.x, b1.y, acc[0][5]);
                acc[0][6] = fmaf(av.x, b1.z, acc[0][6]); acc[0][7] = fmaf(av.x, b1.w, acc[0][7]);
                acc[1][0] = fmaf(av.y, b0.x, acc[1][0]); acc[1][1] = fmaf(av.y, b0.y, acc[1][1]);
                acc[1][2] = fmaf(av.y, b0.z, acc[1][2]); acc[1][3] = fmaf(av.y, b0.w, acc[1][3]);
                acc[1][4] = fmaf(av.y, b1.x, acc[1][4]); acc[1][5] = fmaf(av.y, b1.y, acc[1][5]);
                acc[1][6] = fmaf(av.y, b1.z, acc[1][6]); acc[1][7] = fmaf(av.y, b1.w, acc[1][7]);
            }
            __syncthreads();
        }
    }
    #pragma unroll
    for (int im = 0; im < 2; ++im) {
        size_t row = (size_t)(tBase + m00 + im) * COUT + n0;
        float4 h0 = *(const float4*)&h[row];
        float4 h1 = *(const float4*)&h[row + 4];
        h0.x += acc[im][0]; h0.y += acc[im][1]; h0.z += acc[im][2]; h0.w += acc[im][3];
        h1.x += acc[im][4]; h1.y += acc[im][5]; h1.z += acc[im][6]; h1.w += acc[im][7];
        *(float4*)&h[row] = h0;
        *(float4*)&h[row + 4] = h1;
    }
}

// ------------------------------------------------ final [B,L,C] -> [B,C,L]
__global__ __launch_bounds__(256) void transpose_kernel(
    const float* __restrict__ h, float* __restrict__ out) {
    __shared__ float tile[32][33];
    int lt0 = blockIdx.x * 32, ct0 = blockIdx.y * 32, b = blockIdx.z;
    int c = threadIdx.x & 31, r = threadIdx.x >> 5;
    #pragma unroll
    for (int j = 0; j < 4; ++j) {
        int ll = r + 8 * j;
        tile[ll][c] = h[((size_t)b * L + lt0 + ll) * COUT + ct0 + c];
    }
    __syncthreads();
    #pragma unroll
    for (int j = 0; j < 4; ++j) {
        int cc = r + 8 * j;
        out[((size_t)b * COUT + ct0 + cc) * L + lt0 + c] = tile[c][cc];
    }
}

// ======================================================================
extern "C" void kernel_launch(void* const* d_in, const int* in_sizes, int n_in,
                              void* d_out, int out_size, void* d_ws, size_t ws_size,
                              hipStream_t stream) {
    const float* x        = (const float*)d_in[0];
    const float* conv_w   = (const float*)d_in[1];
    const float* conv_b   = (const float*)d_in[2];
    const float* gn_g     = (const float*)d_in[3];
    const float* gn_b     = (const float*)d_in[4];
    const float* prelu_a  = (const float*)d_in[5];
    const float* ln_g     = (const float*)d_in[6];
    const float* ln_b     = (const float*)d_in[7];
    const float* W_in     = (const float*)d_in[8];
    const float* conv1d_w = (const float*)d_in[9];
    const float* conv1d_b = (const float*)d_in[10];
    const float* W_xproj  = (const float*)d_in[11];
    const float* W_dt     = (const float*)d_in[12];
    const float* b_dt     = (const float*)d_in[13];
    const float* A_log    = (const float*)d_in[14];
    const float* D_param  = (const float*)d_in[15];
    const float* W_out    = (const float*)d_in[16];

    float* ws = (float*)d_ws;
    float* h     = ws;                   // [B,L,128]
    float* hn    = ws + 1048576;         // [B,L,128] (aliased: Wt pre-loop, dsumb during scans)
    float* xp0   = ws + 2097152;         // [B,L,256] (reused as yg0)
    float* xp1   = ws + 4194304;         //           (reused as yg1)
    float* z0    = ws + 6291456;         // silu(z) from inproj epilogue
    float* z1    = ws + 8388608;
    float* u0    = ws + 10485760;
    float* u1    = ws + 12582912;
    float* dl0   = ws + 14680064;
    float* dl1   = ws + 16777216;
    float* Bm0   = ws + 18874368;        // [B,L,16]
    float* Bm1   = ws + 19005440;
    float* Cm0   = ws + 19136512;
    float* Cm1   = ws + 19267584;
    float* hend  = ws + 19398656;        // [2,B,256,NC,16] = 1,048,576 (prefix in-place)
    float* stats = ws + 20447232;        // [4]
    float* Wt    = hn;                   // [320,128]
    float* dsumb = hn;                   // [2,B,NC,256] = 65,536 (hn dead during scans)

    zero_stats_kernel<<<1, 64, 0, stream>>>(stats);
    transpose_w_kernel<<<160, 256, 0, stream>>>(conv_w, Wt);
    conv_gemm_kernel<<<dim3(TOK / 64, COUT / 32), 256, 0, stream>>>(x, Wt, conv_b, h, stats);
    gn_prelu_kernel<<<(TOK * COUT / 4) / 256, 256, 0, stream>>>(h, gn_g, gn_b, prelu_a, stats);

    for (int layer = 0; layer < 2; ++layer) {
        ln_kernel<<<TOK / 4, 256, 0, stream>>>(h, hn, ln_g + layer * COUT, ln_b + layer * COUT);
        inproj_kernel<<<dim3(TOK / 64, 16), 256, 0, stream>>>(hn, W_in, xp0, z0, xp1, z1, layer);
        dwconv_kernel<<<(2 * B2 * L * DI) / 256, 256, 0, stream>>>(xp0, xp1, conv1d_w, conv1d_b, u0, u1, layer);
        xproj_kernel<<<dim3(TOK / 32, 2), 256, 0, stream>>>(u0, u1, W_xproj, W_dt, b_dt,
                                                            dl0, dl1, Bm0, Bm1, Cm0, Cm1, layer);
        scan1_kernel<<<dim3(NC * 4, B2, 2), 256, 0, stream>>>(dl0, dl1, u0, u1, Bm0, Bm1,
                                                              A_log, hend, dsumb, layer);
        combine_kernel<<<64, 256, 0, stream>>>(hend, dsumb, A_log, layer);
        scan2_kernel<<<dim3(NC * 4, B2, 2), 256, 0, stream>>>(dl0, dl1, u0, u1, Bm0, Bm1, Cm0, Cm1,
                                                              z0, z1, hend, A_log, D_param,
                                                              xp0, xp1, layer);
        outproj_kernel<<<TOK / 32, 256, 0, stream>>>(xp0, xp1, W_out, h, layer);
    }
    transpose_kernel<<<dim3(L / 32, COUT / 32, B2), 256, 0, stream>>>(h, (float*)d_out);
}

// Round 9
// 464.537 us; speedup vs baseline: 1.6562x; 1.0801x over previous
//
#include <hip/hip_runtime.h>
#include <hip/hip_bf16.h>
#include <math.h>

// ---- problem dims ----
constexpr int B2   = 2;
constexpr int CIN  = 64;
constexpr int COUT = 128;
constexpr int T    = 8192;
constexpr int L    = 4096;     // T/2
constexpr int DI   = 256;
constexpr int NST  = 16;       // d_state
constexpr int DTR  = 8;
constexpr int Q    = 64;       // scan chunk length
constexpr int NC   = 64;       // L / Q
constexpr int TOK  = B2 * L;   // 8192 tokens

typedef __attribute__((ext_vector_type(8))) short bf16x8s;   // 8 bf16 (4 VGPRs)
typedef __attribute__((ext_vector_type(4))) float f32x4;

__device__ __forceinline__ float sigmoidf_(float x) { return 1.f / (1.f + __expf(-x)); }
__device__ __forceinline__ unsigned short f2bf(float f) {
    unsigned int u = __float_as_uint(f);
    unsigned int r = (u + 0x7FFFu + ((u >> 16) & 1u)) >> 16;
    return (unsigned short)r;
}

// ---------------------------------------------------------------- zero stats
__global__ __launch_bounds__(64) void zero_stats_kernel(float* stats) {
    if (threadIdx.x < 4) stats[threadIdx.x] = 0.f;
}

// ---------------- conv weight reorder+convert: cw[co][ci][kp] -> Wrb[co][kp*64+ci] (bf16)
__global__ __launch_bounds__(256) void wconv_prep_kernel(
    const float* __restrict__ cw, unsigned short* __restrict__ Wrb) {
    int idx = blockIdx.x * 256 + threadIdx.x;     // 40960
    int co = idx / 320, r = idx % 320;
    int kp = r >> 6, ci = r & 63;
    Wrb[idx] = f2bf(cw[co * 320 + ci * 5 + kp]);
}

// ---------------- W_in convert to bf16 (row-major [m][e][k] unchanged)
__global__ __launch_bounds__(256) void win_prep_kernel(
    const float* __restrict__ W_in, unsigned short* __restrict__ Winb) {
    int idx = blockIdx.x * 256 + threadIdx.x;     // 262144
    Winb[idx] = f2bf(W_in[idx]);
}

// ---------------- x transpose+convert: x[b][ci][t] -> xTb[b][t][ci] (bf16)
__global__ __launch_bounds__(256) void xpose_kernel(
    const float* __restrict__ x, unsigned short* __restrict__ xTb) {
    __shared__ float tile[64][65];
    int b = blockIdx.y, tb = blockIdx.x * 64, tid = threadIdx.x;
    #pragma unroll
    for (int i = 0; i < 16; ++i) {
        int idx = i * 256 + tid; int ci = idx >> 6, tt = idx & 63;
        tile[ci][tt] = x[((size_t)b * CIN + ci) * T + tb + tt];
    }
    __syncthreads();
    #pragma unroll
    for (int i = 0; i < 16; ++i) {
        int idx = i * 256 + tid; int tt = idx >> 6, ci = idx & 63;
        xTb[((size_t)b * T + tb + tt) * 64 + ci] = f2bf(tile[ci][tt]);
    }
}

// ---------------- conv1d stride2 as bf16-MFMA implicit GEMM + GN stats
// A[t][kidx]=xT[2l+kp-2][ci] (kidx=kp*64+ci), B[kidx][co]=Wrb[co][kidx].
// Block: 4 waves x 16 tok, 64 cout. grid (TOK/64, COUT/64).
__global__ __launch_bounds__(256) void conv_mfma_kernel(
    const unsigned short* __restrict__ xTb, const unsigned short* __restrict__ Wrb,
    const float* __restrict__ cb, float* __restrict__ h, float* __restrict__ stats) {
    const int tid = threadIdx.x;
    const int w = tid >> 6, lane = tid & 63, q = lane >> 4, c = lane & 15;
    const int t0g = blockIdx.x * 64;
    const int t0  = t0g + w * 16;
    const int ct0 = blockIdx.y * 64;
    const int b   = t0g >> 12;
    const int l   = (t0 + c) & (L - 1);
    f32x4 acc[4] = {};
    for (int kc = 0; kc < 320; kc += 32) {
        int kp  = kc >> 6;                    // (kc%64 + q*8) < 64 always
        int ci0 = (kc & 63) + q * 8;
        int p = 2 * l + kp - 2;
        bf16x8s a = {};
        if (p >= 0 && p < T)
            a = *(const bf16x8s*)&xTb[((size_t)b * T + p) * 64 + ci0];
        #pragma unroll
        for (int i = 0; i < 4; ++i) {
            bf16x8s bb = *(const bf16x8s*)&Wrb[(size_t)(ct0 + i * 16 + c) * 320 + kc + q * 8];
            acc[i] = __builtin_amdgcn_mfma_f32_16x16x32_bf16(a, bb, acc[i], 0, 0, 0);
        }
    }
    float s = 0.f, ss = 0.f;
    #pragma unroll
    for (int i = 0; i < 4; ++i) {
        int cout = ct0 + i * 16 + c;
        float bias = cb[cout];
        #pragma unroll
        for (int r = 0; r < 4; ++r) {
            int tok = t0 + q * 4 + r;
            float v = acc[i][r] + bias;
            h[(size_t)tok * COUT + cout] = v;
            s += v; ss += v * v;
        }
    }
    #pragma unroll
    for (int off = 32; off; off >>= 1) {
        s  += __shfl_down(s,  off, 64);
        ss += __shfl_down(ss, off, 64);
    }
    if (lane == 0) {
        atomicAdd(&stats[b * 2 + 0], s);
        atomicAdd(&stats[b * 2 + 1], ss);
    }
}

// ------------------------------------------------------ GN apply + PReLU
__global__ __launch_bounds__(256) void gn_prelu_kernel(
    float* __restrict__ h, const float* __restrict__ gn_g,
    const float* __restrict__ gn_b, const float* __restrict__ prelu_a,
    const float* __restrict__ stats) {
    int i = blockIdx.x * 256 + threadIdx.x;      // 262144 threads, x4 elements
    size_t base = (size_t)i * 4;
    int b = (base >= (size_t)L * COUT) ? 1 : 0;
    const float n = (float)(L * COUT);
    float mu   = stats[b * 2 + 0] / n;
    float var  = stats[b * 2 + 1] / n - mu * mu;
    float rstd = rsqrtf(var + 1e-5f);
    float a = prelu_a[0];
    float4 v = *(const float4*)&h[base];
    int c = (int)(base % COUT);
    float4 g  = *(const float4*)&gn_g[c];
    float4 bb = *(const float4*)&gn_b[c];
    v.x = (v.x - mu) * rstd * g.x + bb.x; v.x = v.x >= 0.f ? v.x : a * v.x;
    v.y = (v.y - mu) * rstd * g.y + bb.y; v.y = v.y >= 0.f ? v.y : a * v.y;
    v.z = (v.z - mu) * rstd * g.z + bb.z; v.z = v.z >= 0.f ? v.z : a * v.z;
    v.w = (v.w - mu) * rstd * g.w + bb.w; v.w = v.w >= 0.f ? v.w : a * v.w;
    *(float4*)&h[base] = v;
}

// ------------------------------------------------------ per-token LayerNorm -> bf16
__global__ __launch_bounds__(256) void ln_kernel(
    const float* __restrict__ h, unsigned short* __restrict__ hnb,
    const float* __restrict__ g, const float* __restrict__ bta) {
    int wave = threadIdx.x >> 6, lane = threadIdx.x & 63;
    int t = blockIdx.x * 4 + wave;
    const float* row = h + (size_t)t * COUT;
    float2 v = *(const float2*)&row[lane * 2];
    float s = v.x + v.y, ss = v.x * v.x + v.y * v.y;
    #pragma unroll
    for (int off = 32; off; off >>= 1) {
        s  += __shfl_xor(s,  off, 64);
        ss += __shfl_xor(ss, off, 64);
    }
    float mu = s * (1.f / 128.f);
    float var = ss * (1.f / 128.f) - mu * mu;
    float rstd = rsqrtf(var + 1e-5f);
    float2 gg = *(const float2*)&g[lane * 2];
    float2 bb = *(const float2*)&bta[lane * 2];
    ushort2 o;
    o.x = f2bf((v.x - mu) * rstd * gg.x + bb.x);
    o.y = f2bf((v.y - mu) * rstd * gg.y + bb.y);
    *(ushort2*)&hnb[(size_t)t * COUT + lane * 2] = o;
}

// ---------------- inproj as bf16-MFMA GEMM  M=8192 K=128 N=1024 (2 inst x 512)
// Block: 4 waves x 16 tok, 64 e. grid (TOK/64, 16). SiLU on z-half epilogue.
__global__ __launch_bounds__(256) void inproj_mfma_kernel(
    const unsigned short* __restrict__ hnb, const unsigned short* __restrict__ Winb,
    float* __restrict__ xp0, float* __restrict__ z0,
    float* __restrict__ xp1, float* __restrict__ z1, int layer) {
    const int tid = threadIdx.x;
    const int w = tid >> 6, lane = tid & 63, q = lane >> 4, c = lane & 15;
    const int t0 = blockIdx.x * 64 + w * 16;
    const int nBase = blockIdx.y * 64;
    const int inst = nBase >> 9;
    const int e0 = nBase & 511;
    const unsigned short* Wb = Winb + (size_t)(layer * 2 + inst) * 512 * 128;
    f32x4 acc[4] = {};
    for (int kc = 0; kc < 128; kc += 32) {
        bf16x8s a = *(const bf16x8s*)&hnb[(size_t)(t0 + c) * 128 + kc + q * 8];
        #pragma unroll
        for (int i = 0; i < 4; ++i) {
            bf16x8s bb = *(const bf16x8s*)&Wb[(size_t)(e0 + i * 16 + c) * 128 + kc + q * 8];
            acc[i] = __builtin_amdgcn_mfma_f32_16x16x32_bf16(a, bb, acc[i], 0, 0, 0);
        }
    }
    #pragma unroll
    for (int i = 0; i < 4; ++i) {
        int e = e0 + i * 16 + c;
        bool isz = (e >= 256);
        float* dst = isz ? (inst ? z1 : z0) : (inst ? xp1 : xp0);
        int eo = e & 255;
        #pragma unroll
        for (int r = 0; r < 4; ++r) {
            int tok = t0 + q * 4 + r;
            float v = acc[i][r];
            if (isz) v *= sigmoidf_(v);
            dst[(size_t)tok * DI + eo] = v;
        }
    }
}

// ---------------------------------------- depthwise causal conv (d=4) + SiLU
__global__ __launch_bounds__(256) void dwconv_kernel(
    const float* __restrict__ xp0, const float* __restrict__ xp1,
    const float* __restrict__ cw, const float* __restrict__ cbias,
    float* __restrict__ u0, float* __restrict__ u1, int layer) {
    int flat = blockIdx.x * 256 + threadIdx.x;
    int d    = flat & 255;
    int l    = (flat >> 8) & (L - 1);
    int b    = (flat >> 20) & 1;
    int inst = flat >> 21;
    const float* xp = inst ? xp1 : xp0;
    float* u = inst ? u1 : u0;
    int m = layer * 2 + inst;
    const float4 w4 = *(const float4*)&cw[(size_t)(m * DI + d) * 4];
    float acc = cbias[m * DI + d];
    size_t base = ((size_t)b * L) * DI + d;
    if (inst == 0) {  // forward: taps l-3..l, weights w[0]..w[3]
        if (l - 3 >= 0) acc = fmaf(w4.x, xp[base + (size_t)(l - 3) * DI], acc);
        if (l - 2 >= 0) acc = fmaf(w4.y, xp[base + (size_t)(l - 2) * DI], acc);
        if (l - 1 >= 0) acc = fmaf(w4.z, xp[base + (size_t)(l - 1) * DI], acc);
        acc = fmaf(w4.w, xp[base + (size_t)l * DI], acc);
    } else {          // backward (natural coords): taps l..l+3, w[3]..w[0]
        acc = fmaf(w4.w, xp[base + (size_t)l * DI], acc);
        if (l + 1 < L) acc = fmaf(w4.z, xp[base + (size_t)(l + 1) * DI], acc);
        if (l + 2 < L) acc = fmaf(w4.y, xp[base + (size_t)(l + 2) * DI], acc);
        if (l + 3 < L) acc = fmaf(w4.x, xp[base + (size_t)(l + 3) * DI], acc);
    }
    u[base + (size_t)l * DI] = acc * sigmoidf_(acc);
}

// ------------------------------------- xproj as GEMM (M=32tok/blk, N=40, K=256)
__global__ __launch_bounds__(256) void xproj_kernel(
    const float* __restrict__ u0, const float* __restrict__ u1,
    const float* __restrict__ Wx, const float* __restrict__ Wdt,
    const float* __restrict__ bdt,
    float* __restrict__ dl0, float* __restrict__ dl1,
    float* __restrict__ Bm0, float* __restrict__ Bm1,
    float* __restrict__ Cm0, float* __restrict__ Cm1, int layer) {
    __shared__ float Ws[40 * 132];   // [e][k-sub] current K slab
    __shared__ float As[128 * 33];   // [k][t] half-K u tile
    __shared__ float xd[32 * 9];     // dt outputs
    const int tid   = threadIdx.x;
    const int tBase = blockIdx.x * 32;
    const int inst  = blockIdx.y;
    const int m     = layer * 2 + inst;
    const float* u  = inst ? u1 : u0;
    const float* Wm = Wx + (size_t)m * 40 * 256;
    const int t  = tid & 31;
    const int eq = tid >> 5;                // 0..7
    float acc[5] = {};
    for (int kc = 0; kc < 256; kc += 128) {
        __syncthreads();
        #pragma unroll
        for (int i = 0; i < 5; ++i) {
            int idx = i * 256 + tid;
            int e = idx >> 5, kq = idx & 31;
            float4 w4 = *(const float4*)&Wm[(size_t)e * 256 + kc + kq * 4];
            float* dstw = &Ws[e * 132 + kq * 4];
            dstw[0] = w4.x; dstw[1] = w4.y; dstw[2] = w4.z; dstw[3] = w4.w;
        }
        #pragma unroll
        for (int i = 0; i < 4; ++i) {
            int flat = i * 256 + tid;
            int tt = flat >> 5, kq = flat & 31;
            float4 v = *(const float4*)&u[(size_t)(tBase + tt) * DI + kc + kq * 4];
            As[(kq * 4 + 0) * 33 + tt] = v.x;
            As[(kq * 4 + 1) * 33 + tt] = v.y;
            As[(kq * 4 + 2) * 33 + tt] = v.z;
            As[(kq * 4 + 3) * 33 + tt] = v.w;
        }
        __syncthreads();
        #pragma unroll 4
        for (int kk = 0; kk < 128; ++kk) {
            float a = As[kk * 33 + t];
            acc[0] = fmaf(a, Ws[(eq     ) * 132 + kk], acc[0]);
            acc[1] = fmaf(a, Ws[(eq +  8) * 132 + kk], acc[1]);
            acc[2] = fmaf(a, Ws[(eq + 16) * 132 + kk], acc[2]);
            acc[3] = fmaf(a, Ws[(eq + 24) * 132 + kk], acc[3]);
            acc[4] = fmaf(a, Ws[(eq + 32) * 132 + kk], acc[4]);
        }
    }
    {
        int tok = tBase + t;
        float* Bm = inst ? Bm1 : Bm0;
        float* Cm = inst ? Cm1 : Cm0;
        xd[t * 9 + eq] = acc[0];
        Bm[(size_t)tok * NST + eq]     = acc[1];
        Bm[(size_t)tok * NST + 8 + eq] = acc[2];
        Cm[(size_t)tok * NST + eq]     = acc[3];
        Cm[(size_t)tok * NST + 8 + eq] = acc[4];
    }
    __syncthreads();
    {
        int d = tid;
        float wr[8];
        #pragma unroll
        for (int r = 0; r < 8; ++r) wr[r] = Wdt[((size_t)m * DI + d) * DTR + r];
        float bb = bdt[m * DI + d];
        float* dl = inst ? dl1 : dl0;
        #pragma unroll 4
        for (int tt = 0; tt < 32; ++tt) {
            float a2 = bb;
            #pragma unroll
            for (int r = 0; r < 8; ++r) a2 = fmaf(xd[tt * 9 + r], wr[r], a2);
            float sp = fmaxf(a2, 0.f) + __logf(1.f + __expf(-fabsf(a2)));
            dl[(size_t)(tBase + tt) * DI + d] = sp;
        }
    }
}

// ---------------------------------------------- scan phase 1: chunk-local
__global__ __launch_bounds__(256) void scan1_kernel(
    const float* __restrict__ dl0, const float* __restrict__ dl1,
    const float* __restrict__ u0,  const float* __restrict__ u1,
    const float* __restrict__ Bm0, const float* __restrict__ Bm1,
    const float* __restrict__ A_log,
    float* __restrict__ hend, float* __restrict__ dsumb, int layer) {
    const int tid = threadIdx.x;
    const int nq = tid & 3, dlane = tid >> 2;
    const int chunk = blockIdx.x & (NC - 1), dtile = blockIdx.x >> 6;
    const int b = blockIdx.y, inst = blockIdx.z;
    const int m = layer * 2 + inst, dir = inst;
    const int d = dtile * 64 + dlane;
    const float* dl = inst ? dl1 : dl0;
    const float* u  = inst ? u1  : u0;
    const float* Bm = inst ? Bm1 : Bm0;
    float4 av = *(const float4*)&A_log[((size_t)m * DI + d) * NST + nq * 4];
    const float a0 = -expf(av.x), a1 = -expf(av.y), a2 = -expf(av.z), a3 = -expf(av.w);
    const int s0 = chunk * Q;
    const int l0 = dir ? (L - 1 - s0) : s0;
    const int stp = dir ? -1 : 1;
    long iDU = ((long)(b * L + l0)) * DI + d;
    int  iB  = ((b * L + l0) << 4) + nq * 4;
    const long sDU = (long)stp * DI;
    const int  sB  = stp * NST;
    float h0 = 0.f, h1 = 0.f, h2 = 0.f, h3 = 0.f, dsum = 0.f;
    #pragma unroll 4
    for (int t = 0; t < Q; ++t) {
        float dlt = dl[iDU], uu = u[iDU];
        float4 bm = *(const float4*)&Bm[iB];
        float du = dlt * uu;
        h0 = fmaf(__expf(dlt * a0), h0, du * bm.x);
        h1 = fmaf(__expf(dlt * a1), h1, du * bm.y);
        h2 = fmaf(__expf(dlt * a2), h2, du * bm.z);
        h3 = fmaf(__expf(dlt * a3), h3, du * bm.w);
        dsum += dlt;
        iDU += sDU; iB += sB;
    }
    size_t oh = (((size_t)(inst * 2 + b) * DI + d) * NC + chunk) * NST + nq * 4;
    *(float4*)&hend[oh] = make_float4(h0, h1, h2, h3);
    if (nq == 0) dsumb[((size_t)(inst * 2 + b) * NC + chunk) * DI + d] = dsum;
}

// ---------------------------------------------- scan combine (in-place prefix)
__global__ __launch_bounds__(256) void combine_kernel(
    float* __restrict__ hend, const float* __restrict__ dsumb,
    const float* __restrict__ A_log, int layer) {
    int flat = blockIdx.x * 256 + threadIdx.x;   // 16384
    int n = flat & 15;
    int d = (flat >> 4) & 255;
    int b = (flat >> 12) & 1;
    int inst = flat >> 13;
    int m = layer * 2 + inst;
    float a = -expf(A_log[((size_t)m * DI + d) * NST + n]);
    size_t baseE = (((size_t)(inst * 2 + b) * DI + d) * NC) * NST + n;
    size_t baseD = ((size_t)(inst * 2 + b) * NC) * DI + d;
    float hc = 0.f;
    for (int c = 0; c < NC; ++c) {
        float tmp = hend[baseE + (size_t)c * NST];
        hend[baseE + (size_t)c * NST] = hc;
        float ds = dsumb[baseD + (size_t)c * DI];
        hc = fmaf(__expf(a * ds), hc, tmp);
    }
}

// --------------------------------- scan phase 2: full scan + y + gate
__global__ __launch_bounds__(256) void scan2_kernel(
    const float* __restrict__ dl0, const float* __restrict__ dl1,
    const float* __restrict__ u0,  const float* __restrict__ u1,
    const float* __restrict__ Bm0, const float* __restrict__ Bm1,
    const float* __restrict__ Cm0, const float* __restrict__ Cm1,
    const float* __restrict__ zs0, const float* __restrict__ zs1,
    const float* __restrict__ hin, const float* __restrict__ A_log,
    const float* __restrict__ Dp,
    float* __restrict__ yg0, float* __restrict__ yg1, int layer) {
    const int tid = threadIdx.x;
    const int nq = tid & 3, dlane = tid >> 2;
    const int chunk = blockIdx.x & (NC - 1), dtile = blockIdx.x >> 6;
    const int b = blockIdx.y, inst = blockIdx.z;
    const int m = layer * 2 + inst, dir = inst;
    const int d = dtile * 64 + dlane;
    const float* dl = inst ? dl1 : dl0;
    const float* u  = inst ? u1  : u0;
    const float* Bm = inst ? Bm1 : Bm0;
    const float* Cm = inst ? Cm1 : Cm0;
    const float* zs = inst ? zs1 : zs0;
    float* yg = inst ? yg1 : yg0;
    float4 av = *(const float4*)&A_log[((size_t)m * DI + d) * NST + nq * 4];
    const float a0 = -expf(av.x), a1 = -expf(av.y), a2 = -expf(av.z), a3 = -expf(av.w);
    const float dpar = Dp[m * DI + d];
    const int s0 = chunk * Q;
    const int l0 = dir ? (L - 1 - s0) : s0;
    const int stp = dir ? -1 : 1;
    long iDU = ((long)(b * L + l0)) * DI + d;
    int  iB  = ((b * L + l0) << 4) + nq * 4;
    const long sDU = (long)stp * DI;
    const int  sB  = stp * NST;
    float4 hv = *(const float4*)&hin[(((size_t)(inst * 2 + b) * DI + d) * NC + chunk) * NST + nq * 4];
    float h0 = hv.x, h1 = hv.y, h2 = hv.z, h3 = hv.w;
    #pragma unroll 4
    for (int t = 0; t < Q; ++t) {
        float dlt = dl[iDU], uu = u[iDU];
        float4 bm = *(const float4*)&Bm[iB];
        float4 cm = *(const float4*)&Cm[iB];
        float du = dlt * uu;
        h0 = fmaf(__expf(dlt * a0), h0, du * bm.x);
        h1 = fmaf(__expf(dlt * a1), h1, du * bm.y);
        h2 = fmaf(__expf(dlt * a2), h2, du * bm.z);
        h3 = fmaf(__expf(dlt * a3), h3, du * bm.w);
        float yp = h0 * cm.x + h1 * cm.y + h2 * cm.z + h3 * cm.w;
        yp += __shfl_xor(yp, 1, 4);
        yp += __shfl_xor(yp, 2, 4);
        if (nq == 0) {
            float zv = zs[iDU];
            yg[iDU] = fmaf(uu, dpar, yp) * zv;
        }
        iDU += sDU; iB += sB;
    }
}

// ------------------------------- outproj GEMM (both insts) + residual into h
__global__ __launch_bounds__(256) void outproj_kernel(
    const float* __restrict__ yg0, const float* __restrict__ yg1,
    const float* __restrict__ W_out, float* __restrict__ h, int layer) {
    __shared__ float As[32 * 36];
    __shared__ float Bs[32 * 132];
    const int tid = threadIdx.x;
    const int tBase = blockIdx.x * 32;
    const int m00 = (tid & 15) * 2, n0 = (tid >> 4) * 8;
    float acc[2][8] = {};
    for (int inst = 0; inst < 2; ++inst) {
        const float* yg = inst ? yg1 : yg0;
        const float* Wm = W_out + (size_t)(layer * 2 + inst) * COUT * DI;
        for (int kc = 0; kc < 256; kc += 32) {
            {
                int t = tid >> 3, kq = tid & 7;
                float4 v = *(const float4*)&yg[(size_t)(tBase + t) * DI + kc + kq * 4];
                As[(kq * 4 + 0) * 36 + t] = v.x; As[(kq * 4 + 1) * 36 + t] = v.y;
                As[(kq * 4 + 2) * 36 + t] = v.z; As[(kq * 4 + 3) * 36 + t] = v.w;
                int nr = tid >> 1, kq2 = tid & 1;
                const float* wsrc = Wm + (size_t)nr * DI + kc + kq2 * 16;
                #pragma unroll
                for (int q2 = 0; q2 < 4; ++q2) {
                    float4 wv = *(const float4*)(wsrc + q2 * 4);
                    int kk = kq2 * 16 + q2 * 4;
                    Bs[(kk + 0) * 132 + nr] = wv.x; Bs[(kk + 1) * 132 + nr] = wv.y;
                    Bs[(kk + 2) * 132 + nr] = wv.z; Bs[(kk + 3) * 132 + nr] = wv.w;
                }
            }
            __syncthreads();
            #pragma unroll
            for (int kk = 0; kk < 32; ++kk) {
                float2 av = *(const float2*)&As[kk * 36 + m00];
                float4 b0 = *(const float4*)&Bs[kk * 132 + n0];
                float4 b1 = *(const float4*)&Bs[kk * 132 + n0 + 4];
                acc[0][0] = fmaf(av.x, b0.x, acc[0][0]); acc[0][1] = fmaf(av.x, b0.y, acc[0][1]);
                acc[0][2] = fmaf(av.x, b0.z, acc[0][2]); acc[0][3] = fmaf(av.x, b0.w, acc[0][3]);
                acc[0][4] = fmaf(av.x, b1.x, acc[0][4]); acc[0][5] = fmaf(av.x, b1.y, acc[0][5]);
                acc[0][6] = fmaf(av.x, b1.z, acc[0][6]); acc[0][7] = fmaf(av.x, b1.w, acc[0][7]);
                acc[1][0] = fmaf(av.y, b0.x, acc[1][0]); acc[1][1] = fmaf(av.y, b0.y, acc[1][1]);
                acc[1][2] = fmaf(av.y, b0.z, acc[1][2]); acc[1][3] = fmaf(av.y, b0.w, acc[1][3]);
                acc[1][4] = fmaf(av.y, b1.x, acc[1][4]); acc[1][5] = fmaf(av.y, b1.y, acc[1][5]);
                acc[1][6] = fmaf(av.y, b1.z, acc[1][6]); acc[1][7] = fmaf(av.y, b1.w, acc[1][7]);
            }
            __syncthreads();
        }
    }
    #pragma unroll
    for (int im = 0; im < 2; ++im) {
        size_t row = (size_t)(tBase + m00 + im) * COUT + n0;
        float4 h0 = *(const float4*)&h[row];
        float4 h1 = *(const float4*)&h[row + 4];
        h0.x += acc[im][0]; h0.y += acc[im][1]; h0.z += acc[im][2]; h0.w += acc[im][3];
        h1.x += acc[im][4]; h1.y += acc[im][5]; h1.z += acc[im][6]; h1.w += acc[im][7];
        *(float4*)&h[row] = h0;
        *(float4*)&h[row + 4] = h1;
    }
}

// ------------------------------------------------ final [B,L,C] -> [B,C,L]
__global__ __launch_bounds__(256) void transpose_kernel(
    const float* __restrict__ h, float* __restrict__ out) {
    __shared__ float tile[32][33];
    int lt0 = blockIdx.x * 32, ct0 = blockIdx.y * 32, b = blockIdx.z;
    int c = threadIdx.x & 31, r = threadIdx.x >> 5;
    #pragma unroll
    for (int j = 0; j < 4; ++j) {
        int ll = r + 8 * j;
        tile[ll][c] = h[((size_t)b * L + lt0 + ll) * COUT + ct0 + c];
    }
    __syncthreads();
    #pragma unroll
    for (int j = 0; j < 4; ++j) {
        int cc = r + 8 * j;
        out[((size_t)b * COUT + ct0 + cc) * L + lt0 + c] = tile[c][cc];
    }
}

// ======================================================================
extern "C" void kernel_launch(void* const* d_in, const int* in_sizes, int n_in,
                              void* d_out, int out_size, void* d_ws, size_t ws_size,
                              hipStream_t stream) {
    const float* x        = (const float*)d_in[0];
    const float* conv_w   = (const float*)d_in[1];
    const float* conv_b   = (const float*)d_in[2];
    const float* gn_g     = (const float*)d_in[3];
    const float* gn_b     = (const float*)d_in[4];
    const float* prelu_a  = (const float*)d_in[5];
    const float* ln_g     = (const float*)d_in[6];
    const float* ln_b     = (const float*)d_in[7];
    const float* W_in     = (const float*)d_in[8];
    const float* conv1d_w = (const float*)d_in[9];
    const float* conv1d_b = (const float*)d_in[10];
    const float* W_xproj  = (const float*)d_in[11];
    const float* W_dt     = (const float*)d_in[12];
    const float* b_dt     = (const float*)d_in[13];
    const float* A_log    = (const float*)d_in[14];
    const float* D_param  = (const float*)d_in[15];
    const float* W_out    = (const float*)d_in[16];

    float* ws = (float*)d_ws;
    float* h     = ws;                   // [B,L,128]
    float* hnblk = ws + 1048576;         // block reused: hnb bf16 / dsumb / Wrb / Winb
    float* xp0   = ws + 2097152;         // [B,L,256] (reused as yg0)
    float* xp1   = ws + 4194304;         //           (reused as yg1)
    float* z0    = ws + 6291456;         // silu(z) from inproj epilogue (xTb aliased pre-loop)
    float* z1    = ws + 8388608;
    float* u0    = ws + 10485760;
    float* u1    = ws + 12582912;
    float* dl0   = ws + 14680064;
    float* dl1   = ws + 16777216;
    float* Bm0   = ws + 18874368;        // [B,L,16]
    float* Bm1   = ws + 19005440;
    float* Cm0   = ws + 19136512;
    float* Cm1   = ws + 19267584;
    float* hend  = ws + 19398656;        // [2,B,256,NC,16] = 1,048,576 (prefix in-place)
    float* stats = ws + 20447232;        // [4]

    unsigned short* hnb  = (unsigned short*)hnblk;               // 1M bf16 = 524288 f
    float*          dsumb = hnblk + 524288;                      // 65536 f
    unsigned short* Wrb  = (unsigned short*)(hnblk + 589824);    // 40960 bf16
    unsigned short* Winb = (unsigned short*)(hnblk + 610304);    // 262144 bf16
    unsigned short* xTb  = (unsigned short*)z0;                  // 1M bf16 (dead before inproj writes z0)

    zero_stats_kernel<<<1, 64, 0, stream>>>(stats);
    wconv_prep_kernel<<<160, 256, 0, stream>>>(conv_w, Wrb);
    win_prep_kernel<<<1024, 256, 0, stream>>>(W_in, Winb);
    xpose_kernel<<<dim3(T / 64, B2), 256, 0, stream>>>(x, xTb);
    conv_mfma_kernel<<<dim3(TOK / 64, COUT / 64), 256, 0, stream>>>(xTb, Wrb, conv_b, h, stats);
    gn_prelu_kernel<<<(TOK * COUT / 4) / 256, 256, 0, stream>>>(h, gn_g, gn_b, prelu_a, stats);

    for (int layer = 0; layer < 2; ++layer) {
        ln_kernel<<<TOK / 4, 256, 0, stream>>>(h, hnb, ln_g + layer * COUT, ln_b + layer * COUT);
        inproj_mfma_kernel<<<dim3(TOK / 64, 16), 256, 0, stream>>>(hnb, Winb, xp0, z0, xp1, z1, layer);
        dwconv_kernel<<<(2 * B2 * L * DI) / 256, 256, 0, stream>>>(xp0, xp1, conv1d_w, conv1d_b, u0, u1, layer);
        xproj_kernel<<<dim3(TOK / 32, 2), 256, 0, stream>>>(u0, u1, W_xproj, W_dt, b_dt,
                                                            dl0, dl1, Bm0, Bm1, Cm0, Cm1, layer);
        scan1_kernel<<<dim3(NC * 4, B2, 2), 256, 0, stream>>>(dl0, dl1, u0, u1, Bm0, Bm1,
                                                              A_log, hend, dsumb, layer);
        combine_kernel<<<64, 256, 0, stream>>>(hend, dsumb, A_log, layer);
        scan2_kernel<<<dim3(NC * 4, B2, 2), 256, 0, stream>>>(dl0, dl1, u0, u1, Bm0, Bm1, Cm0, Cm1,
                                                              z0, z1, hend, A_log, D_param,
                                                              xp0, xp1, layer);
        outproj_kernel<<<TOK / 32, 256, 0, stream>>>(xp0, xp1, W_out, h, layer);
    }
    transpose_kernel<<<dim3(L / 32, COUT / 32, B2), 256, 0, stream>>>(h, (float*)d_out);
}

// Round 11
// 454.810 us; speedup vs baseline: 1.6917x; 1.0214x over previous
//
#include <hip/hip_runtime.h>
#include <hip/hip_bf16.h>
#include <math.h>

// ---- problem dims ----
constexpr int B2   = 2;
constexpr int CIN  = 64;
constexpr int COUT = 128;
constexpr int T    = 8192;
constexpr int L    = 4096;     // T/2
constexpr int DI   = 256;
constexpr int NST  = 16;       // d_state
constexpr int DTR  = 8;
constexpr int Q    = 32;       // scan chunk length
constexpr int NC   = 128;      // L / Q
constexpr int TOK  = B2 * L;   // 8192 tokens

typedef __attribute__((ext_vector_type(8))) short bf16x8s;   // 8 bf16 (4 VGPRs)
typedef __attribute__((ext_vector_type(4))) float f32x4;

__device__ __forceinline__ float sigmoidf_(float x) { return 1.f / (1.f + __expf(-x)); }
__device__ __forceinline__ unsigned short f2bf(float f) {
    unsigned int u = __float_as_uint(f);
    unsigned int r = (u + 0x7FFFu + ((u >> 16) & 1u)) >> 16;
    return (unsigned short)r;
}
__device__ __forceinline__ float bf2f(unsigned short s) {
    return __uint_as_float((unsigned int)s << 16);
}

// ---------------------------------------------------------------- zero stats
__global__ __launch_bounds__(64) void zero_stats_kernel(float* stats) {
    if (threadIdx.x < 4) stats[threadIdx.x] = 0.f;
}

// ---------------- conv weight reorder+convert: cw[co][ci][kp] -> Wrb[co][kp*64+ci] (bf16)
__global__ __launch_bounds__(256) void wconv_prep_kernel(
    const float* __restrict__ cw, unsigned short* __restrict__ Wrb) {
    int idx = blockIdx.x * 256 + threadIdx.x;     // 40960
    int co = idx / 320, r = idx % 320;
    int kp = r >> 6, ci = r & 63;
    Wrb[idx] = f2bf(cw[co * 320 + ci * 5 + kp]);
}

// ---------------- W_in convert to bf16 (row-major [m][e][k] unchanged)
__global__ __launch_bounds__(256) void win_prep_kernel(
    const float* __restrict__ W_in, unsigned short* __restrict__ Winb) {
    int idx = blockIdx.x * 256 + threadIdx.x;     // 262144
    Winb[idx] = f2bf(W_in[idx]);
}

// ---------------- x transpose+convert: x[b][ci][t] -> xTb[b][t][ci] (bf16)
__global__ __launch_bounds__(256) void xpose_kernel(
    const float* __restrict__ x, unsigned short* __restrict__ xTb) {
    __shared__ float tile[64][65];
    int b = blockIdx.y, tb = blockIdx.x * 64, tid = threadIdx.x;
    #pragma unroll
    for (int i = 0; i < 16; ++i) {
        int idx = i * 256 + tid; int ci = idx >> 6, tt = idx & 63;
        tile[ci][tt] = x[((size_t)b * CIN + ci) * T + tb + tt];
    }
    __syncthreads();
    #pragma unroll
    for (int i = 0; i < 16; ++i) {
        int idx = i * 256 + tid; int tt = idx >> 6, ci = idx & 63;
        xTb[((size_t)b * T + tb + tt) * 64 + ci] = f2bf(tile[ci][tt]);
    }
}

// ---------------- conv1d stride2 as bf16-MFMA implicit GEMM + GN stats
__global__ __launch_bounds__(256) void conv_mfma_kernel(
    const unsigned short* __restrict__ xTb, const unsigned short* __restrict__ Wrb,
    const float* __restrict__ cb, float* __restrict__ h, float* __restrict__ stats) {
    const int tid = threadIdx.x;
    const int w = tid >> 6, lane = tid & 63, q = lane >> 4, c = lane & 15;
    const int t0g = blockIdx.x * 64;
    const int t0  = t0g + w * 16;
    const int ct0 = blockIdx.y * 64;
    const int b   = t0g >> 12;
    const int l   = (t0 + c) & (L - 1);
    f32x4 acc[4] = {};
    for (int kc = 0; kc < 320; kc += 32) {
        int kp  = kc >> 6;
        int ci0 = (kc & 63) + q * 8;
        int p = 2 * l + kp - 2;
        bf16x8s a = {};
        if (p >= 0 && p < T)
            a = *(const bf16x8s*)&xTb[((size_t)b * T + p) * 64 + ci0];
        #pragma unroll
        for (int i = 0; i < 4; ++i) {
            bf16x8s bb = *(const bf16x8s*)&Wrb[(size_t)(ct0 + i * 16 + c) * 320 + kc + q * 8];
            acc[i] = __builtin_amdgcn_mfma_f32_16x16x32_bf16(a, bb, acc[i], 0, 0, 0);
        }
    }
    float s = 0.f, ss = 0.f;
    #pragma unroll
    for (int i = 0; i < 4; ++i) {
        int cout = ct0 + i * 16 + c;
        float bias = cb[cout];
        #pragma unroll
        for (int r = 0; r < 4; ++r) {
            int tok = t0 + q * 4 + r;
            float v = acc[i][r] + bias;
            h[(size_t)tok * COUT + cout] = v;
            s += v; ss += v * v;
        }
    }
    #pragma unroll
    for (int off = 32; off; off >>= 1) {
        s  += __shfl_down(s,  off, 64);
        ss += __shfl_down(ss, off, 64);
    }
    if (lane == 0) {
        atomicAdd(&stats[b * 2 + 0], s);
        atomicAdd(&stats[b * 2 + 1], ss);
    }
}

// ------------------------------------------------------ GN apply + PReLU
__global__ __launch_bounds__(256) void gn_prelu_kernel(
    float* __restrict__ h, const float* __restrict__ gn_g,
    const float* __restrict__ gn_b, const float* __restrict__ prelu_a,
    const float* __restrict__ stats) {
    int i = blockIdx.x * 256 + threadIdx.x;      // 262144 threads, x4 elements
    size_t base = (size_t)i * 4;
    int b = (base >= (size_t)L * COUT) ? 1 : 0;
    const float n = (float)(L * COUT);
    float mu   = stats[b * 2 + 0] / n;
    float var  = stats[b * 2 + 1] / n - mu * mu;
    float rstd = rsqrtf(var + 1e-5f);
    float a = prelu_a[0];
    float4 v = *(const float4*)&h[base];
    int c = (int)(base % COUT);
    float4 g  = *(const float4*)&gn_g[c];
    float4 bb = *(const float4*)&gn_b[c];
    v.x = (v.x - mu) * rstd * g.x + bb.x; v.x = v.x >= 0.f ? v.x : a * v.x;
    v.y = (v.y - mu) * rstd * g.y + bb.y; v.y = v.y >= 0.f ? v.y : a * v.y;
    v.z = (v.z - mu) * rstd * g.z + bb.z; v.z = v.z >= 0.f ? v.z : a * v.z;
    v.w = (v.w - mu) * rstd * g.w + bb.w; v.w = v.w >= 0.f ? v.w : a * v.w;
    *(float4*)&h[base] = v;
}

// ------------------------------------------------------ per-token LayerNorm -> bf16
__global__ __launch_bounds__(256) void ln_kernel(
    const float* __restrict__ h, unsigned short* __restrict__ hnb,
    const float* __restrict__ g, const float* __restrict__ bta) {
    int wave = threadIdx.x >> 6, lane = threadIdx.x & 63;
    int t = blockIdx.x * 4 + wave;
    const float* row = h + (size_t)t * COUT;
    float2 v = *(const float2*)&row[lane * 2];
    float s = v.x + v.y, ss = v.x * v.x + v.y * v.y;
    #pragma unroll
    for (int off = 32; off; off >>= 1) {
        s  += __shfl_xor(s,  off, 64);
        ss += __shfl_xor(ss, off, 64);
    }
    float mu = s * (1.f / 128.f);
    float var = ss * (1.f / 128.f) - mu * mu;
    float rstd = rsqrtf(var + 1e-5f);
    float2 gg = *(const float2*)&g[lane * 2];
    float2 bb = *(const float2*)&bta[lane * 2];
    ushort2 o;
    o.x = f2bf((v.x - mu) * rstd * gg.x + bb.x);
    o.y = f2bf((v.y - mu) * rstd * gg.y + bb.y);
    *(ushort2*)&hnb[(size_t)t * COUT + lane * 2] = o;
}

// ---------------- inproj as bf16-MFMA GEMM; z-half -> silu -> bf16 store
__global__ __launch_bounds__(256) void inproj_mfma_kernel(
    const unsigned short* __restrict__ hnb, const unsigned short* __restrict__ Winb,
    float* __restrict__ xp0, unsigned short* __restrict__ zb0,
    float* __restrict__ xp1, unsigned short* __restrict__ zb1, int layer) {
    const int tid = threadIdx.x;
    const int w = tid >> 6, lane = tid & 63, q = lane >> 4, c = lane & 15;
    const int t0 = blockIdx.x * 64 + w * 16;
    const int nBase = blockIdx.y * 64;
    const int inst = nBase >> 9;
    const int e0 = nBase & 511;
    const unsigned short* Wb = Winb + (size_t)(layer * 2 + inst) * 512 * 128;
    f32x4 acc[4] = {};
    for (int kc = 0; kc < 128; kc += 32) {
        bf16x8s a = *(const bf16x8s*)&hnb[(size_t)(t0 + c) * 128 + kc + q * 8];
        #pragma unroll
        for (int i = 0; i < 4; ++i) {
            bf16x8s bb = *(const bf16x8s*)&Wb[(size_t)(e0 + i * 16 + c) * 128 + kc + q * 8];
            acc[i] = __builtin_amdgcn_mfma_f32_16x16x32_bf16(a, bb, acc[i], 0, 0, 0);
        }
    }
    #pragma unroll
    for (int i = 0; i < 4; ++i) {
        int e = e0 + i * 16 + c;
        bool isz = (e >= 256);
        int eo = e & 255;
        #pragma unroll
        for (int r = 0; r < 4; ++r) {
            int tok = t0 + q * 4 + r;
            float v = acc[i][r];
            if (isz) {
                float sv = v * sigmoidf_(v);
                (inst ? zb1 : zb0)[(size_t)tok * DI + eo] = f2bf(sv);
            } else {
                (inst ? xp1 : xp0)[(size_t)tok * DI + eo] = v;
            }
        }
    }
}

// ---------------------------------------- depthwise causal conv (d=4) + SiLU
__global__ __launch_bounds__(256) void dwconv_kernel(
    const float* __restrict__ xp0, const float* __restrict__ xp1,
    const float* __restrict__ cw, const float* __restrict__ cbias,
    float* __restrict__ u0, float* __restrict__ u1, int layer) {
    int flat = blockIdx.x * 256 + threadIdx.x;
    int d    = flat & 255;
    int l    = (flat >> 8) & (L - 1);
    int b    = (flat >> 20) & 1;
    int inst = flat >> 21;
    const float* xp = inst ? xp1 : xp0;
    float* u = inst ? u1 : u0;
    int m = layer * 2 + inst;
    const float4 w4 = *(const float4*)&cw[(size_t)(m * DI + d) * 4];
    float acc = cbias[m * DI + d];
    size_t base = ((size_t)b * L) * DI + d;
    if (inst == 0) {  // forward: taps l-3..l, weights w[0]..w[3]
        if (l - 3 >= 0) acc = fmaf(w4.x, xp[base + (size_t)(l - 3) * DI], acc);
        if (l - 2 >= 0) acc = fmaf(w4.y, xp[base + (size_t)(l - 2) * DI], acc);
        if (l - 1 >= 0) acc = fmaf(w4.z, xp[base + (size_t)(l - 1) * DI], acc);
        acc = fmaf(w4.w, xp[base + (size_t)l * DI], acc);
    } else {          // backward (natural coords): taps l..l+3, w[3]..w[0]
        acc = fmaf(w4.w, xp[base + (size_t)l * DI], acc);
        if (l + 1 < L) acc = fmaf(w4.z, xp[base + (size_t)(l + 1) * DI], acc);
        if (l + 2 < L) acc = fmaf(w4.y, xp[base + (size_t)(l + 2) * DI], acc);
        if (l + 3 < L) acc = fmaf(w4.x, xp[base + (size_t)(l + 3) * DI], acc);
    }
    u[base + (size_t)l * DI] = acc * sigmoidf_(acc);
}

// ------------------------------------- xproj as GEMM (M=32tok/blk, N=40, K=256)
__global__ __launch_bounds__(256) void xproj_kernel(
    const float* __restrict__ u0, const float* __restrict__ u1,
    const float* __restrict__ Wx, const float* __restrict__ Wdt,
    const float* __restrict__ bdt,
    float* __restrict__ dl0, float* __restrict__ dl1,
    float* __restrict__ Bm0, float* __restrict__ Bm1,
    float* __restrict__ Cm0, float* __restrict__ Cm1, int layer) {
    __shared__ float Ws[40 * 132];   // [e][k-sub] current K slab
    __shared__ float As[128 * 33];   // [k][t] half-K u tile
    __shared__ float xd[32 * 9];     // dt outputs
    const int tid   = threadIdx.x;
    const int tBase = blockIdx.x * 32;
    const int inst  = blockIdx.y;
    const int m     = layer * 2 + inst;
    const float* u  = inst ? u1 : u0;
    const float* Wm = Wx + (size_t)m * 40 * 256;
    const int t  = tid & 31;
    const int eq = tid >> 5;                // 0..7
    float acc[5] = {};
    for (int kc = 0; kc < 256; kc += 128) {
        __syncthreads();
        #pragma unroll
        for (int i = 0; i < 5; ++i) {
            int idx = i * 256 + tid;
            int e = idx >> 5, kq = idx & 31;
            float4 w4 = *(const float4*)&Wm[(size_t)e * 256 + kc + kq * 4];
            float* dstw = &Ws[e * 132 + kq * 4];
            dstw[0] = w4.x; dstw[1] = w4.y; dstw[2] = w4.z; dstw[3] = w4.w;
        }
        #pragma unroll
        for (int i = 0; i < 4; ++i) {
            int flat = i * 256 + tid;
            int tt = flat >> 5, kq = flat & 31;
            float4 v = *(const float4*)&u[(size_t)(tBase + tt) * DI + kc + kq * 4];
            As[(kq * 4 + 0) * 33 + tt] = v.x;
            As[(kq * 4 + 1) * 33 + tt] = v.y;
            As[(kq * 4 + 2) * 33 + tt] = v.z;
            As[(kq * 4 + 3) * 33 + tt] = v.w;
        }
        __syncthreads();
        #pragma unroll 4
        for (int kk = 0; kk < 128; ++kk) {
            float a = As[kk * 33 + t];
            acc[0] = fmaf(a, Ws[(eq     ) * 132 + kk], acc[0]);
            acc[1] = fmaf(a, Ws[(eq +  8) * 132 + kk], acc[1]);
            acc[2] = fmaf(a, Ws[(eq + 16) * 132 + kk], acc[2]);
            acc[3] = fmaf(a, Ws[(eq + 24) * 132 + kk], acc[3]);
            acc[4] = fmaf(a, Ws[(eq + 32) * 132 + kk], acc[4]);
        }
    }
    {
        int tok = tBase + t;
        float* Bm = inst ? Bm1 : Bm0;
        float* Cm = inst ? Cm1 : Cm0;
        xd[t * 9 + eq] = acc[0];
        Bm[(size_t)tok * NST + eq]     = acc[1];
        Bm[(size_t)tok * NST + 8 + eq] = acc[2];
        Cm[(size_t)tok * NST + eq]     = acc[3];
        Cm[(size_t)tok * NST + 8 + eq] = acc[4];
    }
    __syncthreads();
    {
        int d = tid;
        float wr[8];
        #pragma unroll
        for (int r = 0; r < 8; ++r) wr[r] = Wdt[((size_t)m * DI + d) * DTR + r];
        float bb = bdt[m * DI + d];
        float* dl = inst ? dl1 : dl0;
        #pragma unroll 4
        for (int tt = 0; tt < 32; ++tt) {
            float a2 = bb;
            #pragma unroll
            for (int r = 0; r < 8; ++r) a2 = fmaf(xd[tt * 9 + r], wr[r], a2);
            float sp = fmaxf(a2, 0.f) + __logf(1.f + __expf(-fabsf(a2)));
            dl[(size_t)(tBase + tt) * DI + d] = sp;
        }
    }
}

// ---------------------------------------------- scan phase 1: chunk-local
// thread = (nq 0..3, dlane 0..63); grid (NC*4, B2, 2).
__global__ __launch_bounds__(256) void scan1_kernel(
    const float* __restrict__ dl0, const float* __restrict__ dl1,
    const float* __restrict__ u0,  const float* __restrict__ u1,
    const float* __restrict__ Bm0, const float* __restrict__ Bm1,
    const float* __restrict__ A_log,
    float* __restrict__ hend, float* __restrict__ dsumb, int layer) {
    const int tid = threadIdx.x;
    const int nq = tid & 3, dlane = tid >> 2;
    const int chunk = blockIdx.x & (NC - 1), dtile = blockIdx.x >> 7;
    const int b = blockIdx.y, inst = blockIdx.z;
    const int m = layer * 2 + inst, dir = inst;
    const int d = dtile * 64 + dlane;
    const float* dl = inst ? dl1 : dl0;
    const float* u  = inst ? u1  : u0;
    const float* Bm = inst ? Bm1 : Bm0;
    float4 av = *(const float4*)&A_log[((size_t)m * DI + d) * NST + nq * 4];
    const float a0 = -expf(av.x), a1 = -expf(av.y), a2 = -expf(av.z), a3 = -expf(av.w);
    const int s0 = chunk * Q;
    const int l0 = dir ? (L - 1 - s0) : s0;
    const int stp = dir ? -1 : 1;
    long iDU = ((long)(b * L + l0)) * DI + d;
    int  iB  = ((b * L + l0) << 4) + nq * 4;
    const long sDU = (long)stp * DI;
    const int  sB  = stp * NST;
    float h0 = 0.f, h1 = 0.f, h2 = 0.f, h3 = 0.f, dsum = 0.f;
    #pragma unroll 4
    for (int t = 0; t < Q; ++t) {
        float dlt = dl[iDU], uu = u[iDU];
        float4 bm = *(const float4*)&Bm[iB];
        float du = dlt * uu;
        h0 = fmaf(__expf(dlt * a0), h0, du * bm.x);
        h1 = fmaf(__expf(dlt * a1), h1, du * bm.y);
        h2 = fmaf(__expf(dlt * a2), h2, du * bm.z);
        h3 = fmaf(__expf(dlt * a3), h3, du * bm.w);
        dsum += dlt;
        iDU += sDU; iB += sB;
    }
    size_t oh = (((size_t)(inst * 2 + b) * DI + d) * NC + chunk) * NST + nq * 4;
    *(float4*)&hend[oh] = make_float4(h0, h1, h2, h3);
    if (nq == 0) dsumb[((size_t)(inst * 2 + b) * NC + chunk) * DI + d] = dsum;
}

// ---------------------------------------------- scan combine (in-place prefix)
__global__ __launch_bounds__(256) void combine_kernel(
    float* __restrict__ hend, const float* __restrict__ dsumb,
    const float* __restrict__ A_log, int layer) {
    int flat = blockIdx.x * 256 + threadIdx.x;   // 16384
    int n = flat & 15;
    int d = (flat >> 4) & 255;
    int b = (flat >> 12) & 1;
    int inst = flat >> 13;
    int m = layer * 2 + inst;
    float a = -expf(A_log[((size_t)m * DI + d) * NST + n]);
    size_t baseE = (((size_t)(inst * 2 + b) * DI + d) * NC) * NST + n;
    size_t baseD = ((size_t)(inst * 2 + b) * NC) * DI + d;
    float hc = 0.f;
    #pragma unroll 4
    for (int c = 0; c < NC; ++c) {
        float tmp = hend[baseE + (size_t)c * NST];
        hend[baseE + (size_t)c * NST] = hc;
        float ds = dsumb[baseD + (size_t)c * DI];
        hc = fmaf(__expf(a * ds), hc, tmp);
    }
}

// --------------------------------- scan phase 2: full scan + y + gate (bf16 z)
__global__ __launch_bounds__(256) void scan2_kernel(
    const float* __restrict__ dl0, const float* __restrict__ dl1,
    const float* __restrict__ u0,  const float* __restrict__ u1,
    const float* __restrict__ Bm0, const float* __restrict__ Bm1,
    const float* __restrict__ Cm0, const float* __restrict__ Cm1,
    const unsigned short* __restrict__ zb0, const unsigned short* __restrict__ zb1,
    const float* __restrict__ hin, const float* __restrict__ A_log,
    const float* __restrict__ Dp,
    float* __restrict__ yg0, float* __restrict__ yg1, int layer) {
    const int tid = threadIdx.x;
    const int nq = tid & 3, dlane = tid >> 2;
    const int chunk = blockIdx.x & (NC - 1), dtile = blockIdx.x >> 7;
    const int b = blockIdx.y, inst = blockIdx.z;
    const int m = layer * 2 + inst, dir = inst;
    const int d = dtile * 64 + dlane;
    const float* dl = inst ? dl1 : dl0;
    const float* u  = inst ? u1  : u0;
    const float* Bm = inst ? Bm1 : Bm0;
    const float* Cm = inst ? Cm1 : Cm0;
    const unsigned short* zs = inst ? zb1 : zb0;
    float* yg = inst ? yg1 : yg0;
    float4 av = *(const float4*)&A_log[((size_t)m * DI + d) * NST + nq * 4];
    const float a0 = -expf(av.x), a1 = -expf(av.y), a2 = -expf(av.z), a3 = -expf(av.w);
    const float dpar = Dp[m * DI + d];
    const int s0 = chunk * Q;
    const int l0 = dir ? (L - 1 - s0) : s0;
    const int stp = dir ? -1 : 1;
    long iDU = ((long)(b * L + l0)) * DI + d;
    int  iB  = ((b * L + l0) << 4) + nq * 4;
    const long sDU = (long)stp * DI;
    const int  sB  = stp * NST;
    float4 hv = *(const float4*)&hin[(((size_t)(inst * 2 + b) * DI + d) * NC + chunk) * NST + nq * 4];
    float h0 = hv.x, h1 = hv.y, h2 = hv.z, h3 = hv.w;
    #pragma unroll 4
    for (int t = 0; t < Q; ++t) {
        float dlt = dl[iDU], uu = u[iDU];
        float4 bm = *(const float4*)&Bm[iB];
        float4 cm = *(const float4*)&Cm[iB];
        float du = dlt * uu;
        h0 = fmaf(__expf(dlt * a0), h0, du * bm.x);
        h1 = fmaf(__expf(dlt * a1), h1, du * bm.y);
        h2 = fmaf(__expf(dlt * a2), h2, du * bm.z);
        h3 = fmaf(__expf(dlt * a3), h3, du * bm.w);
        float yp = h0 * cm.x + h1 * cm.y + h2 * cm.z + h3 * cm.w;
        yp += __shfl_xor(yp, 1, 4);
        yp += __shfl_xor(yp, 2, 4);
        if (nq == 0) {
            float zv = bf2f(zs[iDU]);
            yg[iDU] = fmaf(uu, dpar, yp) * zv;
        }
        iDU += sDU; iB += sB;
    }
}

// ------------------------------- outproj GEMM (both insts) + residual into h
__global__ __launch_bounds__(256) void outproj_kernel(
    const float* __restrict__ yg0, const float* __restrict__ yg1,
    const float* __restrict__ W_out, float* __restrict__ h, int layer) {
    __shared__ float As[32 * 36];
    __shared__ float Bs[32 * 132];
    const int tid = threadIdx.x;
    const int tBase = blockIdx.x * 32;
    const int m00 = (tid & 15) * 2, n0 = (tid >> 4) * 8;
    float acc[2][8] = {};
    for (int inst = 0; inst < 2; ++inst) {
        const float* yg = inst ? yg1 : yg0;
        const float* Wm = W_out + (size_t)(layer * 2 + inst) * COUT * DI;
        for (int kc = 0; kc < 256; kc += 32) {
            {
                int t = tid >> 3, kq = tid & 7;
                float4 v = *(const float4*)&yg[(size_t)(tBase + t) * DI + kc + kq * 4];
                As[(kq * 4 + 0) * 36 + t] = v.x; As[(kq * 4 + 1) * 36 + t] = v.y;
                As[(kq * 4 + 2) * 36 + t] = v.z; As[(kq * 4 + 3) * 36 + t] = v.w;
                int nr = tid >> 1, kq2 = tid & 1;
                const float* wsrc = Wm + (size_t)nr * DI + kc + kq2 * 16;
                #pragma unroll
                for (int q2 = 0; q2 < 4; ++q2) {
                    float4 wv = *(const float4*)(wsrc + q2 * 4);
                    int kk = kq2 * 16 + q2 * 4;
                    Bs[(kk + 0) * 132 + nr] = wv.x; Bs[(kk + 1) * 132 + nr] = wv.y;
                    Bs[(kk + 2) * 132 + nr] = wv.z; Bs[(kk + 3) * 132 + nr] = wv.w;
                }
            }
            __syncthreads();
            #pragma unroll
            for (int kk = 0; kk < 32; ++kk) {
                float2 av = *(const float2*)&As[kk * 36 + m00];
                float4 b0 = *(const float4*)&Bs[kk * 132 + n0];
                float4 b1 = *(const float4*)&Bs[kk * 132 + n0 + 4];
                acc[0][0] = fmaf(av.x, b0.x, acc[0][0]); acc[0][1] = fmaf(av.x, b0.y, acc[0][1]);
                acc[0][2] = fmaf(av.x, b0.z, acc[0][2]); acc[0][3] = fmaf(av.x, b0.w, acc[0][3]);
                acc[0][4] = fmaf(av.x, b1.x, acc[0][4]); acc[0][5] = fmaf(av.x, b1.y, acc[0][5]);
                acc[0][6] = fmaf(av.x, b1.z, acc[0][6]); acc[0][7] = fmaf(av.x, b1.w, acc[0][7]);
                acc[1][0] = fmaf(av.y, b0.x, acc[1][0]); acc[1][1] = fmaf(av.y, b0.y, acc[1][1]);
                acc[1][2] = fmaf(av.y, b0.z, acc[1][2]); acc[1][3] = fmaf(av.y, b0.w, acc[1][3]);
                acc[1][4] = fmaf(av.y, b1.x, acc[1][4]); acc[1][5] = fmaf(av.y, b1.y, acc[1][5]);
                acc[1][6] = fmaf(av.y, b1.z, acc[1][6]); acc[1][7] = fmaf(av.y, b1.w, acc[1][7]);
            }
            __syncthreads();
        }
    }
    #pragma unroll
    for (int im = 0; im < 2; ++im) {
        size_t row = (size_t)(tBase + m00 + im) * COUT + n0;
        float4 h0 = *(const float4*)&h[row];
        float4 h1 = *(const float4*)&h[row + 4];
        h0.x += acc[im][0]; h0.y += acc[im][1]; h0.z += acc[im][2]; h0.w += acc[im][3];
        h1.x += acc[im][4]; h1.y += acc[im][5]; h1.z += acc[im][6]; h1.w += acc[im][7];
        *(float4*)&h[row] = h0;
        *(float4*)&h[row + 4] = h1;
    }
}

// ------------------------------------------------ final [B,L,C] -> [B,C,L]
__global__ __launch_bounds__(256) void transpose_kernel(
    const float* __restrict__ h, float* __restrict__ out) {
    __shared__ float tile[32][33];
    int lt0 = blockIdx.x * 32, ct0 = blockIdx.y * 32, b = blockIdx.z;
    int c = threadIdx.x & 31, r = threadIdx.x >> 5;
    #pragma unroll
    for (int j = 0; j < 4; ++j) {
        int ll = r + 8 * j;
        tile[ll][c] = h[((size_t)b * L + lt0 + ll) * COUT + ct0 + c];
    }
    __syncthreads();
    #pragma unroll
    for (int j = 0; j < 4; ++j) {
        int cc = r + 8 * j;
        out[((size_t)b * COUT + ct0 + cc) * L + lt0 + c] = tile[c][cc];
    }
}

// ======================================================================
extern "C" void kernel_launch(void* const* d_in, const int* in_sizes, int n_in,
                              void* d_out, int out_size, void* d_ws, size_t ws_size,
                              hipStream_t stream) {
    const float* x        = (const float*)d_in[0];
    const float* conv_w   = (const float*)d_in[1];
    const float* conv_b   = (const float*)d_in[2];
    const float* gn_g     = (const float*)d_in[3];
    const float* gn_b     = (const float*)d_in[4];
    const float* prelu_a  = (const float*)d_in[5];
    const float* ln_g     = (const float*)d_in[6];
    const float* ln_b     = (const float*)d_in[7];
    const float* W_in     = (const float*)d_in[8];
    const float* conv1d_w = (const float*)d_in[9];
    const float* conv1d_b = (const float*)d_in[10];
    const float* W_xproj  = (const float*)d_in[11];
    const float* W_dt     = (const float*)d_in[12];
    const float* b_dt     = (const float*)d_in[13];
    const float* A_log    = (const float*)d_in[14];
    const float* D_param  = (const float*)d_in[15];
    const float* W_out    = (const float*)d_in[16];

    float* ws = (float*)d_ws;
    float* h     = ws;                         // [B,L,128]               1,048,576
    float* xp0   = ws + 1048576;               // [B,L,256] f32 (yg0)     2,097,152
    float* xp1   = ws + 3145728;               //            (yg1)        2,097,152
    unsigned short* zb0 = (unsigned short*)(ws + 5242880);   // [B,L,256] bf16 (1,048,576 f)
    unsigned short* zb1 = (unsigned short*)(ws + 6291456);   // bf16
    float* u0    = ws + 7340032;               // [B,L,256]               2,097,152
    float* u1    = ws + 9437184;
    float* dl0   = ws + 11534336;
    float* dl1   = ws + 13631488;
    float* Bm0   = ws + 15728640;              // [B,L,16]
    float* Bm1   = ws + 15859712;
    float* Cm0   = ws + 15990784;
    float* Cm1   = ws + 16121856;
    float* hend  = ws + 16252928;              // [2,B,256,NC=128,16] = 2,097,152
    float* dsumb = ws + 18350080;              // [2,B,NC,256] = 131,072
    unsigned short* Winb = (unsigned short*)(ws + 18481152); // 262,144 bf16 (131,072 f)
    unsigned short* Wrb  = (unsigned short*)(ws + 18612224); // 40,960 bf16
    float* stats = ws + 18632704;              // [4]
    unsigned short* hnb = (unsigned short*)hend;             // 1M bf16 (hend dead outside scans)
    unsigned short* xTb = zb0;                               // 1M bf16 (pre-loop only)

    zero_stats_kernel<<<1, 64, 0, stream>>>(stats);
    wconv_prep_kernel<<<160, 256, 0, stream>>>(conv_w, Wrb);
    win_prep_kernel<<<1024, 256, 0, stream>>>(W_in, Winb);
    xpose_kernel<<<dim3(T / 64, B2), 256, 0, stream>>>(x, xTb);
    conv_mfma_kernel<<<dim3(TOK / 64, COUT / 64), 256, 0, stream>>>(xTb, Wrb, conv_b, h, stats);
    gn_prelu_kernel<<<(TOK * COUT / 4) / 256, 256, 0, stream>>>(h, gn_g, gn_b, prelu_a, stats);

    for (int layer = 0; layer < 2; ++layer) {
        ln_kernel<<<TOK / 4, 256, 0, stream>>>(h, hnb, ln_g + layer * COUT, ln_b + layer * COUT);
        inproj_mfma_kernel<<<dim3(TOK / 64, 16), 256, 0, stream>>>(hnb, Winb, xp0, zb0, xp1, zb1, layer);
        dwconv_kernel<<<(2 * B2 * L * DI) / 256, 256, 0, stream>>>(xp0, xp1, conv1d_w, conv1d_b, u0, u1, layer);
        xproj_kernel<<<dim3(TOK / 32, 2), 256, 0, stream>>>(u0, u1, W_xproj, W_dt, b_dt,
                                                            dl0, dl1, Bm0, Bm1, Cm0, Cm1, layer);
        scan1_kernel<<<dim3(NC * 4, B2, 2), 256, 0, stream>>>(dl0, dl1, u0, u1, Bm0, Bm1,
                                                              A_log, hend, dsumb, layer);
        combine_kernel<<<64, 256, 0, stream>>>(hend, dsumb, A_log, layer);
        scan2_kernel<<<dim3(NC * 4, B2, 2), 256, 0, stream>>>(dl0, dl1, u0, u1, Bm0, Bm1, Cm0, Cm1,
                                                              zb0, zb1, hend, A_log, D_param,
                                                              xp0, xp1, layer);
        outproj_kernel<<<TOK / 32, 256, 0, stream>>>(xp0, xp1, W_out, h, layer);
    }
    transpose_kernel<<<dim3(L / 32, COUT / 32, B2), 256, 0, stream>>>(h, (float*)d_out);
}

// Round 12
// 400.278 us; speedup vs baseline: 1.9221x; 1.1362x over previous
//
#include <hip/hip_runtime.h>
#include <hip/hip_bf16.h>
#include <math.h>

// ---- problem dims ----
constexpr int B2   = 2;
constexpr int CIN  = 64;
constexpr int COUT = 128;
constexpr int T    = 8192;
constexpr int L    = 4096;     // T/2
constexpr int DI   = 256;
constexpr int NST  = 16;       // d_state
constexpr int DTR  = 8;
constexpr int Q    = 32;       // scan chunk length
constexpr int NC   = 128;      // L / Q
constexpr int TOK  = B2 * L;   // 8192 tokens

typedef __attribute__((ext_vector_type(8))) short bf16x8s;   // 8 bf16 (4 VGPRs)
typedef __attribute__((ext_vector_type(4))) float f32x4;

__device__ __forceinline__ float sigmoidf_(float x) { return 1.f / (1.f + __expf(-x)); }
__device__ __forceinline__ unsigned short f2bf(float f) {
    unsigned int u = __float_as_uint(f);
    unsigned int r = (u + 0x7FFFu + ((u >> 16) & 1u)) >> 16;
    return (unsigned short)r;
}
__device__ __forceinline__ float bf2f(unsigned short s) {
    return __uint_as_float((unsigned int)s << 16);
}

// ---------------------------------------------------------------- zero stats
__global__ __launch_bounds__(64) void zero_stats_kernel(float* stats) {
    if (threadIdx.x < 4) stats[threadIdx.x] = 0.f;
}

// ---------------- conv weight reorder+convert: cw[co][ci][kp] -> Wrb[co][kp*64+ci] (bf16)
__global__ __launch_bounds__(256) void wconv_prep_kernel(
    const float* __restrict__ cw, unsigned short* __restrict__ Wrb) {
    int idx = blockIdx.x * 256 + threadIdx.x;     // 40960
    int co = idx / 320, r = idx % 320;
    int kp = r >> 6, ci = r & 63;
    Wrb[idx] = f2bf(cw[co * 320 + ci * 5 + kp]);
}

// ---------------- W_in convert to bf16 (row-major [m][e][k] unchanged)
__global__ __launch_bounds__(256) void win_prep_kernel(
    const float* __restrict__ W_in, unsigned short* __restrict__ Winb) {
    int idx = blockIdx.x * 256 + threadIdx.x;     // 262144
    Winb[idx] = f2bf(W_in[idx]);
}

// ---------------- W_out convert to bf16 (row-major [m][cout][k] unchanged)
__global__ __launch_bounds__(256) void wout_prep_kernel(
    const float* __restrict__ W_out, unsigned short* __restrict__ Woutb) {
    int idx = blockIdx.x * 256 + threadIdx.x;     // 131072
    Woutb[idx] = f2bf(W_out[idx]);
}

// ---------------- x transpose+convert: x[b][ci][t] -> xTb[b][t][ci] (bf16)
__global__ __launch_bounds__(256) void xpose_kernel(
    const float* __restrict__ x, unsigned short* __restrict__ xTb) {
    __shared__ float tile[64][65];
    int b = blockIdx.y, tb = blockIdx.x * 64, tid = threadIdx.x;
    #pragma unroll
    for (int i = 0; i < 16; ++i) {
        int idx = i * 256 + tid; int ci = idx >> 6, tt = idx & 63;
        tile[ci][tt] = x[((size_t)b * CIN + ci) * T + tb + tt];
    }
    __syncthreads();
    #pragma unroll
    for (int i = 0; i < 16; ++i) {
        int idx = i * 256 + tid; int tt = idx >> 6, ci = idx & 63;
        xTb[((size_t)b * T + tb + tt) * 64 + ci] = f2bf(tile[ci][tt]);
    }
}

// ---------------- conv1d stride2 as bf16-MFMA implicit GEMM + GN stats
__global__ __launch_bounds__(256) void conv_mfma_kernel(
    const unsigned short* __restrict__ xTb, const unsigned short* __restrict__ Wrb,
    const float* __restrict__ cb, float* __restrict__ h, float* __restrict__ stats) {
    const int tid = threadIdx.x;
    const int w = tid >> 6, lane = tid & 63, q = lane >> 4, c = lane & 15;
    const int t0g = blockIdx.x * 64;
    const int t0  = t0g + w * 16;
    const int ct0 = blockIdx.y * 64;
    const int b   = t0g >> 12;
    const int l   = (t0 + c) & (L - 1);
    f32x4 acc[4] = {};
    for (int kc = 0; kc < 320; kc += 32) {
        int kp  = kc >> 6;
        int ci0 = (kc & 63) + q * 8;
        int p = 2 * l + kp - 2;
        bf16x8s a = {};
        if (p >= 0 && p < T)
            a = *(const bf16x8s*)&xTb[((size_t)b * T + p) * 64 + ci0];
        #pragma unroll
        for (int i = 0; i < 4; ++i) {
            bf16x8s bb = *(const bf16x8s*)&Wrb[(size_t)(ct0 + i * 16 + c) * 320 + kc + q * 8];
            acc[i] = __builtin_amdgcn_mfma_f32_16x16x32_bf16(a, bb, acc[i], 0, 0, 0);
        }
    }
    float s = 0.f, ss = 0.f;
    #pragma unroll
    for (int i = 0; i < 4; ++i) {
        int cout = ct0 + i * 16 + c;
        float bias = cb[cout];
        #pragma unroll
        for (int r = 0; r < 4; ++r) {
            int tok = t0 + q * 4 + r;
            float v = acc[i][r] + bias;
            h[(size_t)tok * COUT + cout] = v;
            s += v; ss += v * v;
        }
    }
    #pragma unroll
    for (int off = 32; off; off >>= 1) {
        s  += __shfl_down(s,  off, 64);
        ss += __shfl_down(ss, off, 64);
    }
    if (lane == 0) {
        atomicAdd(&stats[b * 2 + 0], s);
        atomicAdd(&stats[b * 2 + 1], ss);
    }
}

// ------------------------------------------------------ GN apply + PReLU
__global__ __launch_bounds__(256) void gn_prelu_kernel(
    float* __restrict__ h, const float* __restrict__ gn_g,
    const float* __restrict__ gn_b, const float* __restrict__ prelu_a,
    const float* __restrict__ stats) {
    int i = blockIdx.x * 256 + threadIdx.x;      // 262144 threads, x4 elements
    size_t base = (size_t)i * 4;
    int b = (base >= (size_t)L * COUT) ? 1 : 0;
    const float n = (float)(L * COUT);
    float mu   = stats[b * 2 + 0] / n;
    float var  = stats[b * 2 + 1] / n - mu * mu;
    float rstd = rsqrtf(var + 1e-5f);
    float a = prelu_a[0];
    float4 v = *(const float4*)&h[base];
    int c = (int)(base % COUT);
    float4 g  = *(const float4*)&gn_g[c];
    float4 bb = *(const float4*)&gn_b[c];
    v.x = (v.x - mu) * rstd * g.x + bb.x; v.x = v.x >= 0.f ? v.x : a * v.x;
    v.y = (v.y - mu) * rstd * g.y + bb.y; v.y = v.y >= 0.f ? v.y : a * v.y;
    v.z = (v.z - mu) * rstd * g.z + bb.z; v.z = v.z >= 0.f ? v.z : a * v.z;
    v.w = (v.w - mu) * rstd * g.w + bb.w; v.w = v.w >= 0.f ? v.w : a * v.w;
    *(float4*)&h[base] = v;
}

// ------------------------------------------------------ per-token LayerNorm -> bf16
__global__ __launch_bounds__(256) void ln_kernel(
    const float* __restrict__ h, unsigned short* __restrict__ hnb,
    const float* __restrict__ g, const float* __restrict__ bta) {
    int wave = threadIdx.x >> 6, lane = threadIdx.x & 63;
    int t = blockIdx.x * 4 + wave;
    const float* row = h + (size_t)t * COUT;
    float2 v = *(const float2*)&row[lane * 2];
    float s = v.x + v.y, ss = v.x * v.x + v.y * v.y;
    #pragma unroll
    for (int off = 32; off; off >>= 1) {
        s  += __shfl_xor(s,  off, 64);
        ss += __shfl_xor(ss, off, 64);
    }
    float mu = s * (1.f / 128.f);
    float var = ss * (1.f / 128.f) - mu * mu;
    float rstd = rsqrtf(var + 1e-5f);
    float2 gg = *(const float2*)&g[lane * 2];
    float2 bb = *(const float2*)&bta[lane * 2];
    ushort2 o;
    o.x = f2bf((v.x - mu) * rstd * gg.x + bb.x);
    o.y = f2bf((v.y - mu) * rstd * gg.y + bb.y);
    *(ushort2*)&hnb[(size_t)t * COUT + lane * 2] = o;
}

// ---------------- inproj as bf16-MFMA GEMM; z-half -> silu -> bf16 store
__global__ __launch_bounds__(256) void inproj_mfma_kernel(
    const unsigned short* __restrict__ hnb, const unsigned short* __restrict__ Winb,
    float* __restrict__ xp0, unsigned short* __restrict__ zb0,
    float* __restrict__ xp1, unsigned short* __restrict__ zb1, int layer) {
    const int tid = threadIdx.x;
    const int w = tid >> 6, lane = tid & 63, q = lane >> 4, c = lane & 15;
    const int t0 = blockIdx.x * 64 + w * 16;
    const int nBase = blockIdx.y * 64;
    const int inst = nBase >> 9;
    const int e0 = nBase & 511;
    const unsigned short* Wb = Winb + (size_t)(layer * 2 + inst) * 512 * 128;
    f32x4 acc[4] = {};
    for (int kc = 0; kc < 128; kc += 32) {
        bf16x8s a = *(const bf16x8s*)&hnb[(size_t)(t0 + c) * 128 + kc + q * 8];
        #pragma unroll
        for (int i = 0; i < 4; ++i) {
            bf16x8s bb = *(const bf16x8s*)&Wb[(size_t)(e0 + i * 16 + c) * 128 + kc + q * 8];
            acc[i] = __builtin_amdgcn_mfma_f32_16x16x32_bf16(a, bb, acc[i], 0, 0, 0);
        }
    }
    #pragma unroll
    for (int i = 0; i < 4; ++i) {
        int e = e0 + i * 16 + c;
        bool isz = (e >= 256);
        int eo = e & 255;
        #pragma unroll
        for (int r = 0; r < 4; ++r) {
            int tok = t0 + q * 4 + r;
            float v = acc[i][r];
            if (isz) {
                float sv = v * sigmoidf_(v);
                (inst ? zb1 : zb0)[(size_t)tok * DI + eo] = f2bf(sv);
            } else {
                (inst ? xp1 : xp0)[(size_t)tok * DI + eo] = v;
            }
        }
    }
}

// ---------------- depthwise causal conv (d=4) + SiLU — 4 channels/thread (float4)
__global__ __launch_bounds__(256) void dwconv_kernel(
    const float* __restrict__ xp0, const float* __restrict__ xp1,
    const float* __restrict__ cw, const float* __restrict__ cbias,
    float* __restrict__ u0, float* __restrict__ u1, int layer) {
    int flat = blockIdx.x * 256 + threadIdx.x;   // 2*2*4096*64 = 1,048,576
    int dq   = flat & 63;
    int l    = (flat >> 6) & (L - 1);
    int b    = (flat >> 18) & 1;
    int inst = flat >> 19;
    const float* xp = inst ? xp1 : xp0;
    float* u = inst ? u1 : u0;
    int m = layer * 2 + inst;
    int d0 = dq * 4;
    float4 w0 = *(const float4*)&cw[(size_t)(m * DI + d0 + 0) * 4];
    float4 w1 = *(const float4*)&cw[(size_t)(m * DI + d0 + 1) * 4];
    float4 w2 = *(const float4*)&cw[(size_t)(m * DI + d0 + 2) * 4];
    float4 w3 = *(const float4*)&cw[(size_t)(m * DI + d0 + 3) * 4];
    float4 acc = *(const float4*)&cbias[m * DI + d0];
    size_t base = ((size_t)b * L) * DI + d0;
    if (inst == 0) {  // forward: taps l-3..l, weights .x..'.w'
        if (l >= 3) { float4 v = *(const float4*)&xp[base + (size_t)(l - 3) * DI];
            acc.x = fmaf(w0.x, v.x, acc.x); acc.y = fmaf(w1.x, v.y, acc.y);
            acc.z = fmaf(w2.x, v.z, acc.z); acc.w = fmaf(w3.x, v.w, acc.w); }
        if (l >= 2) { float4 v = *(const float4*)&xp[base + (size_t)(l - 2) * DI];
            acc.x = fmaf(w0.y, v.x, acc.x); acc.y = fmaf(w1.y, v.y, acc.y);
            acc.z = fmaf(w2.y, v.z, acc.z); acc.w = fmaf(w3.y, v.w, acc.w); }
        if (l >= 1) { float4 v = *(const float4*)&xp[base + (size_t)(l - 1) * DI];
            acc.x = fmaf(w0.z, v.x, acc.x); acc.y = fmaf(w1.z, v.y, acc.y);
            acc.z = fmaf(w2.z, v.z, acc.z); acc.w = fmaf(w3.z, v.w, acc.w); }
        { float4 v = *(const float4*)&xp[base + (size_t)l * DI];
            acc.x = fmaf(w0.w, v.x, acc.x); acc.y = fmaf(w1.w, v.y, acc.y);
            acc.z = fmaf(w2.w, v.z, acc.z); acc.w = fmaf(w3.w, v.w, acc.w); }
    } else {          // backward (natural coords): taps l..l+3, weights .w..'.x'
        { float4 v = *(const float4*)&xp[base + (size_t)l * DI];
            acc.x = fmaf(w0.w, v.x, acc.x); acc.y = fmaf(w1.w, v.y, acc.y);
            acc.z = fmaf(w2.w, v.z, acc.z); acc.w = fmaf(w3.w, v.w, acc.w); }
        if (l + 1 < L) { float4 v = *(const float4*)&xp[base + (size_t)(l + 1) * DI];
            acc.x = fmaf(w0.z, v.x, acc.x); acc.y = fmaf(w1.z, v.y, acc.y);
            acc.z = fmaf(w2.z, v.z, acc.z); acc.w = fmaf(w3.z, v.w, acc.w); }
        if (l + 2 < L) { float4 v = *(const float4*)&xp[base + (size_t)(l + 2) * DI];
            acc.x = fmaf(w0.y, v.x, acc.x); acc.y = fmaf(w1.y, v.y, acc.y);
            acc.z = fmaf(w2.y, v.z, acc.z); acc.w = fmaf(w3.y, v.w, acc.w); }
        if (l + 3 < L) { float4 v = *(const float4*)&xp[base + (size_t)(l + 3) * DI];
            acc.x = fmaf(w0.x, v.x, acc.x); acc.y = fmaf(w1.x, v.y, acc.y);
            acc.z = fmaf(w2.x, v.z, acc.z); acc.w = fmaf(w3.x, v.w, acc.w); }
    }
    acc.x *= sigmoidf_(acc.x); acc.y *= sigmoidf_(acc.y);
    acc.z *= sigmoidf_(acc.z); acc.w *= sigmoidf_(acc.w);
    *(float4*)&u[base + (size_t)l * DI] = acc;
}

// ------------------------------------- xproj as GEMM (M=32tok/blk, N=40, K=256)
__global__ __launch_bounds__(256) void xproj_kernel(
    const float* __restrict__ u0, const float* __restrict__ u1,
    const float* __restrict__ Wx, const float* __restrict__ Wdt,
    const float* __restrict__ bdt,
    float* __restrict__ dl0, float* __restrict__ dl1,
    float* __restrict__ Bm0, float* __restrict__ Bm1,
    float* __restrict__ Cm0, float* __restrict__ Cm1, int layer) {
    __shared__ float Ws[40 * 132];   // [e][k-sub] current K slab
    __shared__ float As[128 * 33];   // [k][t] half-K u tile
    __shared__ float xd[32 * 9];     // dt outputs
    const int tid   = threadIdx.x;
    const int tBase = blockIdx.x * 32;
    const int inst  = blockIdx.y;
    const int m     = layer * 2 + inst;
    const float* u  = inst ? u1 : u0;
    const float* Wm = Wx + (size_t)m * 40 * 256;
    const int t  = tid & 31;
    const int eq = tid >> 5;                // 0..7
    float acc[5] = {};
    for (int kc = 0; kc < 256; kc += 128) {
        __syncthreads();
        #pragma unroll
        for (int i = 0; i < 5; ++i) {
            int idx = i * 256 + tid;
            int e = idx >> 5, kq = idx & 31;
            float4 w4 = *(const float4*)&Wm[(size_t)e * 256 + kc + kq * 4];
            float* dstw = &Ws[e * 132 + kq * 4];
            dstw[0] = w4.x; dstw[1] = w4.y; dstw[2] = w4.z; dstw[3] = w4.w;
        }
        #pragma unroll
        for (int i = 0; i < 4; ++i) {
            int flat = i * 256 + tid;
            int tt = flat >> 5, kq = flat & 31;
            float4 v = *(const float4*)&u[(size_t)(tBase + tt) * DI + kc + kq * 4];
            As[(kq * 4 + 0) * 33 + tt] = v.x;
            As[(kq * 4 + 1) * 33 + tt] = v.y;
            As[(kq * 4 + 2) * 33 + tt] = v.z;
            As[(kq * 4 + 3) * 33 + tt] = v.w;
        }
        __syncthreads();
        #pragma unroll 4
        for (int kk = 0; kk < 128; ++kk) {
            float a = As[kk * 33 + t];
            acc[0] = fmaf(a, Ws[(eq     ) * 132 + kk], acc[0]);
            acc[1] = fmaf(a, Ws[(eq +  8) * 132 + kk], acc[1]);
            acc[2] = fmaf(a, Ws[(eq + 16) * 132 + kk], acc[2]);
            acc[3] = fmaf(a, Ws[(eq + 24) * 132 + kk], acc[3]);
            acc[4] = fmaf(a, Ws[(eq + 32) * 132 + kk], acc[4]);
        }
    }
    {
        int tok = tBase + t;
        float* Bm = inst ? Bm1 : Bm0;
        float* Cm = inst ? Cm1 : Cm0;
        xd[t * 9 + eq] = acc[0];
        Bm[(size_t)tok * NST + eq]     = acc[1];
        Bm[(size_t)tok * NST + 8 + eq] = acc[2];
        Cm[(size_t)tok * NST + eq]     = acc[3];
        Cm[(size_t)tok * NST + 8 + eq] = acc[4];
    }
    __syncthreads();
    {
        int d = tid;
        float wr[8];
        #pragma unroll
        for (int r = 0; r < 8; ++r) wr[r] = Wdt[((size_t)m * DI + d) * DTR + r];
        float bb = bdt[m * DI + d];
        float* dl = inst ? dl1 : dl0;
        #pragma unroll 4
        for (int tt = 0; tt < 32; ++tt) {
            float a2 = bb;
            #pragma unroll
            for (int r = 0; r < 8; ++r) a2 = fmaf(xd[tt * 9 + r], wr[r], a2);
            float sp = fmaxf(a2, 0.f) + __logf(1.f + __expf(-fabsf(a2)));
            dl[(size_t)(tBase + tt) * DI + d] = sp;
        }
    }
}

// ---------------------------------------------- scan phase 1: chunk-local
// thread = (nq 0..3, dlane 0..63); grid (NC*4, B2, 2).
__global__ __launch_bounds__(256) void scan1_kernel(
    const float* __restrict__ dl0, const float* __restrict__ dl1,
    const float* __restrict__ u0,  const float* __restrict__ u1,
    const float* __restrict__ Bm0, const float* __restrict__ Bm1,
    const float* __restrict__ A_log,
    float* __restrict__ hend, float* __restrict__ dsumb, int layer) {
    const int tid = threadIdx.x;
    const int nq = tid & 3, dlane = tid >> 2;
    const int chunk = blockIdx.x & (NC - 1), dtile = blockIdx.x >> 7;
    const int b = blockIdx.y, inst = blockIdx.z;
    const int m = layer * 2 + inst, dir = inst;
    const int d = dtile * 64 + dlane;
    const float* dl = inst ? dl1 : dl0;
    const float* u  = inst ? u1  : u0;
    const float* Bm = inst ? Bm1 : Bm0;
    float4 av = *(const float4*)&A_log[((size_t)m * DI + d) * NST + nq * 4];
    const float a0 = -expf(av.x), a1 = -expf(av.y), a2 = -expf(av.z), a3 = -expf(av.w);
    const int s0 = chunk * Q;
    const int l0 = dir ? (L - 1 - s0) : s0;
    const int stp = dir ? -1 : 1;
    long iDU = ((long)(b * L + l0)) * DI + d;
    int  iB  = ((b * L + l0) << 4) + nq * 4;
    const long sDU = (long)stp * DI;
    const int  sB  = stp * NST;
    float h0 = 0.f, h1 = 0.f, h2 = 0.f, h3 = 0.f, dsum = 0.f;
    #pragma unroll 4
    for (int t = 0; t < Q; ++t) {
        float dlt = dl[iDU], uu = u[iDU];
        float4 bm = *(const float4*)&Bm[iB];
        float du = dlt * uu;
        h0 = fmaf(__expf(dlt * a0), h0, du * bm.x);
        h1 = fmaf(__expf(dlt * a1), h1, du * bm.y);
        h2 = fmaf(__expf(dlt * a2), h2, du * bm.z);
        h3 = fmaf(__expf(dlt * a3), h3, du * bm.w);
        dsum += dlt;
        iDU += sDU; iB += sB;
    }
    size_t oh = (((size_t)(inst * 2 + b) * DI + d) * NC + chunk) * NST + nq * 4;
    *(float4*)&hend[oh] = make_float4(h0, h1, h2, h3);
    if (nq == 0) dsumb[((size_t)(inst * 2 + b) * NC + chunk) * DI + d] = dsum;
}

// ---------------------------------------------- scan combine (in-place prefix)
__global__ __launch_bounds__(256) void combine_kernel(
    float* __restrict__ hend, const float* __restrict__ dsumb,
    const float* __restrict__ A_log, int layer) {
    int flat = blockIdx.x * 256 + threadIdx.x;   // 16384
    int n = flat & 15;
    int d = (flat >> 4) & 255;
    int b = (flat >> 12) & 1;
    int inst = flat >> 13;
    int m = layer * 2 + inst;
    float a = -expf(A_log[((size_t)m * DI + d) * NST + n]);
    size_t baseE = (((size_t)(inst * 2 + b) * DI + d) * NC) * NST + n;
    size_t baseD = ((size_t)(inst * 2 + b) * NC) * DI + d;
    float hc = 0.f;
    #pragma unroll 4
    for (int c = 0; c < NC; ++c) {
        float tmp = hend[baseE + (size_t)c * NST];
        hend[baseE + (size_t)c * NST] = hc;
        float ds = dsumb[baseD + (size_t)c * DI];
        hc = fmaf(__expf(a * ds), hc, tmp);
    }
}

// ------------- scan phase 2: full scan + y + gate (bf16 z, yg written bf16 IN PLACE over z)
__global__ __launch_bounds__(256) void scan2_kernel(
    const float* __restrict__ dl0, const float* __restrict__ dl1,
    const float* __restrict__ u0,  const float* __restrict__ u1,
    const float* __restrict__ Bm0, const float* __restrict__ Bm1,
    const float* __restrict__ Cm0, const float* __restrict__ Cm1,
    unsigned short* __restrict__ zb0, unsigned short* __restrict__ zb1,
    const float* __restrict__ hin, const float* __restrict__ A_log,
    const float* __restrict__ Dp, int layer) {
    const int tid = threadIdx.x;
    const int nq = tid & 3, dlane = tid >> 2;
    const int chunk = blockIdx.x & (NC - 1), dtile = blockIdx.x >> 7;
    const int b = blockIdx.y, inst = blockIdx.z;
    const int m = layer * 2 + inst, dir = inst;
    const int d = dtile * 64 + dlane;
    const float* dl = inst ? dl1 : dl0;
    const float* u  = inst ? u1  : u0;
    const float* Bm = inst ? Bm1 : Bm0;
    const float* Cm = inst ? Cm1 : Cm0;
    unsigned short* zs = inst ? zb1 : zb0;   // read z, overwrite with yg (same lane)
    float4 av = *(const float4*)&A_log[((size_t)m * DI + d) * NST + nq * 4];
    const float a0 = -expf(av.x), a1 = -expf(av.y), a2 = -expf(av.z), a3 = -expf(av.w);
    const float dpar = Dp[m * DI + d];
    const int s0 = chunk * Q;
    const int l0 = dir ? (L - 1 - s0) : s0;
    const int stp = dir ? -1 : 1;
    long iDU = ((long)(b * L + l0)) * DI + d;
    int  iB  = ((b * L + l0) << 4) + nq * 4;
    const long sDU = (long)stp * DI;
    const int  sB  = stp * NST;
    float4 hv = *(const float4*)&hin[(((size_t)(inst * 2 + b) * DI + d) * NC + chunk) * NST + nq * 4];
    float h0 = hv.x, h1 = hv.y, h2 = hv.z, h3 = hv.w;
    #pragma unroll 4
    for (int t = 0; t < Q; ++t) {
        float dlt = dl[iDU], uu = u[iDU];
        float4 bm = *(const float4*)&Bm[iB];
        float4 cm = *(const float4*)&Cm[iB];
        float du = dlt * uu;
        h0 = fmaf(__expf(dlt * a0), h0, du * bm.x);
        h1 = fmaf(__expf(dlt * a1), h1, du * bm.y);
        h2 = fmaf(__expf(dlt * a2), h2, du * bm.z);
        h3 = fmaf(__expf(dlt * a3), h3, du * bm.w);
        float yp = h0 * cm.x + h1 * cm.y + h2 * cm.z + h3 * cm.w;
        yp += __shfl_xor(yp, 1, 4);
        yp += __shfl_xor(yp, 2, 4);
        if (nq == 0) {
            float zv = bf2f(zs[iDU]);
            zs[iDU] = f2bf(fmaf(uu, dpar, yp) * zv);
        }
        iDU += sDU; iB += sB;
    }
}

// ---------------- outproj as bf16-MFMA GEMM (both insts summed) + residual into h
// M=8192 tok, N=128 cout (32/block), K=256. grid (TOK/64, 4).
__global__ __launch_bounds__(256) void outproj_mfma_kernel(
    const unsigned short* __restrict__ ygb0, const unsigned short* __restrict__ ygb1,
    const unsigned short* __restrict__ Woutb, float* __restrict__ h, int layer) {
    const int tid = threadIdx.x;
    const int w = tid >> 6, lane = tid & 63, q = lane >> 4, c = lane & 15;
    const int t0 = blockIdx.x * 64 + w * 16;
    const int ct0 = blockIdx.y * 32;
    f32x4 acc[2] = {};
    #pragma unroll
    for (int inst = 0; inst < 2; ++inst) {
        const unsigned short* yg = inst ? ygb1 : ygb0;
        const unsigned short* Wb = Woutb + (size_t)(layer * 2 + inst) * COUT * DI;
        for (int kc = 0; kc < 256; kc += 32) {
            bf16x8s a = *(const bf16x8s*)&yg[(size_t)(t0 + c) * DI + kc + q * 8];
            #pragma unroll
            for (int i = 0; i < 2; ++i) {
                bf16x8s bb = *(const bf16x8s*)&Wb[(size_t)(ct0 + i * 16 + c) * DI + kc + q * 8];
                acc[i] = __builtin_amdgcn_mfma_f32_16x16x32_bf16(a, bb, acc[i], 0, 0, 0);
            }
        }
    }
    #pragma unroll
    for (int i = 0; i < 2; ++i) {
        int cout = ct0 + i * 16 + c;
        #pragma unroll
        for (int r = 0; r < 4; ++r) {
            int tok = t0 + q * 4 + r;
            h[(size_t)tok * COUT + cout] += acc[i][r];
        }
    }
}

// ------------------------------------------------ final [B,L,C] -> [B,C,L]
__global__ __launch_bounds__(256) void transpose_kernel(
    const float* __restrict__ h, float* __restrict__ out) {
    __shared__ float tile[32][33];
    int lt0 = blockIdx.x * 32, ct0 = blockIdx.y * 32, b = blockIdx.z;
    int c = threadIdx.x & 31, r = threadIdx.x >> 5;
    #pragma unroll
    for (int j = 0; j < 4; ++j) {
        int ll = r + 8 * j;
        tile[ll][c] = h[((size_t)b * L + lt0 + ll) * COUT + ct0 + c];
    }
    __syncthreads();
    #pragma unroll
    for (int j = 0; j < 4; ++j) {
        int cc = r + 8 * j;
        out[((size_t)b * COUT + ct0 + cc) * L + lt0 + c] = tile[c][cc];
    }
}

// ======================================================================
extern "C" void kernel_launch(void* const* d_in, const int* in_sizes, int n_in,
                              void* d_out, int out_size, void* d_ws, size_t ws_size,
                              hipStream_t stream) {
    const float* x        = (const float*)d_in[0];
    const float* conv_w   = (const float*)d_in[1];
    const float* conv_b   = (const float*)d_in[2];
    const float* gn_g     = (const float*)d_in[3];
    const float* gn_b     = (const float*)d_in[4];
    const float* prelu_a  = (const float*)d_in[5];
    const float* ln_g     = (const float*)d_in[6];
    const float* ln_b     = (const float*)d_in[7];
    const float* W_in     = (const float*)d_in[8];
    const float* conv1d_w = (const float*)d_in[9];
    const float* conv1d_b = (const float*)d_in[10];
    const float* W_xproj  = (const float*)d_in[11];
    const float* W_dt     = (const float*)d_in[12];
    const float* b_dt     = (const float*)d_in[13];
    const float* A_log    = (const float*)d_in[14];
    const float* D_param  = (const float*)d_in[15];
    const float* W_out    = (const float*)d_in[16];

    float* ws = (float*)d_ws;
    float* h     = ws;                         // [B,L,128]               1,048,576
    float* xp0   = ws + 1048576;               // [B,L,256] f32           2,097,152
    float* xp1   = ws + 3145728;               //                         2,097,152
    unsigned short* zb0 = (unsigned short*)(ws + 5242880);   // [B,L,256] bf16; silu(z) then yg in-place
    unsigned short* zb1 = (unsigned short*)(ws + 6291456);   // bf16
    float* u0    = ws + 7340032;               // [B,L,256]               2,097,152
    float* u1    = ws + 9437184;
    float* dl0   = ws + 11534336;
    float* dl1   = ws + 13631488;
    float* Bm0   = ws + 15728640;              // [B,L,16]
    float* Bm1   = ws + 15859712;
    float* Cm0   = ws + 15990784;
    float* Cm1   = ws + 16121856;
    float* hend  = ws + 16252928;              // [2,B,256,NC=128,16] = 2,097,152
    float* dsumb = ws + 18350080;              // [2,B,NC,256] = 131,072
    unsigned short* Winb  = (unsigned short*)(ws + 18481152); // 262,144 bf16 (131,072 f)
    unsigned short* Wrb   = (unsigned short*)(ws + 18612224); // 40,960 bf16 (20,480 f)
    unsigned short* Woutb = (unsigned short*)(ws + 18632704); // 131,072 bf16 (65,536 f)
    float* stats = ws + 18698240;              // [4]
    unsigned short* hnb = (unsigned short*)hend;             // 1M bf16 (hend dead outside scans)
    unsigned short* xTb = zb0;                               // 1M bf16 (pre-loop only)

    zero_stats_kernel<<<1, 64, 0, stream>>>(stats);
    wconv_prep_kernel<<<160, 256, 0, stream>>>(conv_w, Wrb);
    win_prep_kernel<<<1024, 256, 0, stream>>>(W_in, Winb);
    wout_prep_kernel<<<512, 256, 0, stream>>>(W_out, Woutb);
    xpose_kernel<<<dim3(T / 64, B2), 256, 0, stream>>>(x, xTb);
    conv_mfma_kernel<<<dim3(TOK / 64, COUT / 64), 256, 0, stream>>>(xTb, Wrb, conv_b, h, stats);
    gn_prelu_kernel<<<(TOK * COUT / 4) / 256, 256, 0, stream>>>(h, gn_g, gn_b, prelu_a, stats);

    for (int layer = 0; layer < 2; ++layer) {
        ln_kernel<<<TOK / 4, 256, 0, stream>>>(h, hnb, ln_g + layer * COUT, ln_b + layer * COUT);
        inproj_mfma_kernel<<<dim3(TOK / 64, 16), 256, 0, stream>>>(hnb, Winb, xp0, zb0, xp1, zb1, layer);
        dwconv_kernel<<<4096, 256, 0, stream>>>(xp0, xp1, conv1d_w, conv1d_b, u0, u1, layer);
        xproj_kernel<<<dim3(TOK / 32, 2), 256, 0, stream>>>(u0, u1, W_xproj, W_dt, b_dt,
                                                            dl0, dl1, Bm0, Bm1, Cm0, Cm1, layer);
        scan1_kernel<<<dim3(NC * 4, B2, 2), 256, 0, stream>>>(dl0, dl1, u0, u1, Bm0, Bm1,
                                                              A_log, hend, dsumb, layer);
        combine_kernel<<<64, 256, 0, stream>>>(hend, dsumb, A_log, layer);
        scan2_kernel<<<dim3(NC * 4, B2, 2), 256, 0, stream>>>(dl0, dl1, u0, u1, Bm0, Bm1, Cm0, Cm1,
                                                              zb0, zb1, hend, A_log, D_param, layer);
        outproj_mfma_kernel<<<dim3(TOK / 64, 4), 256, 0, stream>>>(zb0, zb1, Woutb, h, layer);
    }
    transpose_kernel<<<dim3(L / 32, COUT / 32, B2), 256, 0, stream>>>(h, (float*)d_out);
}